// Round 11
// baseline (642.309 us; speedup 1.0000x reference)
//
#include <hip/hip_runtime.h>
#include <cstdint>
#include <cmath>

// ---------------------------------------------------------------------------
// Informer encoder forward (B=4, L=2048, ENC_IN=32, D_MODEL=512, D_FF=2048,
// E_LAYERS=2, H=8, FACTOR=5).
// Round 27: wide GEMMs (QKV, FFN1) -> TM=256 under the counted-vmcnt loop.
// R26 post-mortem arithmetic: 8-wave acc[2][4] issues 96 ds_read_b128/CU
// per K-step (~1150cyc LDS) vs ~640cyc MFMA -> LDS-issue-bound (0.75
// reads/MFMA). TM=256 acc[4][4] = 0.5 reads/MFMA. R22 tested this in the
// drain-bound regime (null, m252 regime-gate); R24's T4 made LDS the
// critical path, so re-test. Grids: QKV 384/192, FFN1 512/256; LDS 72KB ->
// 2 blocks/CU (unchanged). Narrow GEMMs stay TM=128 split-K.
// ---------------------------------------------------------------------------

#define NB 4
#define DM 512
#define NH 8
#define HD 64
#define QS 1536  // QKV row stride

typedef unsigned short ushort_t;
typedef __bf16 bf16x8 __attribute__((ext_vector_type(8)));
typedef float floatx4 __attribute__((ext_vector_type(4)));
typedef unsigned short ushort8_t __attribute__((ext_vector_type(8)));

__device__ inline ushort_t f2b(float f) {
  uint32_t u = __float_as_uint(f);
  uint32_t r = (u + 0x7fffu + ((u >> 16) & 1u)) >> 16;
  return (ushort_t)r;
}
__device__ inline float b2f(ushort_t u) {
  return __uint_as_float((uint32_t)u << 16);
}

// ---------------- fused weight casts ---------------------------------------
__global__ void castqkv_k(const float* __restrict__ Wq,
                          const float* __restrict__ Wk,
                          const float* __restrict__ Wv,
                          ushort_t* __restrict__ out) {
  int gid = blockIdx.x * 256 + threadIdx.x;  // 393216 float4 units
  if (gid >= 393216) return;
  int ly = gid / 196608, r4 = gid - ly * 196608;
  int r = r4 >> 7, c4 = r4 & 127;
  int sel = r >> 9, srow = r & 511;
  const float* src = (sel == 0 ? Wq : sel == 1 ? Wk : Wv) + ly * 262144 +
                     srow * 512 + c4 * 4;
  float4 v = *(const float4*)src;
  ushort4 o;
  o.x = f2b(v.x); o.y = f2b(v.y); o.z = f2b(v.z); o.w = f2b(v.w);
  ((ushort4*)out)[ly * 196608 + r * 128 + c4] = o;
}

__global__ void castw3_k(const float* __restrict__ Wo,
                         const float* __restrict__ W1,
                         const float* __restrict__ W2,
                         const float* __restrict__ tw,
                         ushort_t* __restrict__ oWo, ushort_t* __restrict__ oW1,
                         ushort_t* __restrict__ oW2, ushort_t* __restrict__ otw) {
  int gid = blockIdx.x * 256 + threadIdx.x;  // 1,191,936 float4 units
  if (gid >= 1191936) return;
  const float* src;
  ushort4* dst;
  int i;
  if (gid < 131072) { src = Wo; dst = (ushort4*)oWo; i = gid; }
  else if (gid < 655360) { src = W1; dst = (ushort4*)oW1; i = gid - 131072; }
  else if (gid < 1179648) { src = W2; dst = (ushort4*)oW2; i = gid - 655360; }
  else { src = tw; dst = (ushort4*)otw; i = gid - 1179648; }
  float4 v = ((const float4*)src)[i];
  ushort4 o;
  o.x = f2b(v.x); o.y = f2b(v.y); o.z = f2b(v.z); o.w = f2b(v.w);
  dst[i] = o;
}

// conv weight: (D, I, 3) -> bf16 (D, 3, I) so implicit-GEMM staging is
// contiguous in the input channel dim
__global__ void castw_conv_k(const float* __restrict__ in,
                             ushort_t* __restrict__ out) {
  int gid = blockIdx.x * 256 + threadIdx.x;  // 512*1536
  int d = gid / 1536, r = gid - d * 1536;
  int t = r >> 9, i = r & 511;
  out[gid] = f2b(in[d * 1536 + i * 3 + t]);
}

// final projection weight: (32, 512) -> fp32 (512, 32)
__global__ void castproj_k(const float* __restrict__ w,
                           float* __restrict__ wt) {
  int gid = blockIdx.x * 256 + threadIdx.x;  // 16384
  int k = gid >> 5, n = gid & 31;
  wt[gid] = w[n * 512 + k];
}

__global__ void setup_small_k(const float* __restrict__ bq,
                              const float* __restrict__ bk,
                              const float* __restrict__ bv,
                              float* __restrict__ ZB,
                              float* __restrict__ BQKV) {
  int gid = blockIdx.x * 256 + threadIdx.x;  // 3584
  if (gid >= 3584) return;
  if (gid < 512) { ZB[gid] = 0.f; return; }
  int g = gid - 512;
  int layer = g / 1536, r = g - layer * 1536;
  float v;
  if (r < 512) v = bq[layer * 512 + r];
  else if (r < 1024) v = bk[layer * 512 + r - 512];
  else v = bv[layer * 512 + r - 1024];
  BQKV[g] = v;
}

__host__ __device__ inline void threefry2x32(uint32_t k0, uint32_t k1,
                                             uint32_t c0, uint32_t c1,
                                             uint32_t* o0, uint32_t* o1) {
  uint32_t ks0 = k0, ks1 = k1, ks2 = k0 ^ k1 ^ 0x1BD11BDAu;
  uint32_t x0 = c0 + ks0;
  uint32_t x1 = c1 + ks1;
  const uint32_t rotA[4] = {13u, 15u, 26u, 6u};
  const uint32_t rotB[4] = {17u, 29u, 16u, 24u};
  uint32_t ks[3] = {ks0, ks1, ks2};
  #pragma unroll
  for (int i = 0; i < 5; ++i) {
    const uint32_t* r = (i & 1) ? rotB : rotA;
    #pragma unroll
    for (int j = 0; j < 4; ++j) {
      x0 += x1;
      x1 = (x1 << r[j]) | (x1 >> (32u - r[j]));
      x1 ^= x0;
    }
    x0 += ks[(i + 1) % 3];
    x1 += ks[(i + 2) % 3] + (uint32_t)(i + 1);
  }
  *o0 = x0; *o1 = x1;
}

__global__ void gen_idx_k(int* __restrict__ idx, int n, int mask,
                          uint32_t k0, uint32_t k1) {
  int i = blockIdx.x * 256 + threadIdx.x;
  if (i < n) {
    uint32_t o0, o1;
    threefry2x32(k0, k1, 0u, (uint32_t)i, &o0, &o1);
    idx[i] = (int)((o0 ^ o1) & (uint32_t)mask);
  }
}

__device__ inline float wave_sum64(float v) {
  #pragma unroll
  for (int o = 32; o > 0; o >>= 1) v += __shfl_xor(v, o, 64);
  return v;
}

// ---------------- positional-encoding table (2048 x 512) -------------------
__global__ void pe_k(float* __restrict__ pe) {
  int i = blockIdx.x * 256 + threadIdx.x;  // 1,048,576
  int d = i & 511, l = i >> 9;
  int j2 = d & ~1;
  float div = expf((float)j2 * -1.7988946039e-2f);  // -ln(10000)/512
  float ang = (float)l * div;
  pe[i] = (d & 1) ? cosf(ang) : sinf(ang);
}

// ---------------- im2col for token conv: (B*L, 96) bf16 --------------------
__global__ void im2col_tok_k(const float* __restrict__ xe,
                             ushort_t* __restrict__ A) {
  int gid = blockIdx.x * 256 + threadIdx.x;  // 8192*96
  int col = gid % 96;
  int row = gid / 96;
  int c = col / 3, t = col - c * 3;
  int b = row >> 11, l = row & 2047;
  int ls = (l + t - 1) & 2047;
  A[gid] = f2b(xe[((size_t)b * 2048 + ls) * 32 + c]);
}

// ---------------- bf16 MFMA GEMM v9: TM-templated, counted vmcnt -----------
__device__ inline void gload16(const ushort_t* g, ushort_t* l) {
  __builtin_amdgcn_global_load_lds(
      (const __attribute__((address_space(1))) unsigned int*)(const void*)g,
      (__attribute__((address_space(3))) unsigned int*)(void*)l, 16, 0, 0);
}

// CONV: A is Xb (B*L x 512 bf16); logical A[row][k] = Xb[(row_b, (l+t-1)%2048)][c]
// with t = k/512, c = k%512. Otherwise plain row-major A (M x K).
// LDS tile layout: 16-row blocks, row stride 64B; within a row the four 16B
// chunks are stored at position c ^ ((row>>1)&3) (in-segment swizzle; global
// coalescing preserved since the permutation stays inside the 64B segment).
// SPLITK==2: gridDim.x = 2*nb; blocks id>=nb handle the upper K half; both
// halves write RAW fp32 partials to Cf / Cf2; consumers reduce.
template <int TM, int CONV, int GELU, int OMODE, int ADDPE, int SPLITK>
__global__ __launch_bounds__(512, 4) void mgemm_k(
    const ushort_t* __restrict__ A, const ushort_t* __restrict__ W,
    const float* __restrict__ bias, float* __restrict__ Cf,
    float* __restrict__ Cf2, ushort_t* __restrict__ Cb,
    const float* __restrict__ pe, int X, int ldc, int K) {
  constexpr int MT = TM / 64;        // acc row-tiles per wave (2 or 4)
  constexpr int AG = TM / 128;       // A gloads per wave per K-step (1 or 2)
  constexpr int BUFSZ = (TM + 128) * 32;  // ushorts per staging buffer
  constexpr int SHSZ = (3 * BUFSZ > 18432) ? 3 * BUFSZ : 18432;
  __shared__ __align__(16) ushort_t SH[SHSZ];
  int id = blockIdx.x;
  int half = 0;
  if (SPLITK == 2) {
    int nb = gridDim.x >> 1;
    if (id >= nb) { half = 1; id -= nb; }
  }
  int kbase = half * (K >> 1);
  int KK = (SPLITK == 2) ? (K >> 1) : K;
  int cc = id & 7, j = id >> 3;
  int bx = j % X;
  int by = (j / X) * 8 + cc;
  int m0 = by * TM, n0 = bx * 128;
  int t = threadIdx.x;
  int lane = t & 63, wv = t >> 6;  // 8 waves
  int rl = lane >> 2;
  int cl = ((lane & 3) ^ ((rl >> 1) & 3)) * 8;  // in-segment chunk swizzle
  int RaA = wv * (16 * AG);  // A rows staged per wave
  int RaB = wv * 16;         // B rows staged per wave
  const ushort_t* gA[AG];
  int cbv[AG], clrv[AG], lAoff[AG];
  #pragma unroll
  for (int g = 0; g < AG; ++g) {
    int ar = m0 + RaA + g * 16 + rl;
    gA[g] = A + (size_t)ar * K + kbase + cl;  // non-CONV path
    cbv[g] = ar >> 11;                        // CONV: batch
    clrv[g] = ar & 2047;                      // CONV: seq pos
    lAoff[g] = (RaA + g * 16) * 32;
  }
  const ushort_t* gB = W + (size_t)(n0 + RaB + rl) * K + kbase + cl;
  int lBoff = TM * 32 + RaB * 32;

  int quad = lane >> 4, lr = lane & 15;
  int qs = (quad ^ ((lr >> 1) & 3)) * 8;  // swizzled read chunk offset
  int wm = wv >> 1, wn = wv & 1;  // 4 (M) x 2 (N) waves, (TM/4)x64 each

  // stage K-step kst into LDS buffer buf (AG+1 vmem instructions per wave)
  auto STAGE = [&](int kst, int buf) {
    int bb = buf * BUFSZ;
    int ko = kst << 5;
    #pragma unroll
    for (int g = 0; g < AG; ++g) {
      if (CONV) {
        int kg = kbase + ko;
        int tt = kg >> 9;
        int c = (kg & 511) + cl;
        int ls = (clrv[g] + tt - 1) & 2047;
        gload16(A + ((size_t)(cbv[g] * 2048 + ls) * 512 + c),
                SH + bb + lAoff[g]);
      } else {
        gload16(gA[g] + ko, SH + bb + lAoff[g]);
      }
    }
    gload16(gB + ko, SH + bb + lBoff);
  };

  floatx4 acc[MT][4] = {};
  int nt = KK >> 5;
  STAGE(0, 0);
  if (nt > 1) STAGE(1, 1);
  int cur = 0;
  for (int it = 0; it < nt; ++it) {
    // counted wait: own stage(it) complete; stage(it+1) stays in flight
    if (it < nt - 1) {
      if constexpr (AG == 1)
        asm volatile("s_waitcnt vmcnt(2)" ::: "memory");
      else
        asm volatile("s_waitcnt vmcnt(3)" ::: "memory");
    } else {
      asm volatile("s_waitcnt vmcnt(0)" ::: "memory");
    }
    __builtin_amdgcn_s_barrier();        // all waves: stage(it) landed,
    __builtin_amdgcn_sched_barrier(0);   // prior-iter reads retired
    int nx = it + 2;
    if (nx < nt) {
      int nb3 = cur + 2;
      if (nb3 >= 3) nb3 -= 3;
      STAGE(nx, nb3);                    // buf last read at it-1: safe
    }
    const ushort_t* Ab = SH + cur * BUFSZ;
    const ushort_t* Bb = Ab + TM * 32;
    bf16x8 av[MT], bv[4];
    #pragma unroll
    for (int mt = 0; mt < MT; ++mt)
      av[mt] =
          *(const bf16x8*)&Ab[(wm * (16 * MT) + mt * 16 + lr) * 32 + qs];
    #pragma unroll
    for (int nt2 = 0; nt2 < 4; ++nt2)
      bv[nt2] = *(const bf16x8*)&Bb[(wn * 64 + nt2 * 16 + lr) * 32 + qs];
    #pragma unroll
    for (int mt = 0; mt < MT; ++mt)
      #pragma unroll
      for (int nt2 = 0; nt2 < 4; ++nt2)
        acc[mt][nt2] = __builtin_amdgcn_mfma_f32_16x16x32_bf16(
            av[mt], bv[nt2], acc[mt][nt2], 0, 0, 0);
    // all my LDS reads retired before next barrier (closes WAR window)
    asm volatile("s_waitcnt lgkmcnt(0)" ::: "memory");
    __builtin_amdgcn_sched_barrier(0);
    cur = (cur == 2) ? 0 : cur + 1;
  }
  __syncthreads();  // epilogue reuses SH

  if (SPLITK == 2) {
    // raw fp32 partial; bias applied by the consumer
    float* dst = half ? Cf2 : Cf;
    #pragma unroll
    for (int nt2 = 0; nt2 < 4; ++nt2) {
      int col = n0 + wn * 64 + nt2 * 16 + lr;
      #pragma unroll
      for (int mt = 0; mt < MT; ++mt) {
        int row0 = m0 + wm * (16 * MT) + mt * 16 + quad * 4;
        #pragma unroll
        for (int r = 0; r < 4; ++r)
          dst[(size_t)(row0 + r) * ldc + col] = acc[mt][nt2][r];
      }
    }
  } else if (OMODE == 0) {
    #pragma unroll
    for (int nt2 = 0; nt2 < 4; ++nt2) {
      int col = n0 + wn * 64 + nt2 * 16 + lr;
      float bsv = bias[col];
      #pragma unroll
      for (int mt = 0; mt < MT; ++mt) {
        int row0 = m0 + wm * (16 * MT) + mt * 16 + quad * 4;
        #pragma unroll
        for (int r = 0; r < 4; ++r) {
          int row = row0 + r;
          float v = acc[mt][nt2][r] + bsv;
          if (ADDPE) v += pe[(size_t)(row & 2047) * ldc + col];
          if (GELU) v = 0.5f * v * (1.0f + erff(v * 0.70710678118654752f));
          Cf[(size_t)row * ldc + col] = v;
        }
      }
    }
  } else {
    // bf16 through per-wave LDS transpose -> coalesced ushort8 stores.
    ushort_t* ep = SH + wv * 2304;
    #pragma unroll
    for (int p = 0; p < MT / 2; ++p) {
      #pragma unroll
      for (int nt2 = 0; nt2 < 4; ++nt2) {
        int col = n0 + wn * 64 + nt2 * 16 + lr;
        float bsv = bias[col];
        #pragma unroll
        for (int ml = 0; ml < 2; ++ml) {
          int mt = p * 2 + ml;
          #pragma unroll
          for (int r = 0; r < 4; ++r) {
            int row = m0 + wm * (16 * MT) + mt * 16 + quad * 4 + r;
            float v = acc[mt][nt2][r] + bsv;
            if (ADDPE) v += pe[(size_t)(row & 2047) * ldc + col];
            if (GELU) v = 0.5f * v * (1.0f + erff(v * 0.70710678118654752f));
            if (OMODE == 2) Cf[(size_t)row * ldc + col] = v;
            ep[(ml * 16 + quad * 4 + r) * 72 + nt2 * 16 + lr] = f2b(v);
          }
        }
      }
      int r8 = lane >> 3, c8 = (lane & 7) * 8;
      #pragma unroll
      for (int i = 0; i < 4; ++i) {
        int row = i * 8 + r8;
        ushort8_t vv = *(const ushort8_t*)&ep[row * 72 + c8];
        *(ushort8_t*)&Cb[(size_t)(m0 + wm * (16 * MT) + p * 32 + row) * ldc +
                         n0 + wn * 64 + c8] = vv;
      }
    }
  }
}

// ---------------- final projection (M=4096, N=32, K=512, fp32) -------------
__global__ __launch_bounds__(256) void proj_k(
    const float* __restrict__ A, const float* __restrict__ Wt,
    const float* __restrict__ bias, float* __restrict__ C) {
  int t = threadIdx.x;
  int n = t & 31, ml = t >> 5;
  int m = blockIdx.x * 8 + ml;
  const float* a = A + (size_t)m * DM;
  float a0 = 0.f, a1 = 0.f, a2 = 0.f, a3 = 0.f;
  #pragma unroll 4
  for (int k = 0; k < DM; k += 4) {
    float4 av = *(const float4*)&a[k];
    a0 += av.x * Wt[k * 32 + n];
    a1 += av.y * Wt[(k + 1) * 32 + n];
    a2 += av.z * Wt[(k + 2) * 32 + n];
    a3 += av.w * Wt[(k + 3) * 32 + n];
  }
  C[(size_t)m * 32 + n] = (a0 + a2) + (a1 + a3) + bias[n];
}

// ---------------- LayerNorm (+residuals, +col bias, +optional bf16 copy) ---
// O = LN(A + Bres + Bres2 + cbias) * g + be; Bres/Bres2/cbias nullable.
__global__ __launch_bounds__(128) void ln_k(
    const float* __restrict__ A, const float* __restrict__ Bres,
    const float* __restrict__ Bres2, const float* __restrict__ cbias,
    const float* __restrict__ g, const float* __restrict__ be,
    float* __restrict__ O, ushort_t* __restrict__ Ob) {
  int r = blockIdx.x, t = threadIdx.x;
  __shared__ float lds[2];
  float4 v = ((const float4*)(A + (size_t)r * DM))[t];
  if (Bres) {
    float4 u = ((const float4*)(Bres + (size_t)r * DM))[t];
    v.x += u.x; v.y += u.y; v.z += u.z; v.w += u.w;
  }
  if (Bres2) {
    float4 u = ((const float4*)(Bres2 + (size_t)r * DM))[t];
    v.x += u.x; v.y += u.y; v.z += u.z; v.w += u.w;
  }
  if (cbias) {
    float4 u = ((const float4*)cbias)[t];
    v.x += u.x; v.y += u.y; v.z += u.z; v.w += u.w;
  }
  float s = wave_sum64(v.x + v.y + v.z + v.w);
  int w = t >> 6;
  if ((t & 63) == 0) lds[w] = s;
  __syncthreads();
  float mu = (lds[0] + lds[1]) * (1.0f / 512.0f);
  __syncthreads();
  float dx = v.x - mu, dy = v.y - mu, dz = v.z - mu, dw = v.w - mu;
  float sq = wave_sum64(dx * dx + dy * dy + dz * dz + dw * dw);
  if ((t & 63) == 0) lds[w] = sq;
  __syncthreads();
  float var = (lds[0] + lds[1]) * (1.0f / 512.0f);
  float inv = 1.0f / sqrtf(var + 1e-5f);
  float4 gv = ((const float4*)g)[t];
  float4 bv = ((const float4*)be)[t];
  float4 o;
  o.x = dx * inv * gv.x + bv.x;
  o.y = dy * inv * gv.y + bv.y;
  o.z = dz * inv * gv.z + bv.z;
  o.w = dw * inv * gv.w + bv.w;
  ((float4*)(O + (size_t)r * DM))[t] = o;
  if (Ob) {
    ushort4 ob;
    ob.x = f2b(o.x); ob.y = f2b(o.y); ob.z = f2b(o.z); ob.w = f2b(o.w);
    ((ushort4*)(Ob + (size_t)r * DM))[t] = ob;
  }
}

// ---------------- M[b,h,l]: one wave per (b,l), all-bf16 QKV ---------------
template <int UU>
__global__ __launch_bounds__(256) void qk_m_k(
    const ushort_t* __restrict__ QKVb, const int* __restrict__ idx,
    float* __restrict__ Mout, int Lx) {
  int l = blockIdx.x;
  int b = threadIdx.x >> 6;  // wave = batch
  int lane = threadIdx.x & 63;
  const ushort_t* qp = QKVb + ((size_t)b * Lx + l) * QS + lane * 8;
  float q[8];
  {
    ushort8_t qv = *(const ushort8_t*)qp;
    #pragma unroll
    for (int c = 0; c < 8; ++c) q[c] = b2f(qv[c]);
  }
  const ushort_t* Kbase = QKVb + (size_t)b * Lx * QS + 512 + lane * 8;
  const int* ip = idx + (size_t)l * UU;
  float maxv = -INFINITY, sumv = 0.f;
  #pragma unroll
  for (int u0 = 0; u0 < UU; u0 += 8) {
    ushort8_t kv[8];
    #pragma unroll
    for (int j = 0; j < 8; ++j) {
      if (u0 + j < UU)
        kv[j] = *(const ushort8_t*)(Kbase + (size_t)ip[u0 + j] * QS);
    }
    #pragma unroll
    for (int j = 0; j < 8; ++j) {
      if (u0 + j < UU) {
        float p = 0.f;
        #pragma unroll
        for (int c = 0; c < 8; ++c) p += q[c] * b2f(kv[j][c]);
        p += __shfl_xor(p, 1, 64);
        p += __shfl_xor(p, 2, 64);
        p += __shfl_xor(p, 4, 64);
        maxv = fmaxf(maxv, p);
        sumv += p;
      }
    }
  }
  if ((lane & 7) == 0) {
    int h = lane >> 3;
    Mout[(size_t)(b * 8 + h) * Lx + l] = maxv - sumv / (float)Lx;
  }
}

// ---------------- rank-based top-U, 4-way scan split (JAX tie-break) -------
__global__ __launch_bounds__(1024) void topk_k(
    const float* __restrict__ Mbuf, int* __restrict__ Mtop, int Lx, int U) {
  int nch = Lx >> 8;
  int bh = blockIdx.x / nch, ch = blockIdx.x % nch;
  const float* m = Mbuf + (size_t)bh * Lx;
  __shared__ float sm[2048];
  __shared__ int part[1024];
  int t = threadIdx.x;
  int c = t & 255, q = t >> 8;
  for (int i = t; i < Lx; i += 1024) sm[i] = m[i];
  __syncthreads();
  int i0 = (ch << 8) + c;
  float v0 = sm[i0];
  int r0 = 0;
  int qlen = Lx >> 2;
  int j0 = q * qlen, j1 = j0 + qlen;
  for (int j = j0; j < j1; j += 4) {
    float4 mj = *(const float4*)&sm[j];
    r0 += (mj.x > v0) || (mj.x == v0 && (j + 0) < i0);
    r0 += (mj.y > v0) || (mj.y == v0 && (j + 1) < i0);
    r0 += (mj.z > v0) || (mj.z == v0 && (j + 2) < i0);
    r0 += (mj.w > v0) || (mj.w == v0 && (j + 3) < i0);
  }
  part[t] = r0;
  __syncthreads();
  if (q == 0) {
    int r = part[c] + part[c + 256] + part[c + 512] + part[c + 768];
    if (r < U) Mtop[bh * U + r] = i0;
  }
}

// ---------------- meanV from bf16 QKV (V at +1024) -------------------------
__global__ __launch_bounds__(512) void meanv1_k(const ushort_t* __restrict__ QKVb,
                                                float* __restrict__ part,
                                                int Lx) {
  int b = blockIdx.x >> 4, chunk = blockIdx.x & 15;
  int rows = Lx >> 4;
  int t = threadIdx.x;  // 512
  const ushort_t* vp =
      QKVb + ((size_t)b * Lx + (size_t)chunk * rows) * QS + 1024 + t;
  float s = 0.f;
  for (int l = 0; l < rows; ++l) s += b2f(vp[(size_t)l * QS]);
  part[(size_t)blockIdx.x * DM + t] = s;
}
__global__ __launch_bounds__(512) void meanv2_k(const float* __restrict__ part,
                                                float* __restrict__ mv,
                                                int Lx) {
  int b = blockIdx.x, t = threadIdx.x;
  float s = 0.f;
  #pragma unroll
  for (int c = 0; c < 16; ++c) s += part[(size_t)(b * 16 + c) * DM + t];
  mv[b * DM + t] = s / (float)Lx;
}

__global__ void fillctx_k(ushort_t* __restrict__ ctx,
                          const float* __restrict__ mv, int Lx) {
  size_t i4 = (size_t)blockIdx.x * 256 + threadIdx.x;
  int col4 = (int)(i4 & 127);
  size_t row = i4 >> 7;
  int b = (int)(row / (size_t)Lx);
  const float* m = mv + b * DM + col4 * 4;
  ushort4 o;
  o.x = f2b(m[0]); o.y = f2b(m[1]); o.z = f2b(m[2]); o.w = f2b(m[3]);
  ((ushort4*)ctx)[i4] = o;
}

// ---------------- one-shot MFMA attention (wave = one 64-key chunk) --------
template <int UP>  // padded query count (48 >= U)
__global__ __launch_bounds__(256) void attn_mfma_k(
    const ushort_t* __restrict__ QKVb, const int* __restrict__ Mtop,
    float* __restrict__ part, int Lx, int U, int nblk) {
  __shared__ ushort_t Ps[4][UP * 72];   // P transpose buf (stride 72 elems)
  __shared__ ushort_t Vs[4][64 * 64];   // V tile, xor-swizzled
  int bh = blockIdx.x / nblk, blkc = blockIdx.x % nblk;
  int h = bh & 7, b = bh >> 3;
  int t = threadIdx.x;
  int wv = t >> 6, lane = t & 63;
  int quad = lane >> 4, lr = lane & 15;
  int chunk = blkc * 4 + wv;
  int k0 = chunk * 64;
  const ushort_t* Qb = QKVb + (size_t)b * Lx * QS + h * HD;
  const ushort_t* Kb = Qb + 512;
  const ushort_t* Vb = Qb + 1024;

  // Q fragments: rows gathered via Mtop (clamped for padded rows)
  bf16x8 qf[3][2];
  #pragma unroll
  for (int mt = 0; mt < 3; ++mt) {
    int u = mt * 16 + lr;
    int qi = Mtop[bh * U + (u < U ? u : U - 1)];
    const ushort_t* qp = Qb + (size_t)qi * QS + quad * 8;
    qf[mt][0] = *(const bf16x8*)qp;
    qf[mt][1] = *(const bf16x8*)(qp + 32);
  }

  // stage V tile (64 rows x 64 d), xor-swizzle so column reads are
  // conflict-free: elem addr = k*64 + (d ^ (((k>>3)&3)<<4))
  ushort_t* vs = Vs[wv];
  #pragma unroll
  for (int i = 0; i < 8; ++i) {
    int cid = i * 64 + lane;
    int k = cid >> 3, c = cid & 7;
    ushort8_t v = *(const ushort8_t*)(Vb + (size_t)(k0 + k) * QS + c * 8);
    *(ushort8_t*)&vs[k * 64 + ((c * 8) ^ (((k >> 3) & 3) << 4))] = v;
  }

  // S = Q K^T (K frags direct from global)
  floatx4 Sa[3][4] = {};
  #pragma unroll
  for (int kt = 0; kt < 4; ++kt) {
    const ushort_t* kp = Kb + (size_t)(k0 + kt * 16 + lr) * QS + quad * 8;
    bf16x8 kf0 = *(const bf16x8*)kp;
    bf16x8 kf1 = *(const bf16x8*)(kp + 32);
    #pragma unroll
    for (int mt = 0; mt < 3; ++mt) {
      Sa[mt][kt] = __builtin_amdgcn_mfma_f32_16x16x32_bf16(
          qf[mt][0], kf0, Sa[mt][kt], 0, 0, 0);
      Sa[mt][kt] = __builtin_amdgcn_mfma_f32_16x16x32_bf16(
          qf[mt][1], kf1, Sa[mt][kt], 0, 0, 0);
    }
  }

  // softmax over the 64 local keys (rows u = mt*16 + quad*4 + r, col = lr)
  float m_[3][4], l_[3][4];
  #pragma unroll
  for (int mt = 0; mt < 3; ++mt) {
    #pragma unroll
    for (int kt = 0; kt < 4; ++kt) Sa[mt][kt] *= 0.125f;
    #pragma unroll
    for (int r = 0; r < 4; ++r) {
      float mx = fmaxf(fmaxf(Sa[mt][0][r], Sa[mt][1][r]),
                       fmaxf(Sa[mt][2][r], Sa[mt][3][r]));
      #pragma unroll
      for (int o = 1; o <= 8; o <<= 1) mx = fmaxf(mx, __shfl_xor(mx, o, 64));
      float rs = 0.f;
      #pragma unroll
      for (int kt = 0; kt < 4; ++kt) {
        float e = __expf(Sa[mt][kt][r] - mx);
        Sa[mt][kt][r] = e;
        rs += e;
      }
      #pragma unroll
      for (int o = 1; o <= 8; o <<= 1) rs += __shfl_xor(rs, o, 64);
      m_[mt][r] = mx;
      l_[mt][r] = rs;
    }
  }

  // PV in bf16 hi+lo (near-fp32 accuracy). P transposed via per-wave LDS.
  ushort_t* ps = Ps[wv];
  floatx4 Oa[3][4] = {};
  #pragma unroll
  for (int pass = 0; pass < 2; ++pass) {
    #pragma unroll
    for (int mt = 0; mt < 3; ++mt)
      #pragma unroll
      for (int kt = 0; kt < 4; ++kt)
        #pragma unroll
        for (int r = 0; r < 4; ++r) {
          float e = Sa[mt][kt][r];
          ushort_t hb = f2b(e);
          ps[(mt * 16 + quad * 4 + r) * 72 + kt * 16 + lr] = hb;
          Sa[mt][kt][r] = e - b2f(hb);  // residual for lo pass
        }
    #pragma unroll
    for (int kk = 0; kk < 2; ++kk) {
      bf16x8 pf[3];
      #pragma unroll
      for (int mt = 0; mt < 3; ++mt)
        pf[mt] = *(const bf16x8*)&ps[(mt * 16 + lr) * 72 + kk * 32 + quad * 8];
      #pragma unroll
      for (int nt = 0; nt < 4; ++nt) {
        ushort8_t vt;
        #pragma unroll
        for (int j = 0; j < 8; ++j)
          vt[j] = vs[(kk * 32 + quad * 8 + j) * 64 +
                     ((nt * 16 + lr) ^ (quad << 4))];
        bf16x8 vf = *(bf16x8*)&vt;
        #pragma unroll
        for (int mt = 0; mt < 3; ++mt)
          Oa[mt][nt] = __builtin_amdgcn_mfma_f32_16x16x32_bf16(
              pf[mt], vf, Oa[mt][nt], 0, 0, 0);
      }
    }
  }

  // store partial (u < U only; format matches attn_merge_k)
  float* pb = part + (size_t)(bh * (nblk * 4) + chunk) * U * 66;
  #pragma unroll
  for (int mt = 0; mt < 3; ++mt) {
    #pragma unroll
    for (int r = 0; r < 4; ++r) {
      int u = mt * 16 + quad * 4 + r;
      if (u < U) {
        #pragma unroll
        for (int nt = 0; nt < 4; ++nt)
          pb[(size_t)u * 66 + nt * 16 + lr] = Oa[mt][nt][r];
        if (lr == 0) {
          pb[(size_t)u * 66 + 64] = m_[mt][r];
          pb[(size_t)u * 66 + 65] = l_[mt][r];
        }
      }
    }
  }
}

__global__ __launch_bounds__(64) void attn_merge_k(
    const float* __restrict__ part, const int* __restrict__ Mtop,
    ushort_t* __restrict__ ctx, int Lx, int U, int nchunk) {
  int bu = blockIdx.x;
  int u = bu % U, bh = bu / U;
  int h = bh & 7, b = bh >> 3;
  int d = threadIdx.x;  // 64
  float M = -INFINITY;
  for (int c = 0; c < nchunk; ++c)
    M = fmaxf(M, part[((size_t)(bh * nchunk + c) * U + u) * 66 + 64]);
  float L = 0.f, O = 0.f;
  for (int c = 0; c < nchunk; ++c) {
    const float* pp = part + ((size_t)(bh * nchunk + c) * U + u) * 66;
    float w = __expf(pp[64] - M);
    L += pp[65] * w;
    O += pp[d] * w;
  }
  int qi = Mtop[bh * U + u];
  ctx[((size_t)b * Lx + qi) * DM + h * HD + d] = f2b(O / L);
}

// ---------------- batch-norm stats over two partials + bias ----------------
__global__ __launch_bounds__(256) void bn1_k(const float* __restrict__ Y0,
                                             const float* __restrict__ Y1,
                                             const float* __restrict__ cb,
                                             float* __restrict__ ps,
                                             float* __restrict__ pq) {
  int blk = blockIdx.x;
  int t = threadIdx.x;
  float cb0 = cb[t], cb1 = cb[t + 256];
  float s0 = 0, q0 = 0, s1 = 0, q1 = 0;
  const float* b0 = Y0 + (size_t)blk * 256 * DM;
  const float* b1 = Y1 + (size_t)blk * 256 * DM;
  for (int r = 0; r < 256; ++r) {
    float a = b0[(size_t)r * DM + t] + b1[(size_t)r * DM + t] + cb0;
    float b = b0[(size_t)r * DM + t + 256] + b1[(size_t)r * DM + t + 256] + cb1;
    s0 += a; q0 += a * a; s1 += b; q1 += b * b;
  }
  ps[blk * DM + t] = s0; ps[blk * DM + t + 256] = s1;
  pq[blk * DM + t] = q0; pq[blk * DM + t + 256] = q1;
}
__global__ __launch_bounds__(512) void bn2_k(const float* __restrict__ ps,
                                             const float* __restrict__ pq,
                                             float* __restrict__ mu,
                                             float* __restrict__ var) {
  int t = threadIdx.x;
  float s = 0, q = 0;
  #pragma unroll
  for (int c = 0; c < 32; ++c) { s += ps[c * DM + t]; q += pq[c * DM + t]; }
  float m = s * (1.0f / 8192.f);
  mu[t] = m;
  var[t] = q * (1.0f / 8192.f) - m * m;
}

// fused bn+elu+maxpool(k=3,s=2,pad=1) over two partials + bias
__global__ void bnpool_k(const float* __restrict__ Y0,
                         const float* __restrict__ Y1,
                         const float* __restrict__ cb,
                         const float* __restrict__ mu,
                         const float* __restrict__ var,
                         const float* __restrict__ g,
                         const float* __restrict__ be, float* __restrict__ O,
                         ushort_t* __restrict__ Ob) {
  size_t i = (size_t)blockIdx.x * 256 + threadIdx.x;  // 4*1024*512
  int c = (int)(i & 511);
  size_t row = i >> 9;
  int lo = (int)(row & 1023);
  int b = (int)(row >> 10);
  float sc = g[c] / sqrtf(var[c] + 1e-5f);
  float sh = be[c] - mu[c] * sc;
  float cbv = cb[c];
  int l0 = 2 * lo - 1;
  float m = -INFINITY;
  #pragma unroll
  for (int tt = 0; tt < 3; ++tt) {
    int l = l0 + tt;
    if (l >= 0 && l < 2048) {
      size_t off = ((size_t)b * 2048 + l) * DM + c;
      float v = (Y0[off] + Y1[off] + cbv) * sc + sh;
      v = v > 0.f ? v : expm1f(v);
      m = fmaxf(m, v);
    }
  }
  O[i] = m;
  Ob[i] = f2b(m);
}

// ---------------------------------------------------------------------------
extern "C" void kernel_launch(void* const* d_in, const int* in_sizes, int n_in,
                              void* d_out, int out_size, void* d_ws,
                              size_t ws_size, hipStream_t stream) {
  (void)in_sizes; (void)n_in; (void)out_size; (void)ws_size;
  const float* x_enc  = (const float*)d_in[0];
  const float* tok_w  = (const float*)d_in[1];
  const float* Wq     = (const float*)d_in[2];
  const float* bq     = (const float*)d_in[3];
  const float* Wk     = (const float*)d_in[4];
  const float* bk     = (const float*)d_in[5];
  const float* Wv     = (const float*)d_in[6];
  const float* bv     = (const float*)d_in[7];
  const float* Wo     = (const float*)d_in[8];
  const float* bo     = (const float*)d_in[9];
  const float* W1     = (const float*)d_in[10];
  const float* b1     = (const float*)d_in[11];
  const float* W2     = (const float*)d_in[12];
  const float* b2     = (const float*)d_in[13];
  const float* ln1_g  = (const float*)d_in[14];
  const float* ln1_b  = (const float*)d_in[15];
  const float* ln2_g  = (const float*)d_in[16];
  const float* ln2_b  = (const float*)d_in[17];
  const float* conv_w = (const float*)d_in[18];
  const float* conv_b = (const float*)d_in[19];
  const float* bn_g   = (const float*)d_in[20];
  const float* bn_b   = (const float*)d_in[21];
  const float* normf_g = (const float*)d_in[22];
  const float* normf_b = (const float*)d_in[23];
  const float* proj_w = (const float*)d_in[24];
  const float* proj_b = (const float*)d_in[25];
  float* out = (float*)d_out;
  float* ws = (float*)d_ws;

  // ---- fp32 workspace layout (float offsets) ----
  float* X    = ws;                    // 4,194,304
  float* Y2B  = ws + 4194304;          // 4,194,304 (split-K partial #2)
  float* SCR  = ws + 8388608;          // 8,388,608 (final-LN scratch)
  ushort_t* CTXb = (ushort_t*)(ws + 16777216);  // bf16 ctx
  float* Y2   = ws + 20971520;         // 4,194,304 (attn partials / partial #1)
  float* Mb   = ws + 25165824;         // 65,536
  float* MV   = ws + 25231360;         // 2,048
  float* MVP  = ws + 25233408;         // 32,768
  float* BNps = ws + 25266176;         // 16,384
  float* BNpq = ws + 25282560;         // 16,384
  float* BNmu = ws + 25298944;         // 512
  float* BNvr = ws + 25299456;         // 512
  float* ZB   = ws + 25299968;         // 512 (zero bias)
  float* BQKV = ws + 25300480;         // 3,072 (concat qkv bias, 2 layers)
  int*   IDX  = (int*)(ws + 25303552); // 81,920
  int*   MT   = (int*)(ws + 25385472); // 1,280
  // ---- bf16 workspace ----
  ushort_t* U0   = (ushort_t*)(ws + 25386752);
  ushort_t* Xb   = U0;                 // 4,194,304
  ushort_t* Hb   = U0 + 4194304;       // 16,777,216 (FFN hidden)
  ushort_t* QKVb = Hb;                 // alias: bf16 QKV — live QKV-GEMM ->
                                       // attn, before FFN uses Hb
  ushort_t* Wqkvb= U0 + 20971520;      // 1,572,864
  ushort_t* Wob  = U0 + 22544384;      // 524,288
  ushort_t* W1b  = U0 + 23068672;      // 2,097,152
  ushort_t* W2b  = U0 + 25165824;      // 2,097,152
  ushort_t* Cwb  = U0 + 27262976;      // 786,432 ([d][t][i] layout)
  ushort_t* Twb  = U0 + 28049408;      // 49,152
  ushort_t* Atok = U0 + 28098560;      // 786,432
  float* PEf = ws + 39829248;          // 1,048,576 (PE table)
  float* PWt = ws + 40877824;          // 16,384 (transposed proj weight)

  // ---- fused preamble ----
  castqkv_k<<<1536, 256, 0, stream>>>(Wq, Wk, Wv, Wqkvb);
  castw3_k<<<4656, 256, 0, stream>>>(Wo, W1, W2, tok_w, Wob, W1b, W2b, Twb);
  castw_conv_k<<<3072, 256, 0, stream>>>(conv_w, Cwb);
  castproj_k<<<64, 256, 0, stream>>>(proj_w, PWt);
  setup_small_k<<<14, 256, 0, stream>>>(bq, bk, bv, ZB, BQKV);
  pe_k<<<4096, 256, 0, stream>>>(PEf);
  im2col_tok_k<<<3072, 256, 0, stream>>>(x_enc, Atok);

  // token embedding GEMM (+PE): K=96
  mgemm_k<128, 0, 0, 2, 1, 1><<<256, 512, 0, stream>>>(
      Atok, Twb, ZB, X, nullptr, Xb, PEf, 4, DM, 96);

  for (int layer = 0; layer < 2; ++layer) {
    const int Lx = (layer == 0) ? 2048 : 1024;
    const int U  = (layer == 0) ? 40 : 35;
    const int M  = NB * Lx;
    const int Yt = M / 128;
    const int Y2t = M / 256;           // 256-row tiles for wide-N GEMMs
    const int NCHT = Lx / 64;          // one 64-key chunk per wave
    const int NBLK = NCHT / 4;         // 4 waves per block

    uint32_t kl0, kl1, s0, s1;
    threefry2x32(0u, 42u, 0u, (uint32_t)layer, &kl0, &kl1);
    threefry2x32(kl0, kl1, 0u, 1u, &s0, &s1);
    int nidx = Lx * U;
    gen_idx_k<<<(nidx + 255) / 256, 256, 0, stream>>>(IDX, nidx, Lx - 1, s0, s1);

    // fused QKV GEMM: bf16-only output, 256-row tiles (acc[4][4]/wave)
    mgemm_k<256, 0, 0, 1, 0, 1><<<12 * Y2t, 512, 0, stream>>>(
        Xb, Wqkvb + (size_t)layer * 786432, BQKV + layer * 1536, nullptr,
        nullptr, QKVb, nullptr, 12, QS, DM);

    // ProbSparse attention (all bf16 QKV)
    if (layer == 0)
      qk_m_k<40><<<Lx, 256, 0, stream>>>(QKVb, IDX, Mb, Lx);
    else
      qk_m_k<35><<<Lx, 256, 0, stream>>>(QKVb, IDX, Mb, Lx);
    topk_k<<<NB * NH * (Lx >> 8), 1024, 0, stream>>>(Mb, MT, Lx, U);
    meanv1_k<<<NB * 16, 512, 0, stream>>>(QKVb, MVP, Lx);
    meanv2_k<<<NB, 512, 0, stream>>>(MVP, MV, Lx);
    fillctx_k<<<(M * DM / 4) / 256, 256, 0, stream>>>(CTXb, MV, Lx);
    attn_mfma_k<48><<<NB * NH * NBLK, 256, 0, stream>>>(QKVb, MT, Y2, Lx, U,
                                                        NBLK);
    attn_merge_k<<<NB * NH * U, 64, 0, stream>>>(Y2, MT, CTXb, Lx, U, NCHT);

    // output projection split-K x2 (raw partials) + residual+bias in LN1
    mgemm_k<128, 0, 0, 0, 0, 2><<<2 * 4 * Yt, 512, 0, stream>>>(
        CTXb, Wob + (size_t)layer * 262144, nullptr, Y2, Y2B, nullptr,
        nullptr, 4, DM, DM);
    ln_k<<<M, 128, 0, stream>>>(X, Y2, Y2B, bo + layer * DM,
                                ln1_g + layer * DM, ln1_b + layer * DM, X, Xb);

    // FFN1 (GELU fused; hidden kept in bf16), 256-row tiles
    mgemm_k<256, 0, 1, 1, 0, 1><<<16 * Y2t, 512, 0, stream>>>(
        Xb, W1b + (size_t)layer * 1048576, b1 + layer * 2048, nullptr, nullptr,
        Hb, nullptr, 16, 2048, DM);
    // FFN2 split-K x2 (raw partials) + residual+bias in LN2
    mgemm_k<128, 0, 0, 0, 0, 2><<<2 * 4 * Yt, 512, 0, stream>>>(
        Hb, W2b + (size_t)layer * 1048576, nullptr, Y2, Y2B, nullptr,
        nullptr, 4, DM, 2048);
    ln_k<<<M, 128, 0, stream>>>(X, Y2, Y2B, b2 + layer * DM,
                                ln2_g + layer * DM, ln2_b + layer * DM, X, Xb);

    if (layer == 0) {
      // distil conv as implicit GEMM, split-K x2; bias folded into bn stats
      mgemm_k<128, 1, 0, 0, 0, 2><<<2 * 4 * 64, 512, 0, stream>>>(
          Xb, Cwb, nullptr, Y2, Y2B, nullptr, nullptr, 4, DM, 1536);
      bn1_k<<<32, 256, 0, stream>>>(Y2, Y2B, conv_b, BNps, BNpq);
      bn2_k<<<1, 512, 0, stream>>>(BNps, BNpq, BNmu, BNvr);
      bnpool_k<<<(NB * 1024 * 512) / 256, 256, 0, stream>>>(
          Y2, Y2B, conv_b, BNmu, BNvr, bn_g, bn_b, X, Xb);
    }
  }

  // final LN + projection (N=32, fp32)
  ln_k<<<NB * 1024, 128, 0, stream>>>(X, nullptr, nullptr, nullptr, normf_g,
                                      normf_b, SCR, nullptr);
  proj_k<<<512, 256, 0, stream>>>(SCR, PWt, proj_b, out);
}

// Round 12
// 600.211 us; speedup vs baseline: 1.0701x; 1.0701x over previous
//
#include <hip/hip_runtime.h>
#include <cstdint>
#include <cmath>

// ---------------------------------------------------------------------------
// Informer encoder forward (B=4, L=2048, ENC_IN=32, D_MODEL=512, D_FF=2048,
// E_LAYERS=2, H=8, FACTOR=5).
// Round 28: revert R27 (TM=256 wide GEMMs: 61us @ Occ 39% vs 42us @ 45%;
// LDS 72KB caps 2 blocks/CU vs 3 for TM=128 — occupancy loss > read-ratio
// gain; LDS-side GEMM attack now falsified in both regimes R22/R25/R26/R27).
// Back to the measured-best 601us config (R26 body, TM=128 everywhere).
// One orthogonal micro-fix: pe_k was 1M libm sinf/cosf (slow large-arg
// range reduction); now 524K threads computing (sin,cos) pairs via
// __sincosf + __expf, float2 store. PE error ~1e-4 << bf16 rounding.
// ---------------------------------------------------------------------------

#define NB 4
#define DM 512
#define NH 8
#define HD 64
#define QS 1536  // QKV row stride

typedef unsigned short ushort_t;
typedef __bf16 bf16x8 __attribute__((ext_vector_type(8)));
typedef float floatx4 __attribute__((ext_vector_type(4)));
typedef unsigned short ushort8_t __attribute__((ext_vector_type(8)));

__device__ inline ushort_t f2b(float f) {
  uint32_t u = __float_as_uint(f);
  uint32_t r = (u + 0x7fffu + ((u >> 16) & 1u)) >> 16;
  return (ushort_t)r;
}
__device__ inline float b2f(ushort_t u) {
  return __uint_as_float((uint32_t)u << 16);
}

// ---------------- fused weight casts ---------------------------------------
__global__ void castqkv_k(const float* __restrict__ Wq,
                          const float* __restrict__ Wk,
                          const float* __restrict__ Wv,
                          ushort_t* __restrict__ out) {
  int gid = blockIdx.x * 256 + threadIdx.x;  // 393216 float4 units
  if (gid >= 393216) return;
  int ly = gid / 196608, r4 = gid - ly * 196608;
  int r = r4 >> 7, c4 = r4 & 127;
  int sel = r >> 9, srow = r & 511;
  const float* src = (sel == 0 ? Wq : sel == 1 ? Wk : Wv) + ly * 262144 +
                     srow * 512 + c4 * 4;
  float4 v = *(const float4*)src;
  ushort4 o;
  o.x = f2b(v.x); o.y = f2b(v.y); o.z = f2b(v.z); o.w = f2b(v.w);
  ((ushort4*)out)[ly * 196608 + r * 128 + c4] = o;
}

__global__ void castw3_k(const float* __restrict__ Wo,
                         const float* __restrict__ W1,
                         const float* __restrict__ W2,
                         const float* __restrict__ tw,
                         ushort_t* __restrict__ oWo, ushort_t* __restrict__ oW1,
                         ushort_t* __restrict__ oW2, ushort_t* __restrict__ otw) {
  int gid = blockIdx.x * 256 + threadIdx.x;  // 1,191,936 float4 units
  if (gid >= 1191936) return;
  const float* src;
  ushort4* dst;
  int i;
  if (gid < 131072) { src = Wo; dst = (ushort4*)oWo; i = gid; }
  else if (gid < 655360) { src = W1; dst = (ushort4*)oW1; i = gid - 131072; }
  else if (gid < 1179648) { src = W2; dst = (ushort4*)oW2; i = gid - 655360; }
  else { src = tw; dst = (ushort4*)otw; i = gid - 1179648; }
  float4 v = ((const float4*)src)[i];
  ushort4 o;
  o.x = f2b(v.x); o.y = f2b(v.y); o.z = f2b(v.z); o.w = f2b(v.w);
  dst[i] = o;
}

// conv weight: (D, I, 3) -> bf16 (D, 3, I) so implicit-GEMM staging is
// contiguous in the input channel dim
__global__ void castw_conv_k(const float* __restrict__ in,
                             ushort_t* __restrict__ out) {
  int gid = blockIdx.x * 256 + threadIdx.x;  // 512*1536
  int d = gid / 1536, r = gid - d * 1536;
  int t = r >> 9, i = r & 511;
  out[gid] = f2b(in[d * 1536 + i * 3 + t]);
}

// final projection weight: (32, 512) -> fp32 (512, 32)
__global__ void castproj_k(const float* __restrict__ w,
                           float* __restrict__ wt) {
  int gid = blockIdx.x * 256 + threadIdx.x;  // 16384
  int k = gid >> 5, n = gid & 31;
  wt[gid] = w[n * 512 + k];
}

__global__ void setup_small_k(const float* __restrict__ bq,
                              const float* __restrict__ bk,
                              const float* __restrict__ bv,
                              float* __restrict__ ZB,
                              float* __restrict__ BQKV) {
  int gid = blockIdx.x * 256 + threadIdx.x;  // 3584
  if (gid >= 3584) return;
  if (gid < 512) { ZB[gid] = 0.f; return; }
  int g = gid - 512;
  int layer = g / 1536, r = g - layer * 1536;
  float v;
  if (r < 512) v = bq[layer * 512 + r];
  else if (r < 1024) v = bk[layer * 512 + r - 512];
  else v = bv[layer * 512 + r - 1024];
  BQKV[g] = v;
}

__host__ __device__ inline void threefry2x32(uint32_t k0, uint32_t k1,
                                             uint32_t c0, uint32_t c1,
                                             uint32_t* o0, uint32_t* o1) {
  uint32_t ks0 = k0, ks1 = k1, ks2 = k0 ^ k1 ^ 0x1BD11BDAu;
  uint32_t x0 = c0 + ks0;
  uint32_t x1 = c1 + ks1;
  const uint32_t rotA[4] = {13u, 15u, 26u, 6u};
  const uint32_t rotB[4] = {17u, 29u, 16u, 24u};
  uint32_t ks[3] = {ks0, ks1, ks2};
  #pragma unroll
  for (int i = 0; i < 5; ++i) {
    const uint32_t* r = (i & 1) ? rotB : rotA;
    #pragma unroll
    for (int j = 0; j < 4; ++j) {
      x0 += x1;
      x1 = (x1 << r[j]) | (x1 >> (32u - r[j]));
      x1 ^= x0;
    }
    x0 += ks[(i + 1) % 3];
    x1 += ks[(i + 2) % 3] + (uint32_t)(i + 1);
  }
  *o0 = x0; *o1 = x1;
}

__global__ void gen_idx_k(int* __restrict__ idx, int n, int mask,
                          uint32_t k0, uint32_t k1) {
  int i = blockIdx.x * 256 + threadIdx.x;
  if (i < n) {
    uint32_t o0, o1;
    threefry2x32(k0, k1, 0u, (uint32_t)i, &o0, &o1);
    idx[i] = (int)((o0 ^ o1) & (uint32_t)mask);
  }
}

__device__ inline float wave_sum64(float v) {
  #pragma unroll
  for (int o = 32; o > 0; o >>= 1) v += __shfl_xor(v, o, 64);
  return v;
}

// ---------------- positional-encoding table (2048 x 512) -------------------
// 524288 (sin,cos) pairs; __sincosf fast path (err ~1e-4 << bf16 rounding).
__global__ void pe_k(float* __restrict__ pe) {
  int i = blockIdx.x * 256 + threadIdx.x;  // 524,288 pairs
  int d2 = i & 255, l = i >> 8;
  float div = __expf((float)(2 * d2) * -1.7988946039e-2f);  // -ln(10000)/512
  float ang = (float)l * div;
  float s, c;
  __sincosf(ang, &s, &c);
  ((float2*)pe)[i] = make_float2(s, c);
}

// ---------------- im2col for token conv: (B*L, 96) bf16 --------------------
__global__ void im2col_tok_k(const float* __restrict__ xe,
                             ushort_t* __restrict__ A) {
  int gid = blockIdx.x * 256 + threadIdx.x;  // 8192*96
  int col = gid % 96;
  int row = gid / 96;
  int c = col / 3, t = col - c * 3;
  int b = row >> 11, l = row & 2047;
  int ls = (l + t - 1) & 2047;
  A[gid] = f2b(xe[((size_t)b * 2048 + ls) * 32 + c]);
}

// ---------------- bf16 MFMA GEMM: TM=128, in-row swizzle, counted vmcnt ----
__device__ inline void gload16(const ushort_t* g, ushort_t* l) {
  __builtin_amdgcn_global_load_lds(
      (const __attribute__((address_space(1))) unsigned int*)(const void*)g,
      (__attribute__((address_space(3))) unsigned int*)(void*)l, 16, 0, 0);
}

// CONV: A is Xb (B*L x 512 bf16); logical A[row][k] = Xb[(row_b, (l+t-1)%2048)][c]
// with t = k/512, c = k%512. Otherwise plain row-major A (M x K).
// LDS tile layout: 16-row blocks, row stride 64B; within a row the four 16B
// chunks are stored at position c ^ ((row>>1)&3) (in-segment swizzle; global
// coalescing preserved since the permutation stays inside the 64B segment).
// SPLITK==2: gridDim.x = 2*nb; blocks id>=nb handle the upper K half; both
// halves write RAW fp32 partials to Cf / Cf2; consumers reduce.
template <int TM, int CONV, int GELU, int OMODE, int ADDPE, int SPLITK>
__global__ __launch_bounds__(512, 4) void mgemm_k(
    const ushort_t* __restrict__ A, const ushort_t* __restrict__ W,
    const float* __restrict__ bias, float* __restrict__ Cf,
    float* __restrict__ Cf2, ushort_t* __restrict__ Cb,
    const float* __restrict__ pe, int X, int ldc, int K) {
  constexpr int MT = TM / 64;        // acc row-tiles per wave (2 or 4)
  constexpr int AG = TM / 128;       // A gloads per wave per K-step (1 or 2)
  constexpr int BUFSZ = (TM + 128) * 32;  // ushorts per staging buffer
  constexpr int SHSZ = (3 * BUFSZ > 18432) ? 3 * BUFSZ : 18432;
  __shared__ __align__(16) ushort_t SH[SHSZ];
  int id = blockIdx.x;
  int half = 0;
  if (SPLITK == 2) {
    int nb = gridDim.x >> 1;
    if (id >= nb) { half = 1; id -= nb; }
  }
  int kbase = half * (K >> 1);
  int KK = (SPLITK == 2) ? (K >> 1) : K;
  int cc = id & 7, j = id >> 3;
  int bx = j % X;
  int by = (j / X) * 8 + cc;
  int m0 = by * TM, n0 = bx * 128;
  int t = threadIdx.x;
  int lane = t & 63, wv = t >> 6;  // 8 waves
  int rl = lane >> 2;
  int cl = ((lane & 3) ^ ((rl >> 1) & 3)) * 8;  // in-segment chunk swizzle
  int RaA = wv * (16 * AG);  // A rows staged per wave
  int RaB = wv * 16;         // B rows staged per wave
  const ushort_t* gA[AG];
  int cbv[AG], clrv[AG], lAoff[AG];
  #pragma unroll
  for (int g = 0; g < AG; ++g) {
    int ar = m0 + RaA + g * 16 + rl;
    gA[g] = A + (size_t)ar * K + kbase + cl;  // non-CONV path
    cbv[g] = ar >> 11;                        // CONV: batch
    clrv[g] = ar & 2047;                      // CONV: seq pos
    lAoff[g] = (RaA + g * 16) * 32;
  }
  const ushort_t* gB = W + (size_t)(n0 + RaB + rl) * K + kbase + cl;
  int lBoff = TM * 32 + RaB * 32;

  int quad = lane >> 4, lr = lane & 15;
  int qs = (quad ^ ((lr >> 1) & 3)) * 8;  // swizzled read chunk offset
  int wm = wv >> 1, wn = wv & 1;  // 4 (M) x 2 (N) waves, (TM/4)x64 each

  // stage K-step kst into LDS buffer buf (AG+1 vmem instructions per wave)
  auto STAGE = [&](int kst, int buf) {
    int bb = buf * BUFSZ;
    int ko = kst << 5;
    #pragma unroll
    for (int g = 0; g < AG; ++g) {
      if (CONV) {
        int kg = kbase + ko;
        int tt = kg >> 9;
        int c = (kg & 511) + cl;
        int ls = (clrv[g] + tt - 1) & 2047;
        gload16(A + ((size_t)(cbv[g] * 2048 + ls) * 512 + c),
                SH + bb + lAoff[g]);
      } else {
        gload16(gA[g] + ko, SH + bb + lAoff[g]);
      }
    }
    gload16(gB + ko, SH + bb + lBoff);
  };

  floatx4 acc[MT][4] = {};
  int nt = KK >> 5;
  STAGE(0, 0);
  if (nt > 1) STAGE(1, 1);
  int cur = 0;
  for (int it = 0; it < nt; ++it) {
    // counted wait: own stage(it) complete; stage(it+1) stays in flight
    if (it < nt - 1) {
      if constexpr (AG == 1)
        asm volatile("s_waitcnt vmcnt(2)" ::: "memory");
      else
        asm volatile("s_waitcnt vmcnt(3)" ::: "memory");
    } else {
      asm volatile("s_waitcnt vmcnt(0)" ::: "memory");
    }
    __builtin_amdgcn_s_barrier();        // all waves: stage(it) landed,
    __builtin_amdgcn_sched_barrier(0);   // prior-iter reads retired
    int nx = it + 2;
    if (nx < nt) {
      int nb3 = cur + 2;
      if (nb3 >= 3) nb3 -= 3;
      STAGE(nx, nb3);                    // buf last read at it-1: safe
    }
    const ushort_t* Ab = SH + cur * BUFSZ;
    const ushort_t* Bb = Ab + TM * 32;
    bf16x8 av[MT], bv[4];
    #pragma unroll
    for (int mt = 0; mt < MT; ++mt)
      av[mt] =
          *(const bf16x8*)&Ab[(wm * (16 * MT) + mt * 16 + lr) * 32 + qs];
    #pragma unroll
    for (int nt2 = 0; nt2 < 4; ++nt2)
      bv[nt2] = *(const bf16x8*)&Bb[(wn * 64 + nt2 * 16 + lr) * 32 + qs];
    #pragma unroll
    for (int mt = 0; mt < MT; ++mt)
      #pragma unroll
      for (int nt2 = 0; nt2 < 4; ++nt2)
        acc[mt][nt2] = __builtin_amdgcn_mfma_f32_16x16x32_bf16(
            av[mt], bv[nt2], acc[mt][nt2], 0, 0, 0);
    // all my LDS reads retired before next barrier (closes WAR window)
    asm volatile("s_waitcnt lgkmcnt(0)" ::: "memory");
    __builtin_amdgcn_sched_barrier(0);
    cur = (cur == 2) ? 0 : cur + 1;
  }
  __syncthreads();  // epilogue reuses SH

  if (SPLITK == 2) {
    // raw fp32 partial; bias applied by the consumer
    float* dst = half ? Cf2 : Cf;
    #pragma unroll
    for (int nt2 = 0; nt2 < 4; ++nt2) {
      int col = n0 + wn * 64 + nt2 * 16 + lr;
      #pragma unroll
      for (int mt = 0; mt < MT; ++mt) {
        int row0 = m0 + wm * (16 * MT) + mt * 16 + quad * 4;
        #pragma unroll
        for (int r = 0; r < 4; ++r)
          dst[(size_t)(row0 + r) * ldc + col] = acc[mt][nt2][r];
      }
    }
  } else if (OMODE == 0) {
    #pragma unroll
    for (int nt2 = 0; nt2 < 4; ++nt2) {
      int col = n0 + wn * 64 + nt2 * 16 + lr;
      float bsv = bias[col];
      #pragma unroll
      for (int mt = 0; mt < MT; ++mt) {
        int row0 = m0 + wm * (16 * MT) + mt * 16 + quad * 4;
        #pragma unroll
        for (int r = 0; r < 4; ++r) {
          int row = row0 + r;
          float v = acc[mt][nt2][r] + bsv;
          if (ADDPE) v += pe[(size_t)(row & 2047) * ldc + col];
          if (GELU) v = 0.5f * v * (1.0f + erff(v * 0.70710678118654752f));
          Cf[(size_t)row * ldc + col] = v;
        }
      }
    }
  } else {
    // bf16 through per-wave LDS transpose -> coalesced ushort8 stores.
    ushort_t* ep = SH + wv * 2304;
    #pragma unroll
    for (int p = 0; p < MT / 2; ++p) {
      #pragma unroll
      for (int nt2 = 0; nt2 < 4; ++nt2) {
        int col = n0 + wn * 64 + nt2 * 16 + lr;
        float bsv = bias[col];
        #pragma unroll
        for (int ml = 0; ml < 2; ++ml) {
          int mt = p * 2 + ml;
          #pragma unroll
          for (int r = 0; r < 4; ++r) {
            int row = m0 + wm * (16 * MT) + mt * 16 + quad * 4 + r;
            float v = acc[mt][nt2][r] + bsv;
            if (ADDPE) v += pe[(size_t)(row & 2047) * ldc + col];
            if (GELU) v = 0.5f * v * (1.0f + erff(v * 0.70710678118654752f));
            if (OMODE == 2) Cf[(size_t)row * ldc + col] = v;
            ep[(ml * 16 + quad * 4 + r) * 72 + nt2 * 16 + lr] = f2b(v);
          }
        }
      }
      int r8 = lane >> 3, c8 = (lane & 7) * 8;
      #pragma unroll
      for (int i = 0; i < 4; ++i) {
        int row = i * 8 + r8;
        ushort8_t vv = *(const ushort8_t*)&ep[row * 72 + c8];
        *(ushort8_t*)&Cb[(size_t)(m0 + wm * (16 * MT) + p * 32 + row) * ldc +
                         n0 + wn * 64 + c8] = vv;
      }
    }
  }
}

// ---------------- final projection (M=4096, N=32, K=512, fp32) -------------
__global__ __launch_bounds__(256) void proj_k(
    const float* __restrict__ A, const float* __restrict__ Wt,
    const float* __restrict__ bias, float* __restrict__ C) {
  int t = threadIdx.x;
  int n = t & 31, ml = t >> 5;
  int m = blockIdx.x * 8 + ml;
  const float* a = A + (size_t)m * DM;
  float a0 = 0.f, a1 = 0.f, a2 = 0.f, a3 = 0.f;
  #pragma unroll 4
  for (int k = 0; k < DM; k += 4) {
    float4 av = *(const float4*)&a[k];
    a0 += av.x * Wt[k * 32 + n];
    a1 += av.y * Wt[(k + 1) * 32 + n];
    a2 += av.z * Wt[(k + 2) * 32 + n];
    a3 += av.w * Wt[(k + 3) * 32 + n];
  }
  C[(size_t)m * 32 + n] = (a0 + a2) + (a1 + a3) + bias[n];
}

// ---------------- LayerNorm (+residuals, +col bias, +optional bf16 copy) ---
// O = LN(A + Bres + Bres2 + cbias) * g + be; Bres/Bres2/cbias nullable.
__global__ __launch_bounds__(128) void ln_k(
    const float* __restrict__ A, const float* __restrict__ Bres,
    const float* __restrict__ Bres2, const float* __restrict__ cbias,
    const float* __restrict__ g, const float* __restrict__ be,
    float* __restrict__ O, ushort_t* __restrict__ Ob) {
  int r = blockIdx.x, t = threadIdx.x;
  __shared__ float lds[2];
  float4 v = ((const float4*)(A + (size_t)r * DM))[t];
  if (Bres) {
    float4 u = ((const float4*)(Bres + (size_t)r * DM))[t];
    v.x += u.x; v.y += u.y; v.z += u.z; v.w += u.w;
  }
  if (Bres2) {
    float4 u = ((const float4*)(Bres2 + (size_t)r * DM))[t];
    v.x += u.x; v.y += u.y; v.z += u.z; v.w += u.w;
  }
  if (cbias) {
    float4 u = ((const float4*)cbias)[t];
    v.x += u.x; v.y += u.y; v.z += u.z; v.w += u.w;
  }
  float s = wave_sum64(v.x + v.y + v.z + v.w);
  int w = t >> 6;
  if ((t & 63) == 0) lds[w] = s;
  __syncthreads();
  float mu = (lds[0] + lds[1]) * (1.0f / 512.0f);
  __syncthreads();
  float dx = v.x - mu, dy = v.y - mu, dz = v.z - mu, dw = v.w - mu;
  float sq = wave_sum64(dx * dx + dy * dy + dz * dz + dw * dw);
  if ((t & 63) == 0) lds[w] = sq;
  __syncthreads();
  float var = (lds[0] + lds[1]) * (1.0f / 512.0f);
  float inv = 1.0f / sqrtf(var + 1e-5f);
  float4 gv = ((const float4*)g)[t];
  float4 bv = ((const float4*)be)[t];
  float4 o;
  o.x = dx * inv * gv.x + bv.x;
  o.y = dy * inv * gv.y + bv.y;
  o.z = dz * inv * gv.z + bv.z;
  o.w = dw * inv * gv.w + bv.w;
  ((float4*)(O + (size_t)r * DM))[t] = o;
  if (Ob) {
    ushort4 ob;
    ob.x = f2b(o.x); ob.y = f2b(o.y); ob.z = f2b(o.z); ob.w = f2b(o.w);
    ((ushort4*)(Ob + (size_t)r * DM))[t] = ob;
  }
}

// ---------------- M[b,h,l]: one wave per (b,l), all-bf16 QKV ---------------
template <int UU>
__global__ __launch_bounds__(256) void qk_m_k(
    const ushort_t* __restrict__ QKVb, const int* __restrict__ idx,
    float* __restrict__ Mout, int Lx) {
  int l = blockIdx.x;
  int b = threadIdx.x >> 6;  // wave = batch
  int lane = threadIdx.x & 63;
  const ushort_t* qp = QKVb + ((size_t)b * Lx + l) * QS + lane * 8;
  float q[8];
  {
    ushort8_t qv = *(const ushort8_t*)qp;
    #pragma unroll
    for (int c = 0; c < 8; ++c) q[c] = b2f(qv[c]);
  }
  const ushort_t* Kbase = QKVb + (size_t)b * Lx * QS + 512 + lane * 8;
  const int* ip = idx + (size_t)l * UU;
  float maxv = -INFINITY, sumv = 0.f;
  #pragma unroll
  for (int u0 = 0; u0 < UU; u0 += 8) {
    ushort8_t kv[8];
    #pragma unroll
    for (int j = 0; j < 8; ++j) {
      if (u0 + j < UU)
        kv[j] = *(const ushort8_t*)(Kbase + (size_t)ip[u0 + j] * QS);
    }
    #pragma unroll
    for (int j = 0; j < 8; ++j) {
      if (u0 + j < UU) {
        float p = 0.f;
        #pragma unroll
        for (int c = 0; c < 8; ++c) p += q[c] * b2f(kv[j][c]);
        p += __shfl_xor(p, 1, 64);
        p += __shfl_xor(p, 2, 64);
        p += __shfl_xor(p, 4, 64);
        maxv = fmaxf(maxv, p);
        sumv += p;
      }
    }
  }
  if ((lane & 7) == 0) {
    int h = lane >> 3;
    Mout[(size_t)(b * 8 + h) * Lx + l] = maxv - sumv / (float)Lx;
  }
}

// ---------------- rank-based top-U, 4-way scan split (JAX tie-break) -------
__global__ __launch_bounds__(1024) void topk_k(
    const float* __restrict__ Mbuf, int* __restrict__ Mtop, int Lx, int U) {
  int nch = Lx >> 8;
  int bh = blockIdx.x / nch, ch = blockIdx.x % nch;
  const float* m = Mbuf + (size_t)bh * Lx;
  __shared__ float sm[2048];
  __shared__ int part[1024];
  int t = threadIdx.x;
  int c = t & 255, q = t >> 8;
  for (int i = t; i < Lx; i += 1024) sm[i] = m[i];
  __syncthreads();
  int i0 = (ch << 8) + c;
  float v0 = sm[i0];
  int r0 = 0;
  int qlen = Lx >> 2;
  int j0 = q * qlen, j1 = j0 + qlen;
  for (int j = j0; j < j1; j += 4) {
    float4 mj = *(const float4*)&sm[j];
    r0 += (mj.x > v0) || (mj.x == v0 && (j + 0) < i0);
    r0 += (mj.y > v0) || (mj.y == v0 && (j + 1) < i0);
    r0 += (mj.z > v0) || (mj.z == v0 && (j + 2) < i0);
    r0 += (mj.w > v0) || (mj.w == v0 && (j + 3) < i0);
  }
  part[t] = r0;
  __syncthreads();
  if (q == 0) {
    int r = part[c] + part[c + 256] + part[c + 512] + part[c + 768];
    if (r < U) Mtop[bh * U + r] = i0;
  }
}

// ---------------- meanV from bf16 QKV (V at +1024) -------------------------
__global__ __launch_bounds__(512) void meanv1_k(const ushort_t* __restrict__ QKVb,
                                                float* __restrict__ part,
                                                int Lx) {
  int b = blockIdx.x >> 4, chunk = blockIdx.x & 15;
  int rows = Lx >> 4;
  int t = threadIdx.x;  // 512
  const ushort_t* vp =
      QKVb + ((size_t)b * Lx + (size_t)chunk * rows) * QS + 1024 + t;
  float s = 0.f;
  for (int l = 0; l < rows; ++l) s += b2f(vp[(size_t)l * QS]);
  part[(size_t)blockIdx.x * DM + t] = s;
}
__global__ __launch_bounds__(512) void meanv2_k(const float* __restrict__ part,
                                                float* __restrict__ mv,
                                                int Lx) {
  int b = blockIdx.x, t = threadIdx.x;
  float s = 0.f;
  #pragma unroll
  for (int c = 0; c < 16; ++c) s += part[(size_t)(b * 16 + c) * DM + t];
  mv[b * DM + t] = s / (float)Lx;
}

__global__ void fillctx_k(ushort_t* __restrict__ ctx,
                          const float* __restrict__ mv, int Lx) {
  size_t i4 = (size_t)blockIdx.x * 256 + threadIdx.x;
  int col4 = (int)(i4 & 127);
  size_t row = i4 >> 7;
  int b = (int)(row / (size_t)Lx);
  const float* m = mv + b * DM + col4 * 4;
  ushort4 o;
  o.x = f2b(m[0]); o.y = f2b(m[1]); o.z = f2b(m[2]); o.w = f2b(m[3]);
  ((ushort4*)ctx)[i4] = o;
}

// ---------------- one-shot MFMA attention (wave = one 64-key chunk) --------
template <int UP>  // padded query count (48 >= U)
__global__ __launch_bounds__(256) void attn_mfma_k(
    const ushort_t* __restrict__ QKVb, const int* __restrict__ Mtop,
    float* __restrict__ part, int Lx, int U, int nblk) {
  __shared__ ushort_t Ps[4][UP * 72];   // P transpose buf (stride 72 elems)
  __shared__ ushort_t Vs[4][64 * 64];   // V tile, xor-swizzled
  int bh = blockIdx.x / nblk, blkc = blockIdx.x % nblk;
  int h = bh & 7, b = bh >> 3;
  int t = threadIdx.x;
  int wv = t >> 6, lane = t & 63;
  int quad = lane >> 4, lr = lane & 15;
  int chunk = blkc * 4 + wv;
  int k0 = chunk * 64;
  const ushort_t* Qb = QKVb + (size_t)b * Lx * QS + h * HD;
  const ushort_t* Kb = Qb + 512;
  const ushort_t* Vb = Qb + 1024;

  // Q fragments: rows gathered via Mtop (clamped for padded rows)
  bf16x8 qf[3][2];
  #pragma unroll
  for (int mt = 0; mt < 3; ++mt) {
    int u = mt * 16 + lr;
    int qi = Mtop[bh * U + (u < U ? u : U - 1)];
    const ushort_t* qp = Qb + (size_t)qi * QS + quad * 8;
    qf[mt][0] = *(const bf16x8*)qp;
    qf[mt][1] = *(const bf16x8*)(qp + 32);
  }

  // stage V tile (64 rows x 64 d), xor-swizzle so column reads are
  // conflict-free: elem addr = k*64 + (d ^ (((k>>3)&3)<<4))
  ushort_t* vs = Vs[wv];
  #pragma unroll
  for (int i = 0; i < 8; ++i) {
    int cid = i * 64 + lane;
    int k = cid >> 3, c = cid & 7;
    ushort8_t v = *(const ushort8_t*)(Vb + (size_t)(k0 + k) * QS + c * 8);
    *(ushort8_t*)&vs[k * 64 + ((c * 8) ^ (((k >> 3) & 3) << 4))] = v;
  }

  // S = Q K^T (K frags direct from global)
  floatx4 Sa[3][4] = {};
  #pragma unroll
  for (int kt = 0; kt < 4; ++kt) {
    const ushort_t* kp = Kb + (size_t)(k0 + kt * 16 + lr) * QS + quad * 8;
    bf16x8 kf0 = *(const bf16x8*)kp;
    bf16x8 kf1 = *(const bf16x8*)(kp + 32);
    #pragma unroll
    for (int mt = 0; mt < 3; ++mt) {
      Sa[mt][kt] = __builtin_amdgcn_mfma_f32_16x16x32_bf16(
          qf[mt][0], kf0, Sa[mt][kt], 0, 0, 0);
      Sa[mt][kt] = __builtin_amdgcn_mfma_f32_16x16x32_bf16(
          qf[mt][1], kf1, Sa[mt][kt], 0, 0, 0);
    }
  }

  // softmax over the 64 local keys (rows u = mt*16 + quad*4 + r, col = lr)
  float m_[3][4], l_[3][4];
  #pragma unroll
  for (int mt = 0; mt < 3; ++mt) {
    #pragma unroll
    for (int kt = 0; kt < 4; ++kt) Sa[mt][kt] *= 0.125f;
    #pragma unroll
    for (int r = 0; r < 4; ++r) {
      float mx = fmaxf(fmaxf(Sa[mt][0][r], Sa[mt][1][r]),
                       fmaxf(Sa[mt][2][r], Sa[mt][3][r]));
      #pragma unroll
      for (int o = 1; o <= 8; o <<= 1) mx = fmaxf(mx, __shfl_xor(mx, o, 64));
      float rs = 0.f;
      #pragma unroll
      for (int kt = 0; kt < 4; ++kt) {
        float e = __expf(Sa[mt][kt][r] - mx);
        Sa[mt][kt][r] = e;
        rs += e;
      }
      #pragma unroll
      for (int o = 1; o <= 8; o <<= 1) rs += __shfl_xor(rs, o, 64);
      m_[mt][r] = mx;
      l_[mt][r] = rs;
    }
  }

  // PV in bf16 hi+lo (near-fp32 accuracy). P transposed via per-wave LDS.
  ushort_t* ps = Ps[wv];
  floatx4 Oa[3][4] = {};
  #pragma unroll
  for (int pass = 0; pass < 2; ++pass) {
    #pragma unroll
    for (int mt = 0; mt < 3; ++mt)
      #pragma unroll
      for (int kt = 0; kt < 4; ++kt)
        #pragma unroll
        for (int r = 0; r < 4; ++r) {
          float e = Sa[mt][kt][r];
          ushort_t hb = f2b(e);
          ps[(mt * 16 + quad * 4 + r) * 72 + kt * 16 + lr] = hb;
          Sa[mt][kt][r] = e - b2f(hb);  // residual for lo pass
        }
    #pragma unroll
    for (int kk = 0; kk < 2; ++kk) {
      bf16x8 pf[3];
      #pragma unroll
      for (int mt = 0; mt < 3; ++mt)
        pf[mt] = *(const bf16x8*)&ps[(mt * 16 + lr) * 72 + kk * 32 + quad * 8];
      #pragma unroll
      for (int nt = 0; nt < 4; ++nt) {
        ushort8_t vt;
        #pragma unroll
        for (int j = 0; j < 8; ++j)
          vt[j] = vs[(kk * 32 + quad * 8 + j) * 64 +
                     ((nt * 16 + lr) ^ (quad << 4))];
        bf16x8 vf = *(bf16x8*)&vt;
        #pragma unroll
        for (int mt = 0; mt < 3; ++mt)
          Oa[mt][nt] = __builtin_amdgcn_mfma_f32_16x16x32_bf16(
              pf[mt], vf, Oa[mt][nt], 0, 0, 0);
      }
    }
  }

  // store partial (u < U only; format matches attn_merge_k)
  float* pb = part + (size_t)(bh * (nblk * 4) + chunk) * U * 66;
  #pragma unroll
  for (int mt = 0; mt < 3; ++mt) {
    #pragma unroll
    for (int r = 0; r < 4; ++r) {
      int u = mt * 16 + quad * 4 + r;
      if (u < U) {
        #pragma unroll
        for (int nt = 0; nt < 4; ++nt)
          pb[(size_t)u * 66 + nt * 16 + lr] = Oa[mt][nt][r];
        if (lr == 0) {
          pb[(size_t)u * 66 + 64] = m_[mt][r];
          pb[(size_t)u * 66 + 65] = l_[mt][r];
        }
      }
    }
  }
}

__global__ __launch_bounds__(64) void attn_merge_k(
    const float* __restrict__ part, const int* __restrict__ Mtop,
    ushort_t* __restrict__ ctx, int Lx, int U, int nchunk) {
  int bu = blockIdx.x;
  int u = bu % U, bh = bu / U;
  int h = bh & 7, b = bh >> 3;
  int d = threadIdx.x;  // 64
  float M = -INFINITY;
  for (int c = 0; c < nchunk; ++c)
    M = fmaxf(M, part[((size_t)(bh * nchunk + c) * U + u) * 66 + 64]);
  float L = 0.f, O = 0.f;
  for (int c = 0; c < nchunk; ++c) {
    const float* pp = part + ((size_t)(bh * nchunk + c) * U + u) * 66;
    float w = __expf(pp[64] - M);
    L += pp[65] * w;
    O += pp[d] * w;
  }
  int qi = Mtop[bh * U + u];
  ctx[((size_t)b * Lx + qi) * DM + h * HD + d] = f2b(O / L);
}

// ---------------- batch-norm stats over two partials + bias ----------------
__global__ __launch_bounds__(256) void bn1_k(const float* __restrict__ Y0,
                                             const float* __restrict__ Y1,
                                             const float* __restrict__ cb,
                                             float* __restrict__ ps,
                                             float* __restrict__ pq) {
  int blk = blockIdx.x;
  int t = threadIdx.x;
  float cb0 = cb[t], cb1 = cb[t + 256];
  float s0 = 0, q0 = 0, s1 = 0, q1 = 0;
  const float* b0 = Y0 + (size_t)blk * 256 * DM;
  const float* b1 = Y1 + (size_t)blk * 256 * DM;
  for (int r = 0; r < 256; ++r) {
    float a = b0[(size_t)r * DM + t] + b1[(size_t)r * DM + t] + cb0;
    float b = b0[(size_t)r * DM + t + 256] + b1[(size_t)r * DM + t + 256] + cb1;
    s0 += a; q0 += a * a; s1 += b; q1 += b * b;
  }
  ps[blk * DM + t] = s0; ps[blk * DM + t + 256] = s1;
  pq[blk * DM + t] = q0; pq[blk * DM + t + 256] = q1;
}
__global__ __launch_bounds__(512) void bn2_k(const float* __restrict__ ps,
                                             const float* __restrict__ pq,
                                             float* __restrict__ mu,
                                             float* __restrict__ var) {
  int t = threadIdx.x;
  float s = 0, q = 0;
  #pragma unroll
  for (int c = 0; c < 32; ++c) { s += ps[c * DM + t]; q += pq[c * DM + t]; }
  float m = s * (1.0f / 8192.f);
  mu[t] = m;
  var[t] = q * (1.0f / 8192.f) - m * m;
}

// fused bn+elu+maxpool(k=3,s=2,pad=1) over two partials + bias
__global__ void bnpool_k(const float* __restrict__ Y0,
                         const float* __restrict__ Y1,
                         const float* __restrict__ cb,
                         const float* __restrict__ mu,
                         const float* __restrict__ var,
                         const float* __restrict__ g,
                         const float* __restrict__ be, float* __restrict__ O,
                         ushort_t* __restrict__ Ob) {
  size_t i = (size_t)blockIdx.x * 256 + threadIdx.x;  // 4*1024*512
  int c = (int)(i & 511);
  size_t row = i >> 9;
  int lo = (int)(row & 1023);
  int b = (int)(row >> 10);
  float sc = g[c] / sqrtf(var[c] + 1e-5f);
  float sh = be[c] - mu[c] * sc;
  float cbv = cb[c];
  int l0 = 2 * lo - 1;
  float m = -INFINITY;
  #pragma unroll
  for (int tt = 0; tt < 3; ++tt) {
    int l = l0 + tt;
    if (l >= 0 && l < 2048) {
      size_t off = ((size_t)b * 2048 + l) * DM + c;
      float v = (Y0[off] + Y1[off] + cbv) * sc + sh;
      v = v > 0.f ? v : expm1f(v);
      m = fmaxf(m, v);
    }
  }
  O[i] = m;
  Ob[i] = f2b(m);
}

// ---------------------------------------------------------------------------
extern "C" void kernel_launch(void* const* d_in, const int* in_sizes, int n_in,
                              void* d_out, int out_size, void* d_ws,
                              size_t ws_size, hipStream_t stream) {
  (void)in_sizes; (void)n_in; (void)out_size; (void)ws_size;
  const float* x_enc  = (const float*)d_in[0];
  const float* tok_w  = (const float*)d_in[1];
  const float* Wq     = (const float*)d_in[2];
  const float* bq     = (const float*)d_in[3];
  const float* Wk     = (const float*)d_in[4];
  const float* bk     = (const float*)d_in[5];
  const float* Wv     = (const float*)d_in[6];
  const float* bv     = (const float*)d_in[7];
  const float* Wo     = (const float*)d_in[8];
  const float* bo     = (const float*)d_in[9];
  const float* W1     = (const float*)d_in[10];
  const float* b1     = (const float*)d_in[11];
  const float* W2     = (const float*)d_in[12];
  const float* b2     = (const float*)d_in[13];
  const float* ln1_g  = (const float*)d_in[14];
  const float* ln1_b  = (const float*)d_in[15];
  const float* ln2_g  = (const float*)d_in[16];
  const float* ln2_b  = (const float*)d_in[17];
  const float* conv_w = (const float*)d_in[18];
  const float* conv_b = (const float*)d_in[19];
  const float* bn_g   = (const float*)d_in[20];
  const float* bn_b   = (const float*)d_in[21];
  const float* normf_g = (const float*)d_in[22];
  const float* normf_b = (const float*)d_in[23];
  const float* proj_w = (const float*)d_in[24];
  const float* proj_b = (const float*)d_in[25];
  float* out = (float*)d_out;
  float* ws = (float*)d_ws;

  // ---- fp32 workspace layout (float offsets) ----
  float* X    = ws;                    // 4,194,304
  float* Y2B  = ws + 4194304;          // 4,194,304 (split-K partial #2)
  float* SCR  = ws + 8388608;          // 8,388,608 (final-LN scratch)
  ushort_t* CTXb = (ushort_t*)(ws + 16777216);  // bf16 ctx
  float* Y2   = ws + 20971520;         // 4,194,304 (attn partials / partial #1)
  float* Mb   = ws + 25165824;         // 65,536
  float* MV   = ws + 25231360;         // 2,048
  float* MVP  = ws + 25233408;         // 32,768
  float* BNps = ws + 25266176;         // 16,384
  float* BNpq = ws + 25282560;         // 16,384
  float* BNmu = ws + 25298944;         // 512
  float* BNvr = ws + 25299456;         // 512
  float* ZB   = ws + 25299968;         // 512 (zero bias)
  float* BQKV = ws + 25300480;         // 3,072 (concat qkv bias, 2 layers)
  int*   IDX  = (int*)(ws + 25303552); // 81,920
  int*   MT   = (int*)(ws + 25385472); // 1,280
  // ---- bf16 workspace ----
  ushort_t* U0   = (ushort_t*)(ws + 25386752);
  ushort_t* Xb   = U0;                 // 4,194,304
  ushort_t* Hb   = U0 + 4194304;       // 16,777,216 (FFN hidden)
  ushort_t* QKVb = Hb;                 // alias: bf16 QKV — live QKV-GEMM ->
                                       // attn, before FFN uses Hb
  ushort_t* Wqkvb= U0 + 20971520;      // 1,572,864
  ushort_t* Wob  = U0 + 22544384;      // 524,288
  ushort_t* W1b  = U0 + 23068672;      // 2,097,152
  ushort_t* W2b  = U0 + 25165824;      // 2,097,152
  ushort_t* Cwb  = U0 + 27262976;      // 786,432 ([d][t][i] layout)
  ushort_t* Twb  = U0 + 28049408;      // 49,152
  ushort_t* Atok = U0 + 28098560;      // 786,432
  float* PEf = ws + 39829248;          // 1,048,576 (PE table)
  float* PWt = ws + 40877824;          // 16,384 (transposed proj weight)

  // ---- fused preamble ----
  castqkv_k<<<1536, 256, 0, stream>>>(Wq, Wk, Wv, Wqkvb);
  castw3_k<<<4656, 256, 0, stream>>>(Wo, W1, W2, tok_w, Wob, W1b, W2b, Twb);
  castw_conv_k<<<3072, 256, 0, stream>>>(conv_w, Cwb);
  castproj_k<<<64, 256, 0, stream>>>(proj_w, PWt);
  setup_small_k<<<14, 256, 0, stream>>>(bq, bk, bv, ZB, BQKV);
  pe_k<<<2048, 256, 0, stream>>>(PEf);
  im2col_tok_k<<<3072, 256, 0, stream>>>(x_enc, Atok);

  // token embedding GEMM (+PE): K=96
  mgemm_k<128, 0, 0, 2, 1, 1><<<256, 512, 0, stream>>>(
      Atok, Twb, ZB, X, nullptr, Xb, PEf, 4, DM, 96);

  for (int layer = 0; layer < 2; ++layer) {
    const int Lx = (layer == 0) ? 2048 : 1024;
    const int U  = (layer == 0) ? 40 : 35;
    const int M  = NB * Lx;
    const int Yt = M / 128;
    const int NCHT = Lx / 64;          // one 64-key chunk per wave
    const int NBLK = NCHT / 4;         // 4 waves per block

    uint32_t kl0, kl1, s0, s1;
    threefry2x32(0u, 42u, 0u, (uint32_t)layer, &kl0, &kl1);
    threefry2x32(kl0, kl1, 0u, 1u, &s0, &s1);
    int nidx = Lx * U;
    gen_idx_k<<<(nidx + 255) / 256, 256, 0, stream>>>(IDX, nidx, Lx - 1, s0, s1);

    // fused QKV GEMM: bf16-only output
    mgemm_k<128, 0, 0, 1, 0, 1><<<12 * Yt, 512, 0, stream>>>(
        Xb, Wqkvb + (size_t)layer * 786432, BQKV + layer * 1536, nullptr,
        nullptr, QKVb, nullptr, 12, QS, DM);

    // ProbSparse attention (all bf16 QKV)
    if (layer == 0)
      qk_m_k<40><<<Lx, 256, 0, stream>>>(QKVb, IDX, Mb, Lx);
    else
      qk_m_k<35><<<Lx, 256, 0, stream>>>(QKVb, IDX, Mb, Lx);
    topk_k<<<NB * NH * (Lx >> 8), 1024, 0, stream>>>(Mb, MT, Lx, U);
    meanv1_k<<<NB * 16, 512, 0, stream>>>(QKVb, MVP, Lx);
    meanv2_k<<<NB, 512, 0, stream>>>(MVP, MV, Lx);
    fillctx_k<<<(M * DM / 4) / 256, 256, 0, stream>>>(CTXb, MV, Lx);
    attn_mfma_k<48><<<NB * NH * NBLK, 256, 0, stream>>>(QKVb, MT, Y2, Lx, U,
                                                        NBLK);
    attn_merge_k<<<NB * NH * U, 64, 0, stream>>>(Y2, MT, CTXb, Lx, U, NCHT);

    // output projection split-K x2 (raw partials) + residual+bias in LN1
    mgemm_k<128, 0, 0, 0, 0, 2><<<2 * 4 * Yt, 512, 0, stream>>>(
        CTXb, Wob + (size_t)layer * 262144, nullptr, Y2, Y2B, nullptr,
        nullptr, 4, DM, DM);
    ln_k<<<M, 128, 0, stream>>>(X, Y2, Y2B, bo + layer * DM,
                                ln1_g + layer * DM, ln1_b + layer * DM, X, Xb);

    // FFN1 (GELU fused; hidden kept in bf16)
    mgemm_k<128, 0, 1, 1, 0, 1><<<16 * Yt, 512, 0, stream>>>(
        Xb, W1b + (size_t)layer * 1048576, b1 + layer * 2048, nullptr, nullptr,
        Hb, nullptr, 16, 2048, DM);
    // FFN2 split-K x2 (raw partials) + residual+bias in LN2
    mgemm_k<128, 0, 0, 0, 0, 2><<<2 * 4 * Yt, 512, 0, stream>>>(
        Hb, W2b + (size_t)layer * 1048576, nullptr, Y2, Y2B, nullptr,
        nullptr, 4, DM, 2048);
    ln_k<<<M, 128, 0, stream>>>(X, Y2, Y2B, b2 + layer * DM,
                                ln2_g + layer * DM, ln2_b + layer * DM, X, Xb);

    if (layer == 0) {
      // distil conv as implicit GEMM, split-K x2; bias folded into bn stats
      mgemm_k<128, 1, 0, 0, 0, 2><<<2 * 4 * 64, 512, 0, stream>>>(
          Xb, Cwb, nullptr, Y2, Y2B, nullptr, nullptr, 4, DM, 1536);
      bn1_k<<<32, 256, 0, stream>>>(Y2, Y2B, conv_b, BNps, BNpq);
      bn2_k<<<1, 512, 0, stream>>>(BNps, BNpq, BNmu, BNvr);
      bnpool_k<<<(NB * 1024 * 512) / 256, 256, 0, stream>>>(
          Y2, Y2B, conv_b, BNmu, BNvr, bn_g, bn_b, X, Xb);
    }
  }

  // final LN + projection (N=32, fp32)
  ln_k<<<NB * 1024, 128, 0, stream>>>(X, nullptr, nullptr, nullptr, normf_g,
                                      normf_b, SCR, nullptr);
  proj_k<<<512, 256, 0, stream>>>(SCR, PWt, proj_b, out);
}

// Round 13
// 594.797 us; speedup vs baseline: 1.0799x; 1.0091x over previous
//
#include <hip/hip_runtime.h>
#include <cstdint>
#include <cmath>

// ---------------------------------------------------------------------------
// Informer encoder forward (B=4, L=2048, ENC_IN=32, D_MODEL=512, D_FF=2048,
// E_LAYERS=2, H=8, FACTOR=5).
// Round 29: attn_mfma_k occupancy fix. Grid was NB*NH*NBLK = 256 blocks at
// L0 = 1 block/CU x 4 waves = 12.5% occupancy on a latency-bound kernel
// (global K/Q gathers, zero barriers). Waves are fully independent, so:
// 2 waves/block (128 thr), grid doubles (512 @ L0 = 2 blocks/CU), LDS/block
// 60->30 KB. Same math, same per-wave work. Rest = R28 best (600.2 us).
// ---------------------------------------------------------------------------

#define NB 4
#define DM 512
#define NH 8
#define HD 64
#define QS 1536  // QKV row stride

typedef unsigned short ushort_t;
typedef __bf16 bf16x8 __attribute__((ext_vector_type(8)));
typedef float floatx4 __attribute__((ext_vector_type(4)));
typedef unsigned short ushort8_t __attribute__((ext_vector_type(8)));

__device__ inline ushort_t f2b(float f) {
  uint32_t u = __float_as_uint(f);
  uint32_t r = (u + 0x7fffu + ((u >> 16) & 1u)) >> 16;
  return (ushort_t)r;
}
__device__ inline float b2f(ushort_t u) {
  return __uint_as_float((uint32_t)u << 16);
}

// ---------------- fused weight casts ---------------------------------------
__global__ void castqkv_k(const float* __restrict__ Wq,
                          const float* __restrict__ Wk,
                          const float* __restrict__ Wv,
                          ushort_t* __restrict__ out) {
  int gid = blockIdx.x * 256 + threadIdx.x;  // 393216 float4 units
  if (gid >= 393216) return;
  int ly = gid / 196608, r4 = gid - ly * 196608;
  int r = r4 >> 7, c4 = r4 & 127;
  int sel = r >> 9, srow = r & 511;
  const float* src = (sel == 0 ? Wq : sel == 1 ? Wk : Wv) + ly * 262144 +
                     srow * 512 + c4 * 4;
  float4 v = *(const float4*)src;
  ushort4 o;
  o.x = f2b(v.x); o.y = f2b(v.y); o.z = f2b(v.z); o.w = f2b(v.w);
  ((ushort4*)out)[ly * 196608 + r * 128 + c4] = o;
}

__global__ void castw3_k(const float* __restrict__ Wo,
                         const float* __restrict__ W1,
                         const float* __restrict__ W2,
                         const float* __restrict__ tw,
                         ushort_t* __restrict__ oWo, ushort_t* __restrict__ oW1,
                         ushort_t* __restrict__ oW2, ushort_t* __restrict__ otw) {
  int gid = blockIdx.x * 256 + threadIdx.x;  // 1,191,936 float4 units
  if (gid >= 1191936) return;
  const float* src;
  ushort4* dst;
  int i;
  if (gid < 131072) { src = Wo; dst = (ushort4*)oWo; i = gid; }
  else if (gid < 655360) { src = W1; dst = (ushort4*)oW1; i = gid - 131072; }
  else if (gid < 1179648) { src = W2; dst = (ushort4*)oW2; i = gid - 655360; }
  else { src = tw; dst = (ushort4*)otw; i = gid - 1179648; }
  float4 v = ((const float4*)src)[i];
  ushort4 o;
  o.x = f2b(v.x); o.y = f2b(v.y); o.z = f2b(v.z); o.w = f2b(v.w);
  dst[i] = o;
}

// conv weight: (D, I, 3) -> bf16 (D, 3, I) so implicit-GEMM staging is
// contiguous in the input channel dim
__global__ void castw_conv_k(const float* __restrict__ in,
                             ushort_t* __restrict__ out) {
  int gid = blockIdx.x * 256 + threadIdx.x;  // 512*1536
  int d = gid / 1536, r = gid - d * 1536;
  int t = r >> 9, i = r & 511;
  out[gid] = f2b(in[d * 1536 + i * 3 + t]);
}

// final projection weight: (32, 512) -> fp32 (512, 32)
__global__ void castproj_k(const float* __restrict__ w,
                           float* __restrict__ wt) {
  int gid = blockIdx.x * 256 + threadIdx.x;  // 16384
  int k = gid >> 5, n = gid & 31;
  wt[gid] = w[n * 512 + k];
}

__global__ void setup_small_k(const float* __restrict__ bq,
                              const float* __restrict__ bk,
                              const float* __restrict__ bv,
                              float* __restrict__ ZB,
                              float* __restrict__ BQKV) {
  int gid = blockIdx.x * 256 + threadIdx.x;  // 3584
  if (gid >= 3584) return;
  if (gid < 512) { ZB[gid] = 0.f; return; }
  int g = gid - 512;
  int layer = g / 1536, r = g - layer * 1536;
  float v;
  if (r < 512) v = bq[layer * 512 + r];
  else if (r < 1024) v = bk[layer * 512 + r - 512];
  else v = bv[layer * 512 + r - 1024];
  BQKV[g] = v;
}

__host__ __device__ inline void threefry2x32(uint32_t k0, uint32_t k1,
                                             uint32_t c0, uint32_t c1,
                                             uint32_t* o0, uint32_t* o1) {
  uint32_t ks0 = k0, ks1 = k1, ks2 = k0 ^ k1 ^ 0x1BD11BDAu;
  uint32_t x0 = c0 + ks0;
  uint32_t x1 = c1 + ks1;
  const uint32_t rotA[4] = {13u, 15u, 26u, 6u};
  const uint32_t rotB[4] = {17u, 29u, 16u, 24u};
  uint32_t ks[3] = {ks0, ks1, ks2};
  #pragma unroll
  for (int i = 0; i < 5; ++i) {
    const uint32_t* r = (i & 1) ? rotB : rotA;
    #pragma unroll
    for (int j = 0; j < 4; ++j) {
      x0 += x1;
      x1 = (x1 << r[j]) | (x1 >> (32u - r[j]));
      x1 ^= x0;
    }
    x0 += ks[(i + 1) % 3];
    x1 += ks[(i + 2) % 3] + (uint32_t)(i + 1);
  }
  *o0 = x0; *o1 = x1;
}

__global__ void gen_idx_k(int* __restrict__ idx, int n, int mask,
                          uint32_t k0, uint32_t k1) {
  int i = blockIdx.x * 256 + threadIdx.x;
  if (i < n) {
    uint32_t o0, o1;
    threefry2x32(k0, k1, 0u, (uint32_t)i, &o0, &o1);
    idx[i] = (int)((o0 ^ o1) & (uint32_t)mask);
  }
}

__device__ inline float wave_sum64(float v) {
  #pragma unroll
  for (int o = 32; o > 0; o >>= 1) v += __shfl_xor(v, o, 64);
  return v;
}

// ---------------- positional-encoding table (2048 x 512) -------------------
// 524288 (sin,cos) pairs; __sincosf fast path (err ~1e-4 << bf16 rounding).
__global__ void pe_k(float* __restrict__ pe) {
  int i = blockIdx.x * 256 + threadIdx.x;  // 524,288 pairs
  int d2 = i & 255, l = i >> 8;
  float div = __expf((float)(2 * d2) * -1.7988946039e-2f);  // -ln(10000)/512
  float ang = (float)l * div;
  float s, c;
  __sincosf(ang, &s, &c);
  ((float2*)pe)[i] = make_float2(s, c);
}

// ---------------- im2col for token conv: (B*L, 96) bf16 --------------------
__global__ void im2col_tok_k(const float* __restrict__ xe,
                             ushort_t* __restrict__ A) {
  int gid = blockIdx.x * 256 + threadIdx.x;  // 8192*96
  int col = gid % 96;
  int row = gid / 96;
  int c = col / 3, t = col - c * 3;
  int b = row >> 11, l = row & 2047;
  int ls = (l + t - 1) & 2047;
  A[gid] = f2b(xe[((size_t)b * 2048 + ls) * 32 + c]);
}

// ---------------- bf16 MFMA GEMM: TM=128, in-row swizzle, counted vmcnt ----
__device__ inline void gload16(const ushort_t* g, ushort_t* l) {
  __builtin_amdgcn_global_load_lds(
      (const __attribute__((address_space(1))) unsigned int*)(const void*)g,
      (__attribute__((address_space(3))) unsigned int*)(void*)l, 16, 0, 0);
}

// CONV: A is Xb (B*L x 512 bf16); logical A[row][k] = Xb[(row_b, (l+t-1)%2048)][c]
// with t = k/512, c = k%512. Otherwise plain row-major A (M x K).
// LDS tile layout: 16-row blocks, row stride 64B; within a row the four 16B
// chunks are stored at position c ^ ((row>>1)&3) (in-segment swizzle; global
// coalescing preserved since the permutation stays inside the 64B segment).
// SPLITK==2: gridDim.x = 2*nb; blocks id>=nb handle the upper K half; both
// halves write RAW fp32 partials to Cf / Cf2; consumers reduce.
template <int TM, int CONV, int GELU, int OMODE, int ADDPE, int SPLITK>
__global__ __launch_bounds__(512, 4) void mgemm_k(
    const ushort_t* __restrict__ A, const ushort_t* __restrict__ W,
    const float* __restrict__ bias, float* __restrict__ Cf,
    float* __restrict__ Cf2, ushort_t* __restrict__ Cb,
    const float* __restrict__ pe, int X, int ldc, int K) {
  constexpr int MT = TM / 64;        // acc row-tiles per wave (2 or 4)
  constexpr int AG = TM / 128;       // A gloads per wave per K-step (1 or 2)
  constexpr int BUFSZ = (TM + 128) * 32;  // ushorts per staging buffer
  constexpr int SHSZ = (3 * BUFSZ > 18432) ? 3 * BUFSZ : 18432;
  __shared__ __align__(16) ushort_t SH[SHSZ];
  int id = blockIdx.x;
  int half = 0;
  if (SPLITK == 2) {
    int nb = gridDim.x >> 1;
    if (id >= nb) { half = 1; id -= nb; }
  }
  int kbase = half * (K >> 1);
  int KK = (SPLITK == 2) ? (K >> 1) : K;
  int cc = id & 7, j = id >> 3;
  int bx = j % X;
  int by = (j / X) * 8 + cc;
  int m0 = by * TM, n0 = bx * 128;
  int t = threadIdx.x;
  int lane = t & 63, wv = t >> 6;  // 8 waves
  int rl = lane >> 2;
  int cl = ((lane & 3) ^ ((rl >> 1) & 3)) * 8;  // in-segment chunk swizzle
  int RaA = wv * (16 * AG);  // A rows staged per wave
  int RaB = wv * 16;         // B rows staged per wave
  const ushort_t* gA[AG];
  int cbv[AG], clrv[AG], lAoff[AG];
  #pragma unroll
  for (int g = 0; g < AG; ++g) {
    int ar = m0 + RaA + g * 16 + rl;
    gA[g] = A + (size_t)ar * K + kbase + cl;  // non-CONV path
    cbv[g] = ar >> 11;                        // CONV: batch
    clrv[g] = ar & 2047;                      // CONV: seq pos
    lAoff[g] = (RaA + g * 16) * 32;
  }
  const ushort_t* gB = W + (size_t)(n0 + RaB + rl) * K + kbase + cl;
  int lBoff = TM * 32 + RaB * 32;

  int quad = lane >> 4, lr = lane & 15;
  int qs = (quad ^ ((lr >> 1) & 3)) * 8;  // swizzled read chunk offset
  int wm = wv >> 1, wn = wv & 1;  // 4 (M) x 2 (N) waves, (TM/4)x64 each

  // stage K-step kst into LDS buffer buf (AG+1 vmem instructions per wave)
  auto STAGE = [&](int kst, int buf) {
    int bb = buf * BUFSZ;
    int ko = kst << 5;
    #pragma unroll
    for (int g = 0; g < AG; ++g) {
      if (CONV) {
        int kg = kbase + ko;
        int tt = kg >> 9;
        int c = (kg & 511) + cl;
        int ls = (clrv[g] + tt - 1) & 2047;
        gload16(A + ((size_t)(cbv[g] * 2048 + ls) * 512 + c),
                SH + bb + lAoff[g]);
      } else {
        gload16(gA[g] + ko, SH + bb + lAoff[g]);
      }
    }
    gload16(gB + ko, SH + bb + lBoff);
  };

  floatx4 acc[MT][4] = {};
  int nt = KK >> 5;
  STAGE(0, 0);
  if (nt > 1) STAGE(1, 1);
  int cur = 0;
  for (int it = 0; it < nt; ++it) {
    // counted wait: own stage(it) complete; stage(it+1) stays in flight
    if (it < nt - 1) {
      if constexpr (AG == 1)
        asm volatile("s_waitcnt vmcnt(2)" ::: "memory");
      else
        asm volatile("s_waitcnt vmcnt(3)" ::: "memory");
    } else {
      asm volatile("s_waitcnt vmcnt(0)" ::: "memory");
    }
    __builtin_amdgcn_s_barrier();        // all waves: stage(it) landed,
    __builtin_amdgcn_sched_barrier(0);   // prior-iter reads retired
    int nx = it + 2;
    if (nx < nt) {
      int nb3 = cur + 2;
      if (nb3 >= 3) nb3 -= 3;
      STAGE(nx, nb3);                    // buf last read at it-1: safe
    }
    const ushort_t* Ab = SH + cur * BUFSZ;
    const ushort_t* Bb = Ab + TM * 32;
    bf16x8 av[MT], bv[4];
    #pragma unroll
    for (int mt = 0; mt < MT; ++mt)
      av[mt] =
          *(const bf16x8*)&Ab[(wm * (16 * MT) + mt * 16 + lr) * 32 + qs];
    #pragma unroll
    for (int nt2 = 0; nt2 < 4; ++nt2)
      bv[nt2] = *(const bf16x8*)&Bb[(wn * 64 + nt2 * 16 + lr) * 32 + qs];
    #pragma unroll
    for (int mt = 0; mt < MT; ++mt)
      #pragma unroll
      for (int nt2 = 0; nt2 < 4; ++nt2)
        acc[mt][nt2] = __builtin_amdgcn_mfma_f32_16x16x32_bf16(
            av[mt], bv[nt2], acc[mt][nt2], 0, 0, 0);
    // all my LDS reads retired before next barrier (closes WAR window)
    asm volatile("s_waitcnt lgkmcnt(0)" ::: "memory");
    __builtin_amdgcn_sched_barrier(0);
    cur = (cur == 2) ? 0 : cur + 1;
  }
  __syncthreads();  // epilogue reuses SH

  if (SPLITK == 2) {
    // raw fp32 partial; bias applied by the consumer
    float* dst = half ? Cf2 : Cf;
    #pragma unroll
    for (int nt2 = 0; nt2 < 4; ++nt2) {
      int col = n0 + wn * 64 + nt2 * 16 + lr;
      #pragma unroll
      for (int mt = 0; mt < MT; ++mt) {
        int row0 = m0 + wm * (16 * MT) + mt * 16 + quad * 4;
        #pragma unroll
        for (int r = 0; r < 4; ++r)
          dst[(size_t)(row0 + r) * ldc + col] = acc[mt][nt2][r];
      }
    }
  } else if (OMODE == 0) {
    #pragma unroll
    for (int nt2 = 0; nt2 < 4; ++nt2) {
      int col = n0 + wn * 64 + nt2 * 16 + lr;
      float bsv = bias[col];
      #pragma unroll
      for (int mt = 0; mt < MT; ++mt) {
        int row0 = m0 + wm * (16 * MT) + mt * 16 + quad * 4;
        #pragma unroll
        for (int r = 0; r < 4; ++r) {
          int row = row0 + r;
          float v = acc[mt][nt2][r] + bsv;
          if (ADDPE) v += pe[(size_t)(row & 2047) * ldc + col];
          if (GELU) v = 0.5f * v * (1.0f + erff(v * 0.70710678118654752f));
          Cf[(size_t)row * ldc + col] = v;
        }
      }
    }
  } else {
    // bf16 through per-wave LDS transpose -> coalesced ushort8 stores.
    ushort_t* ep = SH + wv * 2304;
    #pragma unroll
    for (int p = 0; p < MT / 2; ++p) {
      #pragma unroll
      for (int nt2 = 0; nt2 < 4; ++nt2) {
        int col = n0 + wn * 64 + nt2 * 16 + lr;
        float bsv = bias[col];
        #pragma unroll
        for (int ml = 0; ml < 2; ++ml) {
          int mt = p * 2 + ml;
          #pragma unroll
          for (int r = 0; r < 4; ++r) {
            int row = m0 + wm * (16 * MT) + mt * 16 + quad * 4 + r;
            float v = acc[mt][nt2][r] + bsv;
            if (ADDPE) v += pe[(size_t)(row & 2047) * ldc + col];
            if (GELU) v = 0.5f * v * (1.0f + erff(v * 0.70710678118654752f));
            if (OMODE == 2) Cf[(size_t)row * ldc + col] = v;
            ep[(ml * 16 + quad * 4 + r) * 72 + nt2 * 16 + lr] = f2b(v);
          }
        }
      }
      int r8 = lane >> 3, c8 = (lane & 7) * 8;
      #pragma unroll
      for (int i = 0; i < 4; ++i) {
        int row = i * 8 + r8;
        ushort8_t vv = *(const ushort8_t*)&ep[row * 72 + c8];
        *(ushort8_t*)&Cb[(size_t)(m0 + wm * (16 * MT) + p * 32 + row) * ldc +
                         n0 + wn * 64 + c8] = vv;
      }
    }
  }
}

// ---------------- final projection (M=4096, N=32, K=512, fp32) -------------
__global__ __launch_bounds__(256) void proj_k(
    const float* __restrict__ A, const float* __restrict__ Wt,
    const float* __restrict__ bias, float* __restrict__ C) {
  int t = threadIdx.x;
  int n = t & 31, ml = t >> 5;
  int m = blockIdx.x * 8 + ml;
  const float* a = A + (size_t)m * DM;
  float a0 = 0.f, a1 = 0.f, a2 = 0.f, a3 = 0.f;
  #pragma unroll 4
  for (int k = 0; k < DM; k += 4) {
    float4 av = *(const float4*)&a[k];
    a0 += av.x * Wt[k * 32 + n];
    a1 += av.y * Wt[(k + 1) * 32 + n];
    a2 += av.z * Wt[(k + 2) * 32 + n];
    a3 += av.w * Wt[(k + 3) * 32 + n];
  }
  C[(size_t)m * 32 + n] = (a0 + a2) + (a1 + a3) + bias[n];
}

// ---------------- LayerNorm (+residuals, +col bias, +optional bf16 copy) ---
// O = LN(A + Bres + Bres2 + cbias) * g + be; Bres/Bres2/cbias nullable.
__global__ __launch_bounds__(128) void ln_k(
    const float* __restrict__ A, const float* __restrict__ Bres,
    const float* __restrict__ Bres2, const float* __restrict__ cbias,
    const float* __restrict__ g, const float* __restrict__ be,
    float* __restrict__ O, ushort_t* __restrict__ Ob) {
  int r = blockIdx.x, t = threadIdx.x;
  __shared__ float lds[2];
  float4 v = ((const float4*)(A + (size_t)r * DM))[t];
  if (Bres) {
    float4 u = ((const float4*)(Bres + (size_t)r * DM))[t];
    v.x += u.x; v.y += u.y; v.z += u.z; v.w += u.w;
  }
  if (Bres2) {
    float4 u = ((const float4*)(Bres2 + (size_t)r * DM))[t];
    v.x += u.x; v.y += u.y; v.z += u.z; v.w += u.w;
  }
  if (cbias) {
    float4 u = ((const float4*)cbias)[t];
    v.x += u.x; v.y += u.y; v.z += u.z; v.w += u.w;
  }
  float s = wave_sum64(v.x + v.y + v.z + v.w);
  int w = t >> 6;
  if ((t & 63) == 0) lds[w] = s;
  __syncthreads();
  float mu = (lds[0] + lds[1]) * (1.0f / 512.0f);
  __syncthreads();
  float dx = v.x - mu, dy = v.y - mu, dz = v.z - mu, dw = v.w - mu;
  float sq = wave_sum64(dx * dx + dy * dy + dz * dz + dw * dw);
  if ((t & 63) == 0) lds[w] = sq;
  __syncthreads();
  float var = (lds[0] + lds[1]) * (1.0f / 512.0f);
  float inv = 1.0f / sqrtf(var + 1e-5f);
  float4 gv = ((const float4*)g)[t];
  float4 bv = ((const float4*)be)[t];
  float4 o;
  o.x = dx * inv * gv.x + bv.x;
  o.y = dy * inv * gv.y + bv.y;
  o.z = dz * inv * gv.z + bv.z;
  o.w = dw * inv * gv.w + bv.w;
  ((float4*)(O + (size_t)r * DM))[t] = o;
  if (Ob) {
    ushort4 ob;
    ob.x = f2b(o.x); ob.y = f2b(o.y); ob.z = f2b(o.z); ob.w = f2b(o.w);
    ((ushort4*)(Ob + (size_t)r * DM))[t] = ob;
  }
}

// ---------------- M[b,h,l]: one wave per (b,l), all-bf16 QKV ---------------
template <int UU>
__global__ __launch_bounds__(256) void qk_m_k(
    const ushort_t* __restrict__ QKVb, const int* __restrict__ idx,
    float* __restrict__ Mout, int Lx) {
  int l = blockIdx.x;
  int b = threadIdx.x >> 6;  // wave = batch
  int lane = threadIdx.x & 63;
  const ushort_t* qp = QKVb + ((size_t)b * Lx + l) * QS + lane * 8;
  float q[8];
  {
    ushort8_t qv = *(const ushort8_t*)qp;
    #pragma unroll
    for (int c = 0; c < 8; ++c) q[c] = b2f(qv[c]);
  }
  const ushort_t* Kbase = QKVb + (size_t)b * Lx * QS + 512 + lane * 8;
  const int* ip = idx + (size_t)l * UU;
  float maxv = -INFINITY, sumv = 0.f;
  #pragma unroll
  for (int u0 = 0; u0 < UU; u0 += 8) {
    ushort8_t kv[8];
    #pragma unroll
    for (int j = 0; j < 8; ++j) {
      if (u0 + j < UU)
        kv[j] = *(const ushort8_t*)(Kbase + (size_t)ip[u0 + j] * QS);
    }
    #pragma unroll
    for (int j = 0; j < 8; ++j) {
      if (u0 + j < UU) {
        float p = 0.f;
        #pragma unroll
        for (int c = 0; c < 8; ++c) p += q[c] * b2f(kv[j][c]);
        p += __shfl_xor(p, 1, 64);
        p += __shfl_xor(p, 2, 64);
        p += __shfl_xor(p, 4, 64);
        maxv = fmaxf(maxv, p);
        sumv += p;
      }
    }
  }
  if ((lane & 7) == 0) {
    int h = lane >> 3;
    Mout[(size_t)(b * 8 + h) * Lx + l] = maxv - sumv / (float)Lx;
  }
}

// ---------------- rank-based top-U, 4-way scan split (JAX tie-break) -------
__global__ __launch_bounds__(1024) void topk_k(
    const float* __restrict__ Mbuf, int* __restrict__ Mtop, int Lx, int U) {
  int nch = Lx >> 8;
  int bh = blockIdx.x / nch, ch = blockIdx.x % nch;
  const float* m = Mbuf + (size_t)bh * Lx;
  __shared__ float sm[2048];
  __shared__ int part[1024];
  int t = threadIdx.x;
  int c = t & 255, q = t >> 8;
  for (int i = t; i < Lx; i += 1024) sm[i] = m[i];
  __syncthreads();
  int i0 = (ch << 8) + c;
  float v0 = sm[i0];
  int r0 = 0;
  int qlen = Lx >> 2;
  int j0 = q * qlen, j1 = j0 + qlen;
  for (int j = j0; j < j1; j += 4) {
    float4 mj = *(const float4*)&sm[j];
    r0 += (mj.x > v0) || (mj.x == v0 && (j + 0) < i0);
    r0 += (mj.y > v0) || (mj.y == v0 && (j + 1) < i0);
    r0 += (mj.z > v0) || (mj.z == v0 && (j + 2) < i0);
    r0 += (mj.w > v0) || (mj.w == v0 && (j + 3) < i0);
  }
  part[t] = r0;
  __syncthreads();
  if (q == 0) {
    int r = part[c] + part[c + 256] + part[c + 512] + part[c + 768];
    if (r < U) Mtop[bh * U + r] = i0;
  }
}

// ---------------- meanV from bf16 QKV (V at +1024) -------------------------
__global__ __launch_bounds__(512) void meanv1_k(const ushort_t* __restrict__ QKVb,
                                                float* __restrict__ part,
                                                int Lx) {
  int b = blockIdx.x >> 4, chunk = blockIdx.x & 15;
  int rows = Lx >> 4;
  int t = threadIdx.x;  // 512
  const ushort_t* vp =
      QKVb + ((size_t)b * Lx + (size_t)chunk * rows) * QS + 1024 + t;
  float s = 0.f;
  for (int l = 0; l < rows; ++l) s += b2f(vp[(size_t)l * QS]);
  part[(size_t)blockIdx.x * DM + t] = s;
}
__global__ __launch_bounds__(512) void meanv2_k(const float* __restrict__ part,
                                                float* __restrict__ mv,
                                                int Lx) {
  int b = blockIdx.x, t = threadIdx.x;
  float s = 0.f;
  #pragma unroll
  for (int c = 0; c < 16; ++c) s += part[(size_t)(b * 16 + c) * DM + t];
  mv[b * DM + t] = s / (float)Lx;
}

__global__ void fillctx_k(ushort_t* __restrict__ ctx,
                          const float* __restrict__ mv, int Lx) {
  size_t i4 = (size_t)blockIdx.x * 256 + threadIdx.x;
  int col4 = (int)(i4 & 127);
  size_t row = i4 >> 7;
  int b = (int)(row / (size_t)Lx);
  const float* m = mv + b * DM + col4 * 4;
  ushort4 o;
  o.x = f2b(m[0]); o.y = f2b(m[1]); o.z = f2b(m[2]); o.w = f2b(m[3]);
  ((ushort4*)ctx)[i4] = o;
}

// ---------------- one-shot MFMA attention (wave = one 64-key chunk) --------
// 2 waves/block (128 thr): waves fully independent; doubles blocks/CU vs
// the 4-wave version whose grid was exactly 1 block/CU at L0.
template <int UP>  // padded query count (48 >= U)
__global__ __launch_bounds__(128) void attn_mfma_k(
    const ushort_t* __restrict__ QKVb, const int* __restrict__ Mtop,
    float* __restrict__ part, int Lx, int U, int nblk) {
  __shared__ ushort_t Ps[2][UP * 72];   // P transpose buf (stride 72 elems)
  __shared__ ushort_t Vs[2][64 * 64];   // V tile, xor-swizzled
  int bh = blockIdx.x / nblk, blkc = blockIdx.x % nblk;
  int h = bh & 7, b = bh >> 3;
  int t = threadIdx.x;
  int wv = t >> 6, lane = t & 63;
  int quad = lane >> 4, lr = lane & 15;
  int chunk = blkc * 2 + wv;
  int k0 = chunk * 64;
  const ushort_t* Qb = QKVb + (size_t)b * Lx * QS + h * HD;
  const ushort_t* Kb = Qb + 512;
  const ushort_t* Vb = Qb + 1024;

  // Q fragments: rows gathered via Mtop (clamped for padded rows)
  bf16x8 qf[3][2];
  #pragma unroll
  for (int mt = 0; mt < 3; ++mt) {
    int u = mt * 16 + lr;
    int qi = Mtop[bh * U + (u < U ? u : U - 1)];
    const ushort_t* qp = Qb + (size_t)qi * QS + quad * 8;
    qf[mt][0] = *(const bf16x8*)qp;
    qf[mt][1] = *(const bf16x8*)(qp + 32);
  }

  // stage V tile (64 rows x 64 d), xor-swizzle so column reads are
  // conflict-free: elem addr = k*64 + (d ^ (((k>>3)&3)<<4))
  ushort_t* vs = Vs[wv];
  #pragma unroll
  for (int i = 0; i < 8; ++i) {
    int cid = i * 64 + lane;
    int k = cid >> 3, c = cid & 7;
    ushort8_t v = *(const ushort8_t*)(Vb + (size_t)(k0 + k) * QS + c * 8);
    *(ushort8_t*)&vs[k * 64 + ((c * 8) ^ (((k >> 3) & 3) << 4))] = v;
  }

  // S = Q K^T (K frags direct from global)
  floatx4 Sa[3][4] = {};
  #pragma unroll
  for (int kt = 0; kt < 4; ++kt) {
    const ushort_t* kp = Kb + (size_t)(k0 + kt * 16 + lr) * QS + quad * 8;
    bf16x8 kf0 = *(const bf16x8*)kp;
    bf16x8 kf1 = *(const bf16x8*)(kp + 32);
    #pragma unroll
    for (int mt = 0; mt < 3; ++mt) {
      Sa[mt][kt] = __builtin_amdgcn_mfma_f32_16x16x32_bf16(
          qf[mt][0], kf0, Sa[mt][kt], 0, 0, 0);
      Sa[mt][kt] = __builtin_amdgcn_mfma_f32_16x16x32_bf16(
          qf[mt][1], kf1, Sa[mt][kt], 0, 0, 0);
    }
  }

  // softmax over the 64 local keys (rows u = mt*16 + quad*4 + r, col = lr)
  float m_[3][4], l_[3][4];
  #pragma unroll
  for (int mt = 0; mt < 3; ++mt) {
    #pragma unroll
    for (int kt = 0; kt < 4; ++kt) Sa[mt][kt] *= 0.125f;
    #pragma unroll
    for (int r = 0; r < 4; ++r) {
      float mx = fmaxf(fmaxf(Sa[mt][0][r], Sa[mt][1][r]),
                       fmaxf(Sa[mt][2][r], Sa[mt][3][r]));
      #pragma unroll
      for (int o = 1; o <= 8; o <<= 1) mx = fmaxf(mx, __shfl_xor(mx, o, 64));
      float rs = 0.f;
      #pragma unroll
      for (int kt = 0; kt < 4; ++kt) {
        float e = __expf(Sa[mt][kt][r] - mx);
        Sa[mt][kt][r] = e;
        rs += e;
      }
      #pragma unroll
      for (int o = 1; o <= 8; o <<= 1) rs += __shfl_xor(rs, o, 64);
      m_[mt][r] = mx;
      l_[mt][r] = rs;
    }
  }

  // PV in bf16 hi+lo (near-fp32 accuracy). P transposed via per-wave LDS.
  ushort_t* ps = Ps[wv];
  floatx4 Oa[3][4] = {};
  #pragma unroll
  for (int pass = 0; pass < 2; ++pass) {
    #pragma unroll
    for (int mt = 0; mt < 3; ++mt)
      #pragma unroll
      for (int kt = 0; kt < 4; ++kt)
        #pragma unroll
        for (int r = 0; r < 4; ++r) {
          float e = Sa[mt][kt][r];
          ushort_t hb = f2b(e);
          ps[(mt * 16 + quad * 4 + r) * 72 + kt * 16 + lr] = hb;
          Sa[mt][kt][r] = e - b2f(hb);  // residual for lo pass
        }
    #pragma unroll
    for (int kk = 0; kk < 2; ++kk) {
      bf16x8 pf[3];
      #pragma unroll
      for (int mt = 0; mt < 3; ++mt)
        pf[mt] = *(const bf16x8*)&ps[(mt * 16 + lr) * 72 + kk * 32 + quad * 8];
      #pragma unroll
      for (int nt = 0; nt < 4; ++nt) {
        ushort8_t vt;
        #pragma unroll
        for (int j = 0; j < 8; ++j)
          vt[j] = vs[(kk * 32 + quad * 8 + j) * 64 +
                     ((nt * 16 + lr) ^ (quad << 4))];
        bf16x8 vf = *(bf16x8*)&vt;
        #pragma unroll
        for (int mt = 0; mt < 3; ++mt)
          Oa[mt][nt] = __builtin_amdgcn_mfma_f32_16x16x32_bf16(
              pf[mt], vf, Oa[mt][nt], 0, 0, 0);
      }
    }
  }

  // store partial (u < U only; format matches attn_merge_k)
  float* pb = part + (size_t)(bh * (nblk * 2) + chunk) * U * 66;
  #pragma unroll
  for (int mt = 0; mt < 3; ++mt) {
    #pragma unroll
    for (int r = 0; r < 4; ++r) {
      int u = mt * 16 + quad * 4 + r;
      if (u < U) {
        #pragma unroll
        for (int nt = 0; nt < 4; ++nt)
          pb[(size_t)u * 66 + nt * 16 + lr] = Oa[mt][nt][r];
        if (lr == 0) {
          pb[(size_t)u * 66 + 64] = m_[mt][r];
          pb[(size_t)u * 66 + 65] = l_[mt][r];
        }
      }
    }
  }
}

__global__ __launch_bounds__(64) void attn_merge_k(
    const float* __restrict__ part, const int* __restrict__ Mtop,
    ushort_t* __restrict__ ctx, int Lx, int U, int nchunk) {
  int bu = blockIdx.x;
  int u = bu % U, bh = bu / U;
  int h = bh & 7, b = bh >> 3;
  int d = threadIdx.x;  // 64
  float M = -INFINITY;
  for (int c = 0; c < nchunk; ++c)
    M = fmaxf(M, part[((size_t)(bh * nchunk + c) * U + u) * 66 + 64]);
  float L = 0.f, O = 0.f;
  for (int c = 0; c < nchunk; ++c) {
    const float* pp = part + ((size_t)(bh * nchunk + c) * U + u) * 66;
    float w = __expf(pp[64] - M);
    L += pp[65] * w;
    O += pp[d] * w;
  }
  int qi = Mtop[bh * U + u];
  ctx[((size_t)b * Lx + qi) * DM + h * HD + d] = f2b(O / L);
}

// ---------------- batch-norm stats over two partials + bias ----------------
__global__ __launch_bounds__(256) void bn1_k(const float* __restrict__ Y0,
                                             const float* __restrict__ Y1,
                                             const float* __restrict__ cb,
                                             float* __restrict__ ps,
                                             float* __restrict__ pq) {
  int blk = blockIdx.x;
  int t = threadIdx.x;
  float cb0 = cb[t], cb1 = cb[t + 256];
  float s0 = 0, q0 = 0, s1 = 0, q1 = 0;
  const float* b0 = Y0 + (size_t)blk * 256 * DM;
  const float* b1 = Y1 + (size_t)blk * 256 * DM;
  for (int r = 0; r < 256; ++r) {
    float a = b0[(size_t)r * DM + t] + b1[(size_t)r * DM + t] + cb0;
    float b = b0[(size_t)r * DM + t + 256] + b1[(size_t)r * DM + t + 256] + cb1;
    s0 += a; q0 += a * a; s1 += b; q1 += b * b;
  }
  ps[blk * DM + t] = s0; ps[blk * DM + t + 256] = s1;
  pq[blk * DM + t] = q0; pq[blk * DM + t + 256] = q1;
}
__global__ __launch_bounds__(512) void bn2_k(const float* __restrict__ ps,
                                             const float* __restrict__ pq,
                                             float* __restrict__ mu,
                                             float* __restrict__ var) {
  int t = threadIdx.x;
  float s = 0, q = 0;
  #pragma unroll
  for (int c = 0; c < 32; ++c) { s += ps[c * DM + t]; q += pq[c * DM + t]; }
  float m = s * (1.0f / 8192.f);
  mu[t] = m;
  var[t] = q * (1.0f / 8192.f) - m * m;
}

// fused bn+elu+maxpool(k=3,s=2,pad=1) over two partials + bias
__global__ void bnpool_k(const float* __restrict__ Y0,
                         const float* __restrict__ Y1,
                         const float* __restrict__ cb,
                         const float* __restrict__ mu,
                         const float* __restrict__ var,
                         const float* __restrict__ g,
                         const float* __restrict__ be, float* __restrict__ O,
                         ushort_t* __restrict__ Ob) {
  size_t i = (size_t)blockIdx.x * 256 + threadIdx.x;  // 4*1024*512
  int c = (int)(i & 511);
  size_t row = i >> 9;
  int lo = (int)(row & 1023);
  int b = (int)(row >> 10);
  float sc = g[c] / sqrtf(var[c] + 1e-5f);
  float sh = be[c] - mu[c] * sc;
  float cbv = cb[c];
  int l0 = 2 * lo - 1;
  float m = -INFINITY;
  #pragma unroll
  for (int tt = 0; tt < 3; ++tt) {
    int l = l0 + tt;
    if (l >= 0 && l < 2048) {
      size_t off = ((size_t)b * 2048 + l) * DM + c;
      float v = (Y0[off] + Y1[off] + cbv) * sc + sh;
      v = v > 0.f ? v : expm1f(v);
      m = fmaxf(m, v);
    }
  }
  O[i] = m;
  Ob[i] = f2b(m);
}

// ---------------------------------------------------------------------------
extern "C" void kernel_launch(void* const* d_in, const int* in_sizes, int n_in,
                              void* d_out, int out_size, void* d_ws,
                              size_t ws_size, hipStream_t stream) {
  (void)in_sizes; (void)n_in; (void)out_size; (void)ws_size;
  const float* x_enc  = (const float*)d_in[0];
  const float* tok_w  = (const float*)d_in[1];
  const float* Wq     = (const float*)d_in[2];
  const float* bq     = (const float*)d_in[3];
  const float* Wk     = (const float*)d_in[4];
  const float* bk     = (const float*)d_in[5];
  const float* Wv     = (const float*)d_in[6];
  const float* bv     = (const float*)d_in[7];
  const float* Wo     = (const float*)d_in[8];
  const float* bo     = (const float*)d_in[9];
  const float* W1     = (const float*)d_in[10];
  const float* b1     = (const float*)d_in[11];
  const float* W2     = (const float*)d_in[12];
  const float* b2     = (const float*)d_in[13];
  const float* ln1_g  = (const float*)d_in[14];
  const float* ln1_b  = (const float*)d_in[15];
  const float* ln2_g  = (const float*)d_in[16];
  const float* ln2_b  = (const float*)d_in[17];
  const float* conv_w = (const float*)d_in[18];
  const float* conv_b = (const float*)d_in[19];
  const float* bn_g   = (const float*)d_in[20];
  const float* bn_b   = (const float*)d_in[21];
  const float* normf_g = (const float*)d_in[22];
  const float* normf_b = (const float*)d_in[23];
  const float* proj_w = (const float*)d_in[24];
  const float* proj_b = (const float*)d_in[25];
  float* out = (float*)d_out;
  float* ws = (float*)d_ws;

  // ---- fp32 workspace layout (float offsets) ----
  float* X    = ws;                    // 4,194,304
  float* Y2B  = ws + 4194304;          // 4,194,304 (split-K partial #2)
  float* SCR  = ws + 8388608;          // 8,388,608 (final-LN scratch)
  ushort_t* CTXb = (ushort_t*)(ws + 16777216);  // bf16 ctx
  float* Y2   = ws + 20971520;         // 4,194,304 (attn partials / partial #1)
  float* Mb   = ws + 25165824;         // 65,536
  float* MV   = ws + 25231360;         // 2,048
  float* MVP  = ws + 25233408;         // 32,768
  float* BNps = ws + 25266176;         // 16,384
  float* BNpq = ws + 25282560;         // 16,384
  float* BNmu = ws + 25298944;         // 512
  float* BNvr = ws + 25299456;         // 512
  float* ZB   = ws + 25299968;         // 512 (zero bias)
  float* BQKV = ws + 25300480;         // 3,072 (concat qkv bias, 2 layers)
  int*   IDX  = (int*)(ws + 25303552); // 81,920
  int*   MT   = (int*)(ws + 25385472); // 1,280
  // ---- bf16 workspace ----
  ushort_t* U0   = (ushort_t*)(ws + 25386752);
  ushort_t* Xb   = U0;                 // 4,194,304
  ushort_t* Hb   = U0 + 4194304;       // 16,777,216 (FFN hidden)
  ushort_t* QKVb = Hb;                 // alias: bf16 QKV — live QKV-GEMM ->
                                       // attn, before FFN uses Hb
  ushort_t* Wqkvb= U0 + 20971520;      // 1,572,864
  ushort_t* Wob  = U0 + 22544384;      // 524,288
  ushort_t* W1b  = U0 + 23068672;      // 2,097,152
  ushort_t* W2b  = U0 + 25165824;      // 2,097,152
  ushort_t* Cwb  = U0 + 27262976;      // 786,432 ([d][t][i] layout)
  ushort_t* Twb  = U0 + 28049408;      // 49,152
  ushort_t* Atok = U0 + 28098560;      // 786,432
  float* PEf = ws + 39829248;          // 1,048,576 (PE table)
  float* PWt = ws + 40877824;          // 16,384 (transposed proj weight)

  // ---- fused preamble ----
  castqkv_k<<<1536, 256, 0, stream>>>(Wq, Wk, Wv, Wqkvb);
  castw3_k<<<4656, 256, 0, stream>>>(Wo, W1, W2, tok_w, Wob, W1b, W2b, Twb);
  castw_conv_k<<<3072, 256, 0, stream>>>(conv_w, Cwb);
  castproj_k<<<64, 256, 0, stream>>>(proj_w, PWt);
  setup_small_k<<<14, 256, 0, stream>>>(bq, bk, bv, ZB, BQKV);
  pe_k<<<2048, 256, 0, stream>>>(PEf);
  im2col_tok_k<<<3072, 256, 0, stream>>>(x_enc, Atok);

  // token embedding GEMM (+PE): K=96
  mgemm_k<128, 0, 0, 2, 1, 1><<<256, 512, 0, stream>>>(
      Atok, Twb, ZB, X, nullptr, Xb, PEf, 4, DM, 96);

  for (int layer = 0; layer < 2; ++layer) {
    const int Lx = (layer == 0) ? 2048 : 1024;
    const int U  = (layer == 0) ? 40 : 35;
    const int M  = NB * Lx;
    const int Yt = M / 128;
    const int NCHT = Lx / 64;          // one 64-key chunk per wave
    const int NBLK = NCHT / 2;         // 2 waves per block

    uint32_t kl0, kl1, s0, s1;
    threefry2x32(0u, 42u, 0u, (uint32_t)layer, &kl0, &kl1);
    threefry2x32(kl0, kl1, 0u, 1u, &s0, &s1);
    int nidx = Lx * U;
    gen_idx_k<<<(nidx + 255) / 256, 256, 0, stream>>>(IDX, nidx, Lx - 1, s0, s1);

    // fused QKV GEMM: bf16-only output
    mgemm_k<128, 0, 0, 1, 0, 1><<<12 * Yt, 512, 0, stream>>>(
        Xb, Wqkvb + (size_t)layer * 786432, BQKV + layer * 1536, nullptr,
        nullptr, QKVb, nullptr, 12, QS, DM);

    // ProbSparse attention (all bf16 QKV)
    if (layer == 0)
      qk_m_k<40><<<Lx, 256, 0, stream>>>(QKVb, IDX, Mb, Lx);
    else
      qk_m_k<35><<<Lx, 256, 0, stream>>>(QKVb, IDX, Mb, Lx);
    topk_k<<<NB * NH * (Lx >> 8), 1024, 0, stream>>>(Mb, MT, Lx, U);
    meanv1_k<<<NB * 16, 512, 0, stream>>>(QKVb, MVP, Lx);
    meanv2_k<<<NB, 512, 0, stream>>>(MVP, MV, Lx);
    fillctx_k<<<(M * DM / 4) / 256, 256, 0, stream>>>(CTXb, MV, Lx);
    attn_mfma_k<48><<<NB * NH * NBLK, 128, 0, stream>>>(QKVb, MT, Y2, Lx, U,
                                                        NBLK);
    attn_merge_k<<<NB * NH * U, 64, 0, stream>>>(Y2, MT, CTXb, Lx, U, NCHT);

    // output projection split-K x2 (raw partials) + residual+bias in LN1
    mgemm_k<128, 0, 0, 0, 0, 2><<<2 * 4 * Yt, 512, 0, stream>>>(
        CTXb, Wob + (size_t)layer * 262144, nullptr, Y2, Y2B, nullptr,
        nullptr, 4, DM, DM);
    ln_k<<<M, 128, 0, stream>>>(X, Y2, Y2B, bo + layer * DM,
                                ln1_g + layer * DM, ln1_b + layer * DM, X, Xb);

    // FFN1 (GELU fused; hidden kept in bf16)
    mgemm_k<128, 0, 1, 1, 0, 1><<<16 * Yt, 512, 0, stream>>>(
        Xb, W1b + (size_t)layer * 1048576, b1 + layer * 2048, nullptr, nullptr,
        Hb, nullptr, 16, 2048, DM);
    // FFN2 split-K x2 (raw partials) + residual+bias in LN2
    mgemm_k<128, 0, 0, 0, 0, 2><<<2 * 4 * Yt, 512, 0, stream>>>(
        Hb, W2b + (size_t)layer * 1048576, nullptr, Y2, Y2B, nullptr,
        nullptr, 4, DM, 2048);
    ln_k<<<M, 128, 0, stream>>>(X, Y2, Y2B, b2 + layer * DM,
                                ln2_g + layer * DM, ln2_b + layer * DM, X, Xb);

    if (layer == 0) {
      // distil conv as implicit GEMM, split-K x2; bias folded into bn stats
      mgemm_k<128, 1, 0, 0, 0, 2><<<2 * 4 * 64, 512, 0, stream>>>(
          Xb, Cwb, nullptr, Y2, Y2B, nullptr, nullptr, 4, DM, 1536);
      bn1_k<<<32, 256, 0, stream>>>(Y2, Y2B, conv_b, BNps, BNpq);
      bn2_k<<<1, 512, 0, stream>>>(BNps, BNpq, BNmu, BNvr);
      bnpool_k<<<(NB * 1024 * 512) / 256, 256, 0, stream>>>(
          Y2, Y2B, conv_b, BNmu, BNvr, bn_g, bn_b, X, Xb);
    }
  }

  // final LN + projection (N=32, fp32)
  ln_k<<<NB * 1024, 128, 0, stream>>>(X, nullptr, nullptr, nullptr, normf_g,
                                      normf_b, SCR, nullptr);
  proj_k<<<512, 256, 0, stream>>>(SCR, PWt, proj_b, out);
}

// Round 14
// 583.457 us; speedup vs baseline: 1.1009x; 1.0194x over previous
//
#include <hip/hip_runtime.h>
#include <cstdint>
#include <cmath>

// ---------------------------------------------------------------------------
// Informer encoder forward (B=4, L=2048, ENC_IN=32, D_MODEL=512, D_FF=2048,
// E_LAYERS=2, H=8, FACTOR=5).
// Round 30: launch fusion. ~46 dispatches/iter; estimated kernel time sums
// to ~350us vs 595us wall -> inter-dispatch overhead is the prime suspect.
// The 7 independent preamble kernels + both layers' gen_idx fused into ONE
// segmented mega-kernel (gid-range dispatch, 3.82M threads). Bit-identical
// outputs; 8 fewer launches. Rest = R29 best (594.8 us).
// ---------------------------------------------------------------------------

#define NB 4
#define DM 512
#define NH 8
#define HD 64
#define QS 1536  // QKV row stride

typedef unsigned short ushort_t;
typedef __bf16 bf16x8 __attribute__((ext_vector_type(8)));
typedef float floatx4 __attribute__((ext_vector_type(4)));
typedef unsigned short ushort8_t __attribute__((ext_vector_type(8)));

__device__ inline ushort_t f2b(float f) {
  uint32_t u = __float_as_uint(f);
  uint32_t r = (u + 0x7fffu + ((u >> 16) & 1u)) >> 16;
  return (ushort_t)r;
}
__device__ inline float b2f(ushort_t u) {
  return __uint_as_float((uint32_t)u << 16);
}

__host__ __device__ inline void threefry2x32(uint32_t k0, uint32_t k1,
                                             uint32_t c0, uint32_t c1,
                                             uint32_t* o0, uint32_t* o1) {
  uint32_t ks0 = k0, ks1 = k1, ks2 = k0 ^ k1 ^ 0x1BD11BDAu;
  uint32_t x0 = c0 + ks0;
  uint32_t x1 = c1 + ks1;
  const uint32_t rotA[4] = {13u, 15u, 26u, 6u};
  const uint32_t rotB[4] = {17u, 29u, 16u, 24u};
  uint32_t ks[3] = {ks0, ks1, ks2};
  #pragma unroll
  for (int i = 0; i < 5; ++i) {
    const uint32_t* r = (i & 1) ? rotB : rotA;
    #pragma unroll
    for (int j = 0; j < 4; ++j) {
      x0 += x1;
      x1 = (x1 << r[j]) | (x1 >> (32u - r[j]));
      x1 ^= x0;
    }
    x0 += ks[(i + 1) % 3];
    x1 += ks[(i + 2) % 3] + (uint32_t)(i + 1);
  }
  *o0 = x0; *o1 = x1;
}

// ---------------- fused preamble: all weight casts + tables + indices ------
// seg0 [0, 393216)           castqkv (float4 units)
// seg1 [393216, 1585152)     castw3 (float4 units)
// seg2 [1585152, 2371584)    castw_conv (scalars)
// seg3 [2371584, 2387968)    castproj
// seg4 [2387968, 2391552)    setup_small (ZB + BQKV)
// seg5 [2391552, 2915840)    pe (sin,cos pairs)
// seg6 [2915840, 3702272)    im2col_tok (scalars)
// seg7 [3702272, 3784192)    gen_idx layer0 (mask 2047)
// seg8 [3784192, 3820032)    gen_idx layer1 (mask 1023)
__global__ void preamble_k(
    const float* __restrict__ Wq, const float* __restrict__ Wk,
    const float* __restrict__ Wv, const float* __restrict__ Wo,
    const float* __restrict__ W1, const float* __restrict__ W2,
    const float* __restrict__ tw, const float* __restrict__ conv_w,
    const float* __restrict__ proj_w, const float* __restrict__ bq,
    const float* __restrict__ bk, const float* __restrict__ bv,
    const float* __restrict__ xe, ushort_t* __restrict__ Wqkvb,
    ushort_t* __restrict__ oWo, ushort_t* __restrict__ oW1,
    ushort_t* __restrict__ oW2, ushort_t* __restrict__ otw,
    ushort_t* __restrict__ Cwb, float* __restrict__ PWt,
    float* __restrict__ ZB, float* __restrict__ BQKV,
    float* __restrict__ pe, ushort_t* __restrict__ Atok,
    int* __restrict__ idx0, int* __restrict__ idx1,
    uint32_t s00, uint32_t s01, uint32_t s10, uint32_t s11) {
  int gid = blockIdx.x * 256 + threadIdx.x;
  if (gid < 393216) {
    // qkv weight cast -> concat bf16 [layer][1536][512]
    int ly = gid / 196608, r4 = gid - ly * 196608;
    int r = r4 >> 7, c4 = r4 & 127;
    int sel = r >> 9, srow = r & 511;
    const float* src = (sel == 0 ? Wq : sel == 1 ? Wk : Wv) + ly * 262144 +
                       srow * 512 + c4 * 4;
    float4 v = *(const float4*)src;
    ushort4 o;
    o.x = f2b(v.x); o.y = f2b(v.y); o.z = f2b(v.z); o.w = f2b(v.w);
    ((ushort4*)Wqkvb)[ly * 196608 + r * 128 + c4] = o;
  } else if (gid < 1585152) {
    int g = gid - 393216;
    const float* src;
    ushort4* dst;
    int i;
    if (g < 131072) { src = Wo; dst = (ushort4*)oWo; i = g; }
    else if (g < 655360) { src = W1; dst = (ushort4*)oW1; i = g - 131072; }
    else if (g < 1179648) { src = W2; dst = (ushort4*)oW2; i = g - 655360; }
    else { src = tw; dst = (ushort4*)otw; i = g - 1179648; }
    float4 v = ((const float4*)src)[i];
    ushort4 o;
    o.x = f2b(v.x); o.y = f2b(v.y); o.z = f2b(v.z); o.w = f2b(v.w);
    dst[i] = o;
  } else if (gid < 2371584) {
    int g = gid - 1585152;  // conv weight (D,I,3) -> bf16 (D,3,I)
    int d = g / 1536, r = g - d * 1536;
    int t = r >> 9, i = r & 511;
    Cwb[g] = f2b(conv_w[d * 1536 + i * 3 + t]);
  } else if (gid < 2387968) {
    int g = gid - 2371584;  // proj weight (32,512) -> (512,32) fp32
    int k = g >> 5, n = g & 31;
    PWt[g] = proj_w[n * 512 + k];
  } else if (gid < 2391552) {
    int g = gid - 2387968;  // ZB + concat qkv bias
    if (g < 512) { ZB[g] = 0.f; }
    else {
      int gg = g - 512;
      int layer = gg / 1536, r = gg - layer * 1536;
      float v;
      if (r < 512) v = bq[layer * 512 + r];
      else if (r < 1024) v = bk[layer * 512 + r - 512];
      else v = bv[layer * 512 + r - 1024];
      BQKV[gg] = v;
    }
  } else if (gid < 2915840) {
    int i = gid - 2391552;  // PE (sin,cos) pairs
    int d2 = i & 255, l = i >> 8;
    float div = __expf((float)(2 * d2) * -1.7988946039e-2f);
    float ang = (float)l * div;
    float s, c;
    __sincosf(ang, &s, &c);
    ((float2*)pe)[i] = make_float2(s, c);
  } else if (gid < 3702272) {
    int g = gid - 2915840;  // im2col for token conv
    int col = g % 96;
    int row = g / 96;
    int c = col / 3, t = col - c * 3;
    int b = row >> 11, l = row & 2047;
    int ls = (l + t - 1) & 2047;
    Atok[g] = f2b(xe[((size_t)b * 2048 + ls) * 32 + c]);
  } else if (gid < 3784192) {
    int i = gid - 3702272;  // gen_idx layer 0
    uint32_t o0, o1;
    threefry2x32(s00, s01, 0u, (uint32_t)i, &o0, &o1);
    idx0[i] = (int)((o0 ^ o1) & 2047u);
  } else if (gid < 3820032) {
    int i = gid - 3784192;  // gen_idx layer 1
    uint32_t o0, o1;
    threefry2x32(s10, s11, 0u, (uint32_t)i, &o0, &o1);
    idx1[i] = (int)((o0 ^ o1) & 1023u);
  }
}

__device__ inline float wave_sum64(float v) {
  #pragma unroll
  for (int o = 32; o > 0; o >>= 1) v += __shfl_xor(v, o, 64);
  return v;
}

// ---------------- bf16 MFMA GEMM: TM=128, in-row swizzle, counted vmcnt ----
__device__ inline void gload16(const ushort_t* g, ushort_t* l) {
  __builtin_amdgcn_global_load_lds(
      (const __attribute__((address_space(1))) unsigned int*)(const void*)g,
      (__attribute__((address_space(3))) unsigned int*)(void*)l, 16, 0, 0);
}

// CONV: A is Xb (B*L x 512 bf16); logical A[row][k] = Xb[(row_b, (l+t-1)%2048)][c]
// with t = k/512, c = k%512. Otherwise plain row-major A (M x K).
// LDS tile layout: 16-row blocks, row stride 64B; within a row the four 16B
// chunks are stored at position c ^ ((row>>1)&3) (in-segment swizzle; global
// coalescing preserved since the permutation stays inside the 64B segment).
// SPLITK==2: gridDim.x = 2*nb; blocks id>=nb handle the upper K half; both
// halves write RAW fp32 partials to Cf / Cf2; consumers reduce.
template <int TM, int CONV, int GELU, int OMODE, int ADDPE, int SPLITK>
__global__ __launch_bounds__(512, 4) void mgemm_k(
    const ushort_t* __restrict__ A, const ushort_t* __restrict__ W,
    const float* __restrict__ bias, float* __restrict__ Cf,
    float* __restrict__ Cf2, ushort_t* __restrict__ Cb,
    const float* __restrict__ pe, int X, int ldc, int K) {
  constexpr int MT = TM / 64;        // acc row-tiles per wave (2 or 4)
  constexpr int AG = TM / 128;       // A gloads per wave per K-step (1 or 2)
  constexpr int BUFSZ = (TM + 128) * 32;  // ushorts per staging buffer
  constexpr int SHSZ = (3 * BUFSZ > 18432) ? 3 * BUFSZ : 18432;
  __shared__ __align__(16) ushort_t SH[SHSZ];
  int id = blockIdx.x;
  int half = 0;
  if (SPLITK == 2) {
    int nb = gridDim.x >> 1;
    if (id >= nb) { half = 1; id -= nb; }
  }
  int kbase = half * (K >> 1);
  int KK = (SPLITK == 2) ? (K >> 1) : K;
  int cc = id & 7, j = id >> 3;
  int bx = j % X;
  int by = (j / X) * 8 + cc;
  int m0 = by * TM, n0 = bx * 128;
  int t = threadIdx.x;
  int lane = t & 63, wv = t >> 6;  // 8 waves
  int rl = lane >> 2;
  int cl = ((lane & 3) ^ ((rl >> 1) & 3)) * 8;  // in-segment chunk swizzle
  int RaA = wv * (16 * AG);  // A rows staged per wave
  int RaB = wv * 16;         // B rows staged per wave
  const ushort_t* gA[AG];
  int cbv[AG], clrv[AG], lAoff[AG];
  #pragma unroll
  for (int g = 0; g < AG; ++g) {
    int ar = m0 + RaA + g * 16 + rl;
    gA[g] = A + (size_t)ar * K + kbase + cl;  // non-CONV path
    cbv[g] = ar >> 11;                        // CONV: batch
    clrv[g] = ar & 2047;                      // CONV: seq pos
    lAoff[g] = (RaA + g * 16) * 32;
  }
  const ushort_t* gB = W + (size_t)(n0 + RaB + rl) * K + kbase + cl;
  int lBoff = TM * 32 + RaB * 32;

  int quad = lane >> 4, lr = lane & 15;
  int qs = (quad ^ ((lr >> 1) & 3)) * 8;  // swizzled read chunk offset
  int wm = wv >> 1, wn = wv & 1;  // 4 (M) x 2 (N) waves, (TM/4)x64 each

  // stage K-step kst into LDS buffer buf (AG+1 vmem instructions per wave)
  auto STAGE = [&](int kst, int buf) {
    int bb = buf * BUFSZ;
    int ko = kst << 5;
    #pragma unroll
    for (int g = 0; g < AG; ++g) {
      if (CONV) {
        int kg = kbase + ko;
        int tt = kg >> 9;
        int c = (kg & 511) + cl;
        int ls = (clrv[g] + tt - 1) & 2047;
        gload16(A + ((size_t)(cbv[g] * 2048 + ls) * 512 + c),
                SH + bb + lAoff[g]);
      } else {
        gload16(gA[g] + ko, SH + bb + lAoff[g]);
      }
    }
    gload16(gB + ko, SH + bb + lBoff);
  };

  floatx4 acc[MT][4] = {};
  int nt = KK >> 5;
  STAGE(0, 0);
  if (nt > 1) STAGE(1, 1);
  int cur = 0;
  for (int it = 0; it < nt; ++it) {
    // counted wait: own stage(it) complete; stage(it+1) stays in flight
    if (it < nt - 1) {
      if constexpr (AG == 1)
        asm volatile("s_waitcnt vmcnt(2)" ::: "memory");
      else
        asm volatile("s_waitcnt vmcnt(3)" ::: "memory");
    } else {
      asm volatile("s_waitcnt vmcnt(0)" ::: "memory");
    }
    __builtin_amdgcn_s_barrier();        // all waves: stage(it) landed,
    __builtin_amdgcn_sched_barrier(0);   // prior-iter reads retired
    int nx = it + 2;
    if (nx < nt) {
      int nb3 = cur + 2;
      if (nb3 >= 3) nb3 -= 3;
      STAGE(nx, nb3);                    // buf last read at it-1: safe
    }
    const ushort_t* Ab = SH + cur * BUFSZ;
    const ushort_t* Bb = Ab + TM * 32;
    bf16x8 av[MT], bv[4];
    #pragma unroll
    for (int mt = 0; mt < MT; ++mt)
      av[mt] =
          *(const bf16x8*)&Ab[(wm * (16 * MT) + mt * 16 + lr) * 32 + qs];
    #pragma unroll
    for (int nt2 = 0; nt2 < 4; ++nt2)
      bv[nt2] = *(const bf16x8*)&Bb[(wn * 64 + nt2 * 16 + lr) * 32 + qs];
    #pragma unroll
    for (int mt = 0; mt < MT; ++mt)
      #pragma unroll
      for (int nt2 = 0; nt2 < 4; ++nt2)
        acc[mt][nt2] = __builtin_amdgcn_mfma_f32_16x16x32_bf16(
            av[mt], bv[nt2], acc[mt][nt2], 0, 0, 0);
    // all my LDS reads retired before next barrier (closes WAR window)
    asm volatile("s_waitcnt lgkmcnt(0)" ::: "memory");
    __builtin_amdgcn_sched_barrier(0);
    cur = (cur == 2) ? 0 : cur + 1;
  }
  __syncthreads();  // epilogue reuses SH

  if (SPLITK == 2) {
    // raw fp32 partial; bias applied by the consumer
    float* dst = half ? Cf2 : Cf;
    #pragma unroll
    for (int nt2 = 0; nt2 < 4; ++nt2) {
      int col = n0 + wn * 64 + nt2 * 16 + lr;
      #pragma unroll
      for (int mt = 0; mt < MT; ++mt) {
        int row0 = m0 + wm * (16 * MT) + mt * 16 + quad * 4;
        #pragma unroll
        for (int r = 0; r < 4; ++r)
          dst[(size_t)(row0 + r) * ldc + col] = acc[mt][nt2][r];
      }
    }
  } else if (OMODE == 0) {
    #pragma unroll
    for (int nt2 = 0; nt2 < 4; ++nt2) {
      int col = n0 + wn * 64 + nt2 * 16 + lr;
      float bsv = bias[col];
      #pragma unroll
      for (int mt = 0; mt < MT; ++mt) {
        int row0 = m0 + wm * (16 * MT) + mt * 16 + quad * 4;
        #pragma unroll
        for (int r = 0; r < 4; ++r) {
          int row = row0 + r;
          float v = acc[mt][nt2][r] + bsv;
          if (ADDPE) v += pe[(size_t)(row & 2047) * ldc + col];
          if (GELU) v = 0.5f * v * (1.0f + erff(v * 0.70710678118654752f));
          Cf[(size_t)row * ldc + col] = v;
        }
      }
    }
  } else {
    // bf16 through per-wave LDS transpose -> coalesced ushort8 stores.
    ushort_t* ep = SH + wv * 2304;
    #pragma unroll
    for (int p = 0; p < MT / 2; ++p) {
      #pragma unroll
      for (int nt2 = 0; nt2 < 4; ++nt2) {
        int col = n0 + wn * 64 + nt2 * 16 + lr;
        float bsv = bias[col];
        #pragma unroll
        for (int ml = 0; ml < 2; ++ml) {
          int mt = p * 2 + ml;
          #pragma unroll
          for (int r = 0; r < 4; ++r) {
            int row = m0 + wm * (16 * MT) + mt * 16 + quad * 4 + r;
            float v = acc[mt][nt2][r] + bsv;
            if (ADDPE) v += pe[(size_t)(row & 2047) * ldc + col];
            if (GELU) v = 0.5f * v * (1.0f + erff(v * 0.70710678118654752f));
            if (OMODE == 2) Cf[(size_t)row * ldc + col] = v;
            ep[(ml * 16 + quad * 4 + r) * 72 + nt2 * 16 + lr] = f2b(v);
          }
        }
      }
      int r8 = lane >> 3, c8 = (lane & 7) * 8;
      #pragma unroll
      for (int i = 0; i < 4; ++i) {
        int row = i * 8 + r8;
        ushort8_t vv = *(const ushort8_t*)&ep[row * 72 + c8];
        *(ushort8_t*)&Cb[(size_t)(m0 + wm * (16 * MT) + p * 32 + row) * ldc +
                         n0 + wn * 64 + c8] = vv;
      }
    }
  }
}

// ---------------- final projection (M=4096, N=32, K=512, fp32) -------------
__global__ __launch_bounds__(256) void proj_k(
    const float* __restrict__ A, const float* __restrict__ Wt,
    const float* __restrict__ bias, float* __restrict__ C) {
  int t = threadIdx.x;
  int n = t & 31, ml = t >> 5;
  int m = blockIdx.x * 8 + ml;
  const float* a = A + (size_t)m * DM;
  float a0 = 0.f, a1 = 0.f, a2 = 0.f, a3 = 0.f;
  #pragma unroll 4
  for (int k = 0; k < DM; k += 4) {
    float4 av = *(const float4*)&a[k];
    a0 += av.x * Wt[k * 32 + n];
    a1 += av.y * Wt[(k + 1) * 32 + n];
    a2 += av.z * Wt[(k + 2) * 32 + n];
    a3 += av.w * Wt[(k + 3) * 32 + n];
  }
  C[(size_t)m * 32 + n] = (a0 + a2) + (a1 + a3) + bias[n];
}

// ---------------- LayerNorm (+residuals, +col bias, +optional bf16 copy) ---
// O = LN(A + Bres + Bres2 + cbias) * g + be; Bres/Bres2/cbias nullable.
__global__ __launch_bounds__(128) void ln_k(
    const float* __restrict__ A, const float* __restrict__ Bres,
    const float* __restrict__ Bres2, const float* __restrict__ cbias,
    const float* __restrict__ g, const float* __restrict__ be,
    float* __restrict__ O, ushort_t* __restrict__ Ob) {
  int r = blockIdx.x, t = threadIdx.x;
  __shared__ float lds[2];
  float4 v = ((const float4*)(A + (size_t)r * DM))[t];
  if (Bres) {
    float4 u = ((const float4*)(Bres + (size_t)r * DM))[t];
    v.x += u.x; v.y += u.y; v.z += u.z; v.w += u.w;
  }
  if (Bres2) {
    float4 u = ((const float4*)(Bres2 + (size_t)r * DM))[t];
    v.x += u.x; v.y += u.y; v.z += u.z; v.w += u.w;
  }
  if (cbias) {
    float4 u = ((const float4*)cbias)[t];
    v.x += u.x; v.y += u.y; v.z += u.z; v.w += u.w;
  }
  float s = wave_sum64(v.x + v.y + v.z + v.w);
  int w = t >> 6;
  if ((t & 63) == 0) lds[w] = s;
  __syncthreads();
  float mu = (lds[0] + lds[1]) * (1.0f / 512.0f);
  __syncthreads();
  float dx = v.x - mu, dy = v.y - mu, dz = v.z - mu, dw = v.w - mu;
  float sq = wave_sum64(dx * dx + dy * dy + dz * dz + dw * dw);
  if ((t & 63) == 0) lds[w] = sq;
  __syncthreads();
  float var = (lds[0] + lds[1]) * (1.0f / 512.0f);
  float inv = 1.0f / sqrtf(var + 1e-5f);
  float4 gv = ((const float4*)g)[t];
  float4 bv = ((const float4*)be)[t];
  float4 o;
  o.x = dx * inv * gv.x + bv.x;
  o.y = dy * inv * gv.y + bv.y;
  o.z = dz * inv * gv.z + bv.z;
  o.w = dw * inv * gv.w + bv.w;
  ((float4*)(O + (size_t)r * DM))[t] = o;
  if (Ob) {
    ushort4 ob;
    ob.x = f2b(o.x); ob.y = f2b(o.y); ob.z = f2b(o.z); ob.w = f2b(o.w);
    ((ushort4*)(Ob + (size_t)r * DM))[t] = ob;
  }
}

// ---------------- M[b,h,l]: one wave per (b,l), all-bf16 QKV ---------------
template <int UU>
__global__ __launch_bounds__(256) void qk_m_k(
    const ushort_t* __restrict__ QKVb, const int* __restrict__ idx,
    float* __restrict__ Mout, int Lx) {
  int l = blockIdx.x;
  int b = threadIdx.x >> 6;  // wave = batch
  int lane = threadIdx.x & 63;
  const ushort_t* qp = QKVb + ((size_t)b * Lx + l) * QS + lane * 8;
  float q[8];
  {
    ushort8_t qv = *(const ushort8_t*)qp;
    #pragma unroll
    for (int c = 0; c < 8; ++c) q[c] = b2f(qv[c]);
  }
  const ushort_t* Kbase = QKVb + (size_t)b * Lx * QS + 512 + lane * 8;
  const int* ip = idx + (size_t)l * UU;
  float maxv = -INFINITY, sumv = 0.f;
  #pragma unroll
  for (int u0 = 0; u0 < UU; u0 += 8) {
    ushort8_t kv[8];
    #pragma unroll
    for (int j = 0; j < 8; ++j) {
      if (u0 + j < UU)
        kv[j] = *(const ushort8_t*)(Kbase + (size_t)ip[u0 + j] * QS);
    }
    #pragma unroll
    for (int j = 0; j < 8; ++j) {
      if (u0 + j < UU) {
        float p = 0.f;
        #pragma unroll
        for (int c = 0; c < 8; ++c) p += q[c] * b2f(kv[j][c]);
        p += __shfl_xor(p, 1, 64);
        p += __shfl_xor(p, 2, 64);
        p += __shfl_xor(p, 4, 64);
        maxv = fmaxf(maxv, p);
        sumv += p;
      }
    }
  }
  if ((lane & 7) == 0) {
    int h = lane >> 3;
    Mout[(size_t)(b * 8 + h) * Lx + l] = maxv - sumv / (float)Lx;
  }
}

// ---------------- rank-based top-U, 4-way scan split (JAX tie-break) -------
__global__ __launch_bounds__(1024) void topk_k(
    const float* __restrict__ Mbuf, int* __restrict__ Mtop, int Lx, int U) {
  int nch = Lx >> 8;
  int bh = blockIdx.x / nch, ch = blockIdx.x % nch;
  const float* m = Mbuf + (size_t)bh * Lx;
  __shared__ float sm[2048];
  __shared__ int part[1024];
  int t = threadIdx.x;
  int c = t & 255, q = t >> 8;
  for (int i = t; i < Lx; i += 1024) sm[i] = m[i];
  __syncthreads();
  int i0 = (ch << 8) + c;
  float v0 = sm[i0];
  int r0 = 0;
  int qlen = Lx >> 2;
  int j0 = q * qlen, j1 = j0 + qlen;
  for (int j = j0; j < j1; j += 4) {
    float4 mj = *(const float4*)&sm[j];
    r0 += (mj.x > v0) || (mj.x == v0 && (j + 0) < i0);
    r0 += (mj.y > v0) || (mj.y == v0 && (j + 1) < i0);
    r0 += (mj.z > v0) || (mj.z == v0 && (j + 2) < i0);
    r0 += (mj.w > v0) || (mj.w == v0 && (j + 3) < i0);
  }
  part[t] = r0;
  __syncthreads();
  if (q == 0) {
    int r = part[c] + part[c + 256] + part[c + 512] + part[c + 768];
    if (r < U) Mtop[bh * U + r] = i0;
  }
}

// ---------------- meanV from bf16 QKV (V at +1024) -------------------------
__global__ __launch_bounds__(512) void meanv1_k(const ushort_t* __restrict__ QKVb,
                                                float* __restrict__ part,
                                                int Lx) {
  int b = blockIdx.x >> 4, chunk = blockIdx.x & 15;
  int rows = Lx >> 4;
  int t = threadIdx.x;  // 512
  const ushort_t* vp =
      QKVb + ((size_t)b * Lx + (size_t)chunk * rows) * QS + 1024 + t;
  float s = 0.f;
  for (int l = 0; l < rows; ++l) s += b2f(vp[(size_t)l * QS]);
  part[(size_t)blockIdx.x * DM + t] = s;
}
__global__ __launch_bounds__(512) void meanv2_k(const float* __restrict__ part,
                                                float* __restrict__ mv,
                                                int Lx) {
  int b = blockIdx.x, t = threadIdx.x;
  float s = 0.f;
  #pragma unroll
  for (int c = 0; c < 16; ++c) s += part[(size_t)(b * 16 + c) * DM + t];
  mv[b * DM + t] = s / (float)Lx;
}

__global__ void fillctx_k(ushort_t* __restrict__ ctx,
                          const float* __restrict__ mv, int Lx) {
  size_t i4 = (size_t)blockIdx.x * 256 + threadIdx.x;
  int col4 = (int)(i4 & 127);
  size_t row = i4 >> 7;
  int b = (int)(row / (size_t)Lx);
  const float* m = mv + b * DM + col4 * 4;
  ushort4 o;
  o.x = f2b(m[0]); o.y = f2b(m[1]); o.z = f2b(m[2]); o.w = f2b(m[3]);
  ((ushort4*)ctx)[i4] = o;
}

// ---------------- one-shot MFMA attention (wave = one 64-key chunk) --------
// 2 waves/block (128 thr): waves fully independent; doubles blocks/CU vs
// the 4-wave version whose grid was exactly 1 block/CU at L0.
template <int UP>  // padded query count (48 >= U)
__global__ __launch_bounds__(128) void attn_mfma_k(
    const ushort_t* __restrict__ QKVb, const int* __restrict__ Mtop,
    float* __restrict__ part, int Lx, int U, int nblk) {
  __shared__ ushort_t Ps[2][UP * 72];   // P transpose buf (stride 72 elems)
  __shared__ ushort_t Vs[2][64 * 64];   // V tile, xor-swizzled
  int bh = blockIdx.x / nblk, blkc = blockIdx.x % nblk;
  int h = bh & 7, b = bh >> 3;
  int t = threadIdx.x;
  int wv = t >> 6, lane = t & 63;
  int quad = lane >> 4, lr = lane & 15;
  int chunk = blkc * 2 + wv;
  int k0 = chunk * 64;
  const ushort_t* Qb = QKVb + (size_t)b * Lx * QS + h * HD;
  const ushort_t* Kb = Qb + 512;
  const ushort_t* Vb = Qb + 1024;

  // Q fragments: rows gathered via Mtop (clamped for padded rows)
  bf16x8 qf[3][2];
  #pragma unroll
  for (int mt = 0; mt < 3; ++mt) {
    int u = mt * 16 + lr;
    int qi = Mtop[bh * U + (u < U ? u : U - 1)];
    const ushort_t* qp = Qb + (size_t)qi * QS + quad * 8;
    qf[mt][0] = *(const bf16x8*)qp;
    qf[mt][1] = *(const bf16x8*)(qp + 32);
  }

  // stage V tile (64 rows x 64 d), xor-swizzle so column reads are
  // conflict-free: elem addr = k*64 + (d ^ (((k>>3)&3)<<4))
  ushort_t* vs = Vs[wv];
  #pragma unroll
  for (int i = 0; i < 8; ++i) {
    int cid = i * 64 + lane;
    int k = cid >> 3, c = cid & 7;
    ushort8_t v = *(const ushort8_t*)(Vb + (size_t)(k0 + k) * QS + c * 8);
    *(ushort8_t*)&vs[k * 64 + ((c * 8) ^ (((k >> 3) & 3) << 4))] = v;
  }

  // S = Q K^T (K frags direct from global)
  floatx4 Sa[3][4] = {};
  #pragma unroll
  for (int kt = 0; kt < 4; ++kt) {
    const ushort_t* kp = Kb + (size_t)(k0 + kt * 16 + lr) * QS + quad * 8;
    bf16x8 kf0 = *(const bf16x8*)kp;
    bf16x8 kf1 = *(const bf16x8*)(kp + 32);
    #pragma unroll
    for (int mt = 0; mt < 3; ++mt) {
      Sa[mt][kt] = __builtin_amdgcn_mfma_f32_16x16x32_bf16(
          qf[mt][0], kf0, Sa[mt][kt], 0, 0, 0);
      Sa[mt][kt] = __builtin_amdgcn_mfma_f32_16x16x32_bf16(
          qf[mt][1], kf1, Sa[mt][kt], 0, 0, 0);
    }
  }

  // softmax over the 64 local keys (rows u = mt*16 + quad*4 + r, col = lr)
  float m_[3][4], l_[3][4];
  #pragma unroll
  for (int mt = 0; mt < 3; ++mt) {
    #pragma unroll
    for (int kt = 0; kt < 4; ++kt) Sa[mt][kt] *= 0.125f;
    #pragma unroll
    for (int r = 0; r < 4; ++r) {
      float mx = fmaxf(fmaxf(Sa[mt][0][r], Sa[mt][1][r]),
                       fmaxf(Sa[mt][2][r], Sa[mt][3][r]));
      #pragma unroll
      for (int o = 1; o <= 8; o <<= 1) mx = fmaxf(mx, __shfl_xor(mx, o, 64));
      float rs = 0.f;
      #pragma unroll
      for (int kt = 0; kt < 4; ++kt) {
        float e = __expf(Sa[mt][kt][r] - mx);
        Sa[mt][kt][r] = e;
        rs += e;
      }
      #pragma unroll
      for (int o = 1; o <= 8; o <<= 1) rs += __shfl_xor(rs, o, 64);
      m_[mt][r] = mx;
      l_[mt][r] = rs;
    }
  }

  // PV in bf16 hi+lo (near-fp32 accuracy). P transposed via per-wave LDS.
  ushort_t* ps = Ps[wv];
  floatx4 Oa[3][4] = {};
  #pragma unroll
  for (int pass = 0; pass < 2; ++pass) {
    #pragma unroll
    for (int mt = 0; mt < 3; ++mt)
      #pragma unroll
      for (int kt = 0; kt < 4; ++kt)
        #pragma unroll
        for (int r = 0; r < 4; ++r) {
          float e = Sa[mt][kt][r];
          ushort_t hb = f2b(e);
          ps[(mt * 16 + quad * 4 + r) * 72 + kt * 16 + lr] = hb;
          Sa[mt][kt][r] = e - b2f(hb);  // residual for lo pass
        }
    #pragma unroll
    for (int kk = 0; kk < 2; ++kk) {
      bf16x8 pf[3];
      #pragma unroll
      for (int mt = 0; mt < 3; ++mt)
        pf[mt] = *(const bf16x8*)&ps[(mt * 16 + lr) * 72 + kk * 32 + quad * 8];
      #pragma unroll
      for (int nt = 0; nt < 4; ++nt) {
        ushort8_t vt;
        #pragma unroll
        for (int j = 0; j < 8; ++j)
          vt[j] = vs[(kk * 32 + quad * 8 + j) * 64 +
                     ((nt * 16 + lr) ^ (quad << 4))];
        bf16x8 vf = *(bf16x8*)&vt;
        #pragma unroll
        for (int mt = 0; mt < 3; ++mt)
          Oa[mt][nt] = __builtin_amdgcn_mfma_f32_16x16x32_bf16(
              pf[mt], vf, Oa[mt][nt], 0, 0, 0);
      }
    }
  }

  // store partial (u < U only; format matches attn_merge_k)
  float* pb = part + (size_t)(bh * (nblk * 2) + chunk) * U * 66;
  #pragma unroll
  for (int mt = 0; mt < 3; ++mt) {
    #pragma unroll
    for (int r = 0; r < 4; ++r) {
      int u = mt * 16 + quad * 4 + r;
      if (u < U) {
        #pragma unroll
        for (int nt = 0; nt < 4; ++nt)
          pb[(size_t)u * 66 + nt * 16 + lr] = Oa[mt][nt][r];
        if (lr == 0) {
          pb[(size_t)u * 66 + 64] = m_[mt][r];
          pb[(size_t)u * 66 + 65] = l_[mt][r];
        }
      }
    }
  }
}

__global__ __launch_bounds__(64) void attn_merge_k(
    const float* __restrict__ part, const int* __restrict__ Mtop,
    ushort_t* __restrict__ ctx, int Lx, int U, int nchunk) {
  int bu = blockIdx.x;
  int u = bu % U, bh = bu / U;
  int h = bh & 7, b = bh >> 3;
  int d = threadIdx.x;  // 64
  float M = -INFINITY;
  for (int c = 0; c < nchunk; ++c)
    M = fmaxf(M, part[((size_t)(bh * nchunk + c) * U + u) * 66 + 64]);
  float L = 0.f, O = 0.f;
  for (int c = 0; c < nchunk; ++c) {
    const float* pp = part + ((size_t)(bh * nchunk + c) * U + u) * 66;
    float w = __expf(pp[64] - M);
    L += pp[65] * w;
    O += pp[d] * w;
  }
  int qi = Mtop[bh * U + u];
  ctx[((size_t)b * Lx + qi) * DM + h * HD + d] = f2b(O / L);
}

// ---------------- batch-norm stats over two partials + bias ----------------
__global__ __launch_bounds__(256) void bn1_k(const float* __restrict__ Y0,
                                             const float* __restrict__ Y1,
                                             const float* __restrict__ cb,
                                             float* __restrict__ ps,
                                             float* __restrict__ pq) {
  int blk = blockIdx.x;
  int t = threadIdx.x;
  float cb0 = cb[t], cb1 = cb[t + 256];
  float s0 = 0, q0 = 0, s1 = 0, q1 = 0;
  const float* b0 = Y0 + (size_t)blk * 256 * DM;
  const float* b1 = Y1 + (size_t)blk * 256 * DM;
  for (int r = 0; r < 256; ++r) {
    float a = b0[(size_t)r * DM + t] + b1[(size_t)r * DM + t] + cb0;
    float b = b0[(size_t)r * DM + t + 256] + b1[(size_t)r * DM + t + 256] + cb1;
    s0 += a; q0 += a * a; s1 += b; q1 += b * b;
  }
  ps[blk * DM + t] = s0; ps[blk * DM + t + 256] = s1;
  pq[blk * DM + t] = q0; pq[blk * DM + t + 256] = q1;
}
__global__ __launch_bounds__(512) void bn2_k(const float* __restrict__ ps,
                                             const float* __restrict__ pq,
                                             float* __restrict__ mu,
                                             float* __restrict__ var) {
  int t = threadIdx.x;
  float s = 0, q = 0;
  #pragma unroll
  for (int c = 0; c < 32; ++c) { s += ps[c * DM + t]; q += pq[c * DM + t]; }
  float m = s * (1.0f / 8192.f);
  mu[t] = m;
  var[t] = q * (1.0f / 8192.f) - m * m;
}

// fused bn+elu+maxpool(k=3,s=2,pad=1) over two partials + bias
__global__ void bnpool_k(const float* __restrict__ Y0,
                         const float* __restrict__ Y1,
                         const float* __restrict__ cb,
                         const float* __restrict__ mu,
                         const float* __restrict__ var,
                         const float* __restrict__ g,
                         const float* __restrict__ be, float* __restrict__ O,
                         ushort_t* __restrict__ Ob) {
  size_t i = (size_t)blockIdx.x * 256 + threadIdx.x;  // 4*1024*512
  int c = (int)(i & 511);
  size_t row = i >> 9;
  int lo = (int)(row & 1023);
  int b = (int)(row >> 10);
  float sc = g[c] / sqrtf(var[c] + 1e-5f);
  float sh = be[c] - mu[c] * sc;
  float cbv = cb[c];
  int l0 = 2 * lo - 1;
  float m = -INFINITY;
  #pragma unroll
  for (int tt = 0; tt < 3; ++tt) {
    int l = l0 + tt;
    if (l >= 0 && l < 2048) {
      size_t off = ((size_t)b * 2048 + l) * DM + c;
      float v = (Y0[off] + Y1[off] + cbv) * sc + sh;
      v = v > 0.f ? v : expm1f(v);
      m = fmaxf(m, v);
    }
  }
  O[i] = m;
  Ob[i] = f2b(m);
}

// ---------------------------------------------------------------------------
extern "C" void kernel_launch(void* const* d_in, const int* in_sizes, int n_in,
                              void* d_out, int out_size, void* d_ws,
                              size_t ws_size, hipStream_t stream) {
  (void)in_sizes; (void)n_in; (void)out_size; (void)ws_size;
  const float* x_enc  = (const float*)d_in[0];
  const float* tok_w  = (const float*)d_in[1];
  const float* Wq     = (const float*)d_in[2];
  const float* bq     = (const float*)d_in[3];
  const float* Wk     = (const float*)d_in[4];
  const float* bk     = (const float*)d_in[5];
  const float* Wv     = (const float*)d_in[6];
  const float* bv     = (const float*)d_in[7];
  const float* Wo     = (const float*)d_in[8];
  const float* bo     = (const float*)d_in[9];
  const float* W1     = (const float*)d_in[10];
  const float* b1     = (const float*)d_in[11];
  const float* W2     = (const float*)d_in[12];
  const float* b2     = (const float*)d_in[13];
  const float* ln1_g  = (const float*)d_in[14];
  const float* ln1_b  = (const float*)d_in[15];
  const float* ln2_g  = (const float*)d_in[16];
  const float* ln2_b  = (const float*)d_in[17];
  const float* conv_w = (const float*)d_in[18];
  const float* conv_b = (const float*)d_in[19];
  const float* bn_g   = (const float*)d_in[20];
  const float* bn_b   = (const float*)d_in[21];
  const float* normf_g = (const float*)d_in[22];
  const float* normf_b = (const float*)d_in[23];
  const float* proj_w = (const float*)d_in[24];
  const float* proj_b = (const float*)d_in[25];
  float* out = (float*)d_out;
  float* ws = (float*)d_ws;

  // ---- fp32 workspace layout (float offsets) ----
  float* X    = ws;                    // 4,194,304
  float* Y2B  = ws + 4194304;          // 4,194,304 (split-K partial #2)
  float* SCR  = ws + 8388608;          // 8,388,608 (final-LN scratch)
  ushort_t* CTXb = (ushort_t*)(ws + 16777216);  // bf16 ctx
  float* Y2   = ws + 20971520;         // 4,194,304 (attn partials / partial #1)
  float* Mb   = ws + 25165824;         // 65,536
  float* MV   = ws + 25231360;         // 2,048
  float* MVP  = ws + 25233408;         // 32,768
  float* BNps = ws + 25266176;         // 16,384
  float* BNpq = ws + 25282560;         // 16,384
  float* BNmu = ws + 25298944;         // 512
  float* BNvr = ws + 25299456;         // 512
  float* ZB   = ws + 25299968;         // 512 (zero bias)
  float* BQKV = ws + 25300480;         // 3,072 (concat qkv bias, 2 layers)
  int*   IDX  = (int*)(ws + 25303552); // 81,920 (layer 0)
  int*   MT   = (int*)(ws + 25385472); // 1,280
  // ---- bf16 workspace ----
  ushort_t* U0   = (ushort_t*)(ws + 25386752);
  ushort_t* Xb   = U0;                 // 4,194,304
  ushort_t* Hb   = U0 + 4194304;       // 16,777,216 (FFN hidden)
  ushort_t* QKVb = Hb;                 // alias: bf16 QKV — live QKV-GEMM ->
                                       // attn, before FFN uses Hb
  ushort_t* Wqkvb= U0 + 20971520;      // 1,572,864
  ushort_t* Wob  = U0 + 22544384;      // 524,288
  ushort_t* W1b  = U0 + 23068672;      // 2,097,152
  ushort_t* W2b  = U0 + 25165824;      // 2,097,152
  ushort_t* Cwb  = U0 + 27262976;      // 786,432 ([d][t][i] layout)
  ushort_t* Twb  = U0 + 28049408;      // 49,152
  ushort_t* Atok = U0 + 28098560;      // 786,432
  float* PEf = ws + 39829248;          // 1,048,576 (PE table)
  float* PWt = ws + 40877824;          // 16,384 (transposed proj weight)
  int*   IDX2 = (int*)(ws + 40894208); // 35,840 (layer 1)

  // ---- single fused preamble launch (casts + tables + both idx sets) ----
  uint32_t s00, s01, s10, s11;
  {
    uint32_t kl0, kl1;
    threefry2x32(0u, 42u, 0u, 0u, &kl0, &kl1);
    threefry2x32(kl0, kl1, 0u, 1u, &s00, &s01);
    threefry2x32(0u, 42u, 0u, 1u, &kl0, &kl1);
    threefry2x32(kl0, kl1, 0u, 1u, &s10, &s11);
  }
  preamble_k<<<14922, 256, 0, stream>>>(
      Wq, Wk, Wv, Wo, W1, W2, tok_w, conv_w, proj_w, bq, bk, bv, x_enc,
      Wqkvb, Wob, W1b, W2b, Twb, Cwb, PWt, ZB, BQKV, PEf, Atok,
      IDX, IDX2, s00, s01, s10, s11);

  // token embedding GEMM (+PE): K=96
  mgemm_k<128, 0, 0, 2, 1, 1><<<256, 512, 0, stream>>>(
      Atok, Twb, ZB, X, nullptr, Xb, PEf, 4, DM, 96);

  for (int layer = 0; layer < 2; ++layer) {
    const int Lx = (layer == 0) ? 2048 : 1024;
    const int U  = (layer == 0) ? 40 : 35;
    const int M  = NB * Lx;
    const int Yt = M / 128;
    const int NCHT = Lx / 64;          // one 64-key chunk per wave
    const int NBLK = NCHT / 2;         // 2 waves per block
    const int* idxp = (layer == 0) ? IDX : IDX2;

    // fused QKV GEMM: bf16-only output
    mgemm_k<128, 0, 0, 1, 0, 1><<<12 * Yt, 512, 0, stream>>>(
        Xb, Wqkvb + (size_t)layer * 786432, BQKV + layer * 1536, nullptr,
        nullptr, QKVb, nullptr, 12, QS, DM);

    // ProbSparse attention (all bf16 QKV)
    if (layer == 0)
      qk_m_k<40><<<Lx, 256, 0, stream>>>(QKVb, idxp, Mb, Lx);
    else
      qk_m_k<35><<<Lx, 256, 0, stream>>>(QKVb, idxp, Mb, Lx);
    topk_k<<<NB * NH * (Lx >> 8), 1024, 0, stream>>>(Mb, MT, Lx, U);
    meanv1_k<<<NB * 16, 512, 0, stream>>>(QKVb, MVP, Lx);
    meanv2_k<<<NB, 512, 0, stream>>>(MVP, MV, Lx);
    fillctx_k<<<(M * DM / 4) / 256, 256, 0, stream>>>(CTXb, MV, Lx);
    attn_mfma_k<48><<<NB * NH * NBLK, 128, 0, stream>>>(QKVb, MT, Y2, Lx, U,
                                                        NBLK);
    attn_merge_k<<<NB * NH * U, 64, 0, stream>>>(Y2, MT, CTXb, Lx, U, NCHT);

    // output projection split-K x2 (raw partials) + residual+bias in LN1
    mgemm_k<128, 0, 0, 0, 0, 2><<<2 * 4 * Yt, 512, 0, stream>>>(
        CTXb, Wob + (size_t)layer * 262144, nullptr, Y2, Y2B, nullptr,
        nullptr, 4, DM, DM);
    ln_k<<<M, 128, 0, stream>>>(X, Y2, Y2B, bo + layer * DM,
                                ln1_g + layer * DM, ln1_b + layer * DM, X, Xb);

    // FFN1 (GELU fused; hidden kept in bf16)
    mgemm_k<128, 0, 1, 1, 0, 1><<<16 * Yt, 512, 0, stream>>>(
        Xb, W1b + (size_t)layer * 1048576, b1 + layer * 2048, nullptr, nullptr,
        Hb, nullptr, 16, 2048, DM);
    // FFN2 split-K x2 (raw partials) + residual+bias in LN2
    mgemm_k<128, 0, 0, 0, 0, 2><<<2 * 4 * Yt, 512, 0, stream>>>(
        Hb, W2b + (size_t)layer * 1048576, nullptr, Y2, Y2B, nullptr,
        nullptr, 4, DM, 2048);
    ln_k<<<M, 128, 0, stream>>>(X, Y2, Y2B, b2 + layer * DM,
                                ln2_g + layer * DM, ln2_b + layer * DM, X, Xb);

    if (layer == 0) {
      // distil conv as implicit GEMM, split-K x2; bias folded into bn stats
      mgemm_k<128, 1, 0, 0, 0, 2><<<2 * 4 * 64, 512, 0, stream>>>(
          Xb, Cwb, nullptr, Y2, Y2B, nullptr, nullptr, 4, DM, 1536);
      bn1_k<<<32, 256, 0, stream>>>(Y2, Y2B, conv_b, BNps, BNpq);
      bn2_k<<<1, 512, 0, stream>>>(BNps, BNpq, BNmu, BNvr);
      bnpool_k<<<(NB * 1024 * 512) / 256, 256, 0, stream>>>(
          Y2, Y2B, conv_b, BNmu, BNvr, bn_g, bn_b, X, Xb);
    }
  }

  // final LN + projection (N=32, fp32)
  ln_k<<<NB * 1024, 128, 0, stream>>>(X, nullptr, nullptr, nullptr, normf_g,
                                      normf_b, SCR, nullptr);
  proj_k<<<512, 256, 0, stream>>>(SCR, PWt, proj_b, out);
}

// Round 15
// 566.587 us; speedup vs baseline: 1.1336x; 1.0298x over previous
//
#include <hip/hip_runtime.h>
#include <cstdint>
#include <cmath>

// ---------------------------------------------------------------------------
// Informer encoder forward (B=4, L=2048, ENC_IN=32, D_MODEL=512, D_FF=2048,
// E_LAYERS=2, H=8, FACTOR=5).
// Round 31: two more launch fusions (R30 proved ~1.4us/launch):
// (1) qk_m + meanv1 -> qkmean_k (both only read QKVb, independent):
//     segmented grid; qk part = 512 thr covering two l's (wave w: b=w&3,
//     l=2*blk+(w>>2)); meanv1 body verbatim in the tail blocks.
// (2) final ln + proj -> lnprojf_k (projection is row-local): normalized
//     row -> LDS -> 32n x 4 k-slice dot products; removes the 16MB SCR
//     write + 16MB read (~5us HBM) and one launch.
// Rest = R30 best (583.5 us).
// ---------------------------------------------------------------------------

#define NB 4
#define DM 512
#define NH 8
#define HD 64
#define QS 1536  // QKV row stride

typedef unsigned short ushort_t;
typedef __bf16 bf16x8 __attribute__((ext_vector_type(8)));
typedef float floatx4 __attribute__((ext_vector_type(4)));
typedef unsigned short ushort8_t __attribute__((ext_vector_type(8)));

__device__ inline ushort_t f2b(float f) {
  uint32_t u = __float_as_uint(f);
  uint32_t r = (u + 0x7fffu + ((u >> 16) & 1u)) >> 16;
  return (ushort_t)r;
}
__device__ inline float b2f(ushort_t u) {
  return __uint_as_float((uint32_t)u << 16);
}

__host__ __device__ inline void threefry2x32(uint32_t k0, uint32_t k1,
                                             uint32_t c0, uint32_t c1,
                                             uint32_t* o0, uint32_t* o1) {
  uint32_t ks0 = k0, ks1 = k1, ks2 = k0 ^ k1 ^ 0x1BD11BDAu;
  uint32_t x0 = c0 + ks0;
  uint32_t x1 = c1 + ks1;
  const uint32_t rotA[4] = {13u, 15u, 26u, 6u};
  const uint32_t rotB[4] = {17u, 29u, 16u, 24u};
  uint32_t ks[3] = {ks0, ks1, ks2};
  #pragma unroll
  for (int i = 0; i < 5; ++i) {
    const uint32_t* r = (i & 1) ? rotB : rotA;
    #pragma unroll
    for (int j = 0; j < 4; ++j) {
      x0 += x1;
      x1 = (x1 << r[j]) | (x1 >> (32u - r[j]));
      x1 ^= x0;
    }
    x0 += ks[(i + 1) % 3];
    x1 += ks[(i + 2) % 3] + (uint32_t)(i + 1);
  }
  *o0 = x0; *o1 = x1;
}

// ---------------- fused preamble: all weight casts + tables + indices ------
__global__ void preamble_k(
    const float* __restrict__ Wq, const float* __restrict__ Wk,
    const float* __restrict__ Wv, const float* __restrict__ Wo,
    const float* __restrict__ W1, const float* __restrict__ W2,
    const float* __restrict__ tw, const float* __restrict__ conv_w,
    const float* __restrict__ proj_w, const float* __restrict__ bq,
    const float* __restrict__ bk, const float* __restrict__ bv,
    const float* __restrict__ xe, ushort_t* __restrict__ Wqkvb,
    ushort_t* __restrict__ oWo, ushort_t* __restrict__ oW1,
    ushort_t* __restrict__ oW2, ushort_t* __restrict__ otw,
    ushort_t* __restrict__ Cwb, float* __restrict__ PWt,
    float* __restrict__ ZB, float* __restrict__ BQKV,
    float* __restrict__ pe, ushort_t* __restrict__ Atok,
    int* __restrict__ idx0, int* __restrict__ idx1,
    uint32_t s00, uint32_t s01, uint32_t s10, uint32_t s11) {
  int gid = blockIdx.x * 256 + threadIdx.x;
  if (gid < 393216) {
    int ly = gid / 196608, r4 = gid - ly * 196608;
    int r = r4 >> 7, c4 = r4 & 127;
    int sel = r >> 9, srow = r & 511;
    const float* src = (sel == 0 ? Wq : sel == 1 ? Wk : Wv) + ly * 262144 +
                       srow * 512 + c4 * 4;
    float4 v = *(const float4*)src;
    ushort4 o;
    o.x = f2b(v.x); o.y = f2b(v.y); o.z = f2b(v.z); o.w = f2b(v.w);
    ((ushort4*)Wqkvb)[ly * 196608 + r * 128 + c4] = o;
  } else if (gid < 1585152) {
    int g = gid - 393216;
    const float* src;
    ushort4* dst;
    int i;
    if (g < 131072) { src = Wo; dst = (ushort4*)oWo; i = g; }
    else if (g < 655360) { src = W1; dst = (ushort4*)oW1; i = g - 131072; }
    else if (g < 1179648) { src = W2; dst = (ushort4*)oW2; i = g - 655360; }
    else { src = tw; dst = (ushort4*)otw; i = g - 1179648; }
    float4 v = ((const float4*)src)[i];
    ushort4 o;
    o.x = f2b(v.x); o.y = f2b(v.y); o.z = f2b(v.z); o.w = f2b(v.w);
    dst[i] = o;
  } else if (gid < 2371584) {
    int g = gid - 1585152;  // conv weight (D,I,3) -> bf16 (D,3,I)
    int d = g / 1536, r = g - d * 1536;
    int t = r >> 9, i = r & 511;
    Cwb[g] = f2b(conv_w[d * 1536 + i * 3 + t]);
  } else if (gid < 2387968) {
    int g = gid - 2371584;  // proj weight (32,512) -> (512,32) fp32
    int k = g >> 5, n = g & 31;
    PWt[g] = proj_w[n * 512 + k];
  } else if (gid < 2391552) {
    int g = gid - 2387968;  // ZB + concat qkv bias
    if (g < 512) { ZB[g] = 0.f; }
    else {
      int gg = g - 512;
      int layer = gg / 1536, r = gg - layer * 1536;
      float v;
      if (r < 512) v = bq[layer * 512 + r];
      else if (r < 1024) v = bk[layer * 512 + r - 512];
      else v = bv[layer * 512 + r - 1024];
      BQKV[gg] = v;
    }
  } else if (gid < 2915840) {
    int i = gid - 2391552;  // PE (sin,cos) pairs
    int d2 = i & 255, l = i >> 8;
    float div = __expf((float)(2 * d2) * -1.7988946039e-2f);
    float ang = (float)l * div;
    float s, c;
    __sincosf(ang, &s, &c);
    ((float2*)pe)[i] = make_float2(s, c);
  } else if (gid < 3702272) {
    int g = gid - 2915840;  // im2col for token conv
    int col = g % 96;
    int row = g / 96;
    int c = col / 3, t = col - c * 3;
    int b = row >> 11, l = row & 2047;
    int ls = (l + t - 1) & 2047;
    Atok[g] = f2b(xe[((size_t)b * 2048 + ls) * 32 + c]);
  } else if (gid < 3784192) {
    int i = gid - 3702272;  // gen_idx layer 0
    uint32_t o0, o1;
    threefry2x32(s00, s01, 0u, (uint32_t)i, &o0, &o1);
    idx0[i] = (int)((o0 ^ o1) & 2047u);
  } else if (gid < 3820032) {
    int i = gid - 3784192;  // gen_idx layer 1
    uint32_t o0, o1;
    threefry2x32(s10, s11, 0u, (uint32_t)i, &o0, &o1);
    idx1[i] = (int)((o0 ^ o1) & 1023u);
  }
}

__device__ inline float wave_sum64(float v) {
  #pragma unroll
  for (int o = 32; o > 0; o >>= 1) v += __shfl_xor(v, o, 64);
  return v;
}

// ---------------- bf16 MFMA GEMM: TM=128, in-row swizzle, counted vmcnt ----
__device__ inline void gload16(const ushort_t* g, ushort_t* l) {
  __builtin_amdgcn_global_load_lds(
      (const __attribute__((address_space(1))) unsigned int*)(const void*)g,
      (__attribute__((address_space(3))) unsigned int*)(void*)l, 16, 0, 0);
}

// CONV: A is Xb (B*L x 512 bf16); logical A[row][k] = Xb[(row_b, (l+t-1)%2048)][c]
// with t = k/512, c = k%512. Otherwise plain row-major A (M x K).
// SPLITK==2: both halves write RAW fp32 partials; consumers reduce.
template <int TM, int CONV, int GELU, int OMODE, int ADDPE, int SPLITK>
__global__ __launch_bounds__(512, 4) void mgemm_k(
    const ushort_t* __restrict__ A, const ushort_t* __restrict__ W,
    const float* __restrict__ bias, float* __restrict__ Cf,
    float* __restrict__ Cf2, ushort_t* __restrict__ Cb,
    const float* __restrict__ pe, int X, int ldc, int K) {
  constexpr int MT = TM / 64;        // acc row-tiles per wave (2 or 4)
  constexpr int AG = TM / 128;       // A gloads per wave per K-step (1 or 2)
  constexpr int BUFSZ = (TM + 128) * 32;  // ushorts per staging buffer
  constexpr int SHSZ = (3 * BUFSZ > 18432) ? 3 * BUFSZ : 18432;
  __shared__ __align__(16) ushort_t SH[SHSZ];
  int id = blockIdx.x;
  int half = 0;
  if (SPLITK == 2) {
    int nb = gridDim.x >> 1;
    if (id >= nb) { half = 1; id -= nb; }
  }
  int kbase = half * (K >> 1);
  int KK = (SPLITK == 2) ? (K >> 1) : K;
  int cc = id & 7, j = id >> 3;
  int bx = j % X;
  int by = (j / X) * 8 + cc;
  int m0 = by * TM, n0 = bx * 128;
  int t = threadIdx.x;
  int lane = t & 63, wv = t >> 6;  // 8 waves
  int rl = lane >> 2;
  int cl = ((lane & 3) ^ ((rl >> 1) & 3)) * 8;  // in-segment chunk swizzle
  int RaA = wv * (16 * AG);  // A rows staged per wave
  int RaB = wv * 16;         // B rows staged per wave
  const ushort_t* gA[AG];
  int cbv[AG], clrv[AG], lAoff[AG];
  #pragma unroll
  for (int g = 0; g < AG; ++g) {
    int ar = m0 + RaA + g * 16 + rl;
    gA[g] = A + (size_t)ar * K + kbase + cl;  // non-CONV path
    cbv[g] = ar >> 11;                        // CONV: batch
    clrv[g] = ar & 2047;                      // CONV: seq pos
    lAoff[g] = (RaA + g * 16) * 32;
  }
  const ushort_t* gB = W + (size_t)(n0 + RaB + rl) * K + kbase + cl;
  int lBoff = TM * 32 + RaB * 32;

  int quad = lane >> 4, lr = lane & 15;
  int qs = (quad ^ ((lr >> 1) & 3)) * 8;  // swizzled read chunk offset
  int wm = wv >> 1, wn = wv & 1;  // 4 (M) x 2 (N) waves, (TM/4)x64 each

  // stage K-step kst into LDS buffer buf (AG+1 vmem instructions per wave)
  auto STAGE = [&](int kst, int buf) {
    int bb = buf * BUFSZ;
    int ko = kst << 5;
    #pragma unroll
    for (int g = 0; g < AG; ++g) {
      if (CONV) {
        int kg = kbase + ko;
        int tt = kg >> 9;
        int c = (kg & 511) + cl;
        int ls = (clrv[g] + tt - 1) & 2047;
        gload16(A + ((size_t)(cbv[g] * 2048 + ls) * 512 + c),
                SH + bb + lAoff[g]);
      } else {
        gload16(gA[g] + ko, SH + bb + lAoff[g]);
      }
    }
    gload16(gB + ko, SH + bb + lBoff);
  };

  floatx4 acc[MT][4] = {};
  int nt = KK >> 5;
  STAGE(0, 0);
  if (nt > 1) STAGE(1, 1);
  int cur = 0;
  for (int it = 0; it < nt; ++it) {
    // counted wait: own stage(it) complete; stage(it+1) stays in flight
    if (it < nt - 1) {
      if constexpr (AG == 1)
        asm volatile("s_waitcnt vmcnt(2)" ::: "memory");
      else
        asm volatile("s_waitcnt vmcnt(3)" ::: "memory");
    } else {
      asm volatile("s_waitcnt vmcnt(0)" ::: "memory");
    }
    __builtin_amdgcn_s_barrier();        // all waves: stage(it) landed,
    __builtin_amdgcn_sched_barrier(0);   // prior-iter reads retired
    int nx = it + 2;
    if (nx < nt) {
      int nb3 = cur + 2;
      if (nb3 >= 3) nb3 -= 3;
      STAGE(nx, nb3);                    // buf last read at it-1: safe
    }
    const ushort_t* Ab = SH + cur * BUFSZ;
    const ushort_t* Bb = Ab + TM * 32;
    bf16x8 av[MT], bv[4];
    #pragma unroll
    for (int mt = 0; mt < MT; ++mt)
      av[mt] =
          *(const bf16x8*)&Ab[(wm * (16 * MT) + mt * 16 + lr) * 32 + qs];
    #pragma unroll
    for (int nt2 = 0; nt2 < 4; ++nt2)
      bv[nt2] = *(const bf16x8*)&Bb[(wn * 64 + nt2 * 16 + lr) * 32 + qs];
    #pragma unroll
    for (int mt = 0; mt < MT; ++mt)
      #pragma unroll
      for (int nt2 = 0; nt2 < 4; ++nt2)
        acc[mt][nt2] = __builtin_amdgcn_mfma_f32_16x16x32_bf16(
            av[mt], bv[nt2], acc[mt][nt2], 0, 0, 0);
    // all my LDS reads retired before next barrier (closes WAR window)
    asm volatile("s_waitcnt lgkmcnt(0)" ::: "memory");
    __builtin_amdgcn_sched_barrier(0);
    cur = (cur == 2) ? 0 : cur + 1;
  }
  __syncthreads();  // epilogue reuses SH

  if (SPLITK == 2) {
    // raw fp32 partial; bias applied by the consumer
    float* dst = half ? Cf2 : Cf;
    #pragma unroll
    for (int nt2 = 0; nt2 < 4; ++nt2) {
      int col = n0 + wn * 64 + nt2 * 16 + lr;
      #pragma unroll
      for (int mt = 0; mt < MT; ++mt) {
        int row0 = m0 + wm * (16 * MT) + mt * 16 + quad * 4;
        #pragma unroll
        for (int r = 0; r < 4; ++r)
          dst[(size_t)(row0 + r) * ldc + col] = acc[mt][nt2][r];
      }
    }
  } else if (OMODE == 0) {
    #pragma unroll
    for (int nt2 = 0; nt2 < 4; ++nt2) {
      int col = n0 + wn * 64 + nt2 * 16 + lr;
      float bsv = bias[col];
      #pragma unroll
      for (int mt = 0; mt < MT; ++mt) {
        int row0 = m0 + wm * (16 * MT) + mt * 16 + quad * 4;
        #pragma unroll
        for (int r = 0; r < 4; ++r) {
          int row = row0 + r;
          float v = acc[mt][nt2][r] + bsv;
          if (ADDPE) v += pe[(size_t)(row & 2047) * ldc + col];
          if (GELU) v = 0.5f * v * (1.0f + erff(v * 0.70710678118654752f));
          Cf[(size_t)row * ldc + col] = v;
        }
      }
    }
  } else {
    // bf16 through per-wave LDS transpose -> coalesced ushort8 stores.
    ushort_t* ep = SH + wv * 2304;
    #pragma unroll
    for (int p = 0; p < MT / 2; ++p) {
      #pragma unroll
      for (int nt2 = 0; nt2 < 4; ++nt2) {
        int col = n0 + wn * 64 + nt2 * 16 + lr;
        float bsv = bias[col];
        #pragma unroll
        for (int ml = 0; ml < 2; ++ml) {
          int mt = p * 2 + ml;
          #pragma unroll
          for (int r = 0; r < 4; ++r) {
            int row = m0 + wm * (16 * MT) + mt * 16 + quad * 4 + r;
            float v = acc[mt][nt2][r] + bsv;
            if (ADDPE) v += pe[(size_t)(row & 2047) * ldc + col];
            if (GELU) v = 0.5f * v * (1.0f + erff(v * 0.70710678118654752f));
            if (OMODE == 2) Cf[(size_t)row * ldc + col] = v;
            ep[(ml * 16 + quad * 4 + r) * 72 + nt2 * 16 + lr] = f2b(v);
          }
        }
      }
      int r8 = lane >> 3, c8 = (lane & 7) * 8;
      #pragma unroll
      for (int i = 0; i < 4; ++i) {
        int row = i * 8 + r8;
        ushort8_t vv = *(const ushort8_t*)&ep[row * 72 + c8];
        *(ushort8_t*)&Cb[(size_t)(m0 + wm * (16 * MT) + p * 32 + row) * ldc +
                         n0 + wn * 64 + c8] = vv;
      }
    }
  }
}

// ---------------- fused final LayerNorm + projection (row-local) -----------
// out[r][n] = (LN(A[r]) * g + be) @ Wt[:,n] + bias[n];  Wt is (512,32).
__global__ __launch_bounds__(128) void lnprojf_k(
    const float* __restrict__ A, const float* __restrict__ g,
    const float* __restrict__ be, const float* __restrict__ Wt,
    const float* __restrict__ bias, float* __restrict__ C) {
  int r = blockIdx.x, t = threadIdx.x;
  __shared__ float red[2];
  __shared__ float row[512];
  __shared__ float pacc[128];
  float4 v = ((const float4*)(A + (size_t)r * DM))[t];
  float s = wave_sum64(v.x + v.y + v.z + v.w);
  int w = t >> 6;
  if ((t & 63) == 0) red[w] = s;
  __syncthreads();
  float mu = (red[0] + red[1]) * (1.0f / 512.0f);
  __syncthreads();
  float dx = v.x - mu, dy = v.y - mu, dz = v.z - mu, dw = v.w - mu;
  float sq = wave_sum64(dx * dx + dy * dy + dz * dz + dw * dw);
  if ((t & 63) == 0) red[w] = sq;
  __syncthreads();
  float var = (red[0] + red[1]) * (1.0f / 512.0f);
  float inv = 1.0f / sqrtf(var + 1e-5f);
  float4 gv = ((const float4*)g)[t];
  float4 bv = ((const float4*)be)[t];
  float4 o;
  o.x = dx * inv * gv.x + bv.x;
  o.y = dy * inv * gv.y + bv.y;
  o.z = dz * inv * gv.z + bv.z;
  o.w = dw * inv * gv.w + bv.w;
  ((float4*)row)[t] = o;
  __syncthreads();
  int n = t & 31, ks = t >> 5;  // 4 k-slices of 128
  const float* rp = row + ks * 128;
  const float* wp = Wt + ks * 128 * 32 + n;
  float acc = 0.f;
  #pragma unroll 4
  for (int k = 0; k < 128; ++k) acc += rp[k] * wp[k * 32];
  pacc[t] = acc;
  __syncthreads();
  if (t < 32)
    C[(size_t)r * 32 + t] =
        (pacc[t] + pacc[t + 64]) + (pacc[t + 32] + pacc[t + 96]) + bias[t];
}

// ---------------- LayerNorm (+residuals, +col bias, +optional bf16 copy) ---
// O = LN(A + Bres + Bres2 + cbias) * g + be; Bres/Bres2/cbias nullable.
__global__ __launch_bounds__(128) void ln_k(
    const float* __restrict__ A, const float* __restrict__ Bres,
    const float* __restrict__ Bres2, const float* __restrict__ cbias,
    const float* __restrict__ g, const float* __restrict__ be,
    float* __restrict__ O, ushort_t* __restrict__ Ob) {
  int r = blockIdx.x, t = threadIdx.x;
  __shared__ float lds[2];
  float4 v = ((const float4*)(A + (size_t)r * DM))[t];
  if (Bres) {
    float4 u = ((const float4*)(Bres + (size_t)r * DM))[t];
    v.x += u.x; v.y += u.y; v.z += u.z; v.w += u.w;
  }
  if (Bres2) {
    float4 u = ((const float4*)(Bres2 + (size_t)r * DM))[t];
    v.x += u.x; v.y += u.y; v.z += u.z; v.w += u.w;
  }
  if (cbias) {
    float4 u = ((const float4*)cbias)[t];
    v.x += u.x; v.y += u.y; v.z += u.z; v.w += u.w;
  }
  float s = wave_sum64(v.x + v.y + v.z + v.w);
  int w = t >> 6;
  if ((t & 63) == 0) lds[w] = s;
  __syncthreads();
  float mu = (lds[0] + lds[1]) * (1.0f / 512.0f);
  __syncthreads();
  float dx = v.x - mu, dy = v.y - mu, dz = v.z - mu, dw = v.w - mu;
  float sq = wave_sum64(dx * dx + dy * dy + dz * dz + dw * dw);
  if ((t & 63) == 0) lds[w] = sq;
  __syncthreads();
  float var = (lds[0] + lds[1]) * (1.0f / 512.0f);
  float inv = 1.0f / sqrtf(var + 1e-5f);
  float4 gv = ((const float4*)g)[t];
  float4 bv = ((const float4*)be)[t];
  float4 o;
  o.x = dx * inv * gv.x + bv.x;
  o.y = dy * inv * gv.y + bv.y;
  o.z = dz * inv * gv.z + bv.z;
  o.w = dw * inv * gv.w + bv.w;
  ((float4*)(O + (size_t)r * DM))[t] = o;
  if (Ob) {
    ushort4 ob;
    ob.x = f2b(o.x); ob.y = f2b(o.y); ob.z = f2b(o.z); ob.w = f2b(o.w);
    ((ushort4*)(Ob + (size_t)r * DM))[t] = ob;
  }
}

// ---------------- fused M[b,h,l] + meanV stage 1 ---------------------------
// blocks [0, Lx/2): qk_m for two l's (wave w: b = w&3, l = 2*blk + (w>>2)).
// blocks [Lx/2, Lx/2 + 64): meanv1 body (b = c>>4, chunk = c&15).
template <int UU>
__global__ __launch_bounds__(512) void qkmean_k(
    const ushort_t* __restrict__ QKVb, const int* __restrict__ idx,
    float* __restrict__ Mout, float* __restrict__ part, int Lx) {
  int qkb = Lx >> 1;
  int t = threadIdx.x;
  if ((int)blockIdx.x < qkb) {
    int wv = t >> 6, lane = t & 63;
    int b = wv & 3;
    int l = ((int)blockIdx.x << 1) + (wv >> 2);
    const ushort_t* qp = QKVb + ((size_t)b * Lx + l) * QS + lane * 8;
    float q[8];
    {
      ushort8_t qv = *(const ushort8_t*)qp;
      #pragma unroll
      for (int c = 0; c < 8; ++c) q[c] = b2f(qv[c]);
    }
    const ushort_t* Kbase = QKVb + (size_t)b * Lx * QS + 512 + lane * 8;
    const int* ip = idx + (size_t)l * UU;
    float maxv = -INFINITY, sumv = 0.f;
    #pragma unroll
    for (int u0 = 0; u0 < UU; u0 += 8) {
      ushort8_t kv[8];
      #pragma unroll
      for (int j = 0; j < 8; ++j) {
        if (u0 + j < UU)
          kv[j] = *(const ushort8_t*)(Kbase + (size_t)ip[u0 + j] * QS);
      }
      #pragma unroll
      for (int j = 0; j < 8; ++j) {
        if (u0 + j < UU) {
          float p = 0.f;
          #pragma unroll
          for (int c = 0; c < 8; ++c) p += q[c] * b2f(kv[j][c]);
          p += __shfl_xor(p, 1, 64);
          p += __shfl_xor(p, 2, 64);
          p += __shfl_xor(p, 4, 64);
          maxv = fmaxf(maxv, p);
          sumv += p;
        }
      }
    }
    if ((lane & 7) == 0) {
      int h = lane >> 3;
      Mout[(size_t)(b * 8 + h) * Lx + l] = maxv - sumv / (float)Lx;
    }
  } else {
    int blkc = (int)blockIdx.x - qkb;  // 0..63
    int b = blkc >> 4, chunk = blkc & 15;
    int rows = Lx >> 4;
    const ushort_t* vp =
        QKVb + ((size_t)b * Lx + (size_t)chunk * rows) * QS + 1024 + t;
    float s = 0.f;
    for (int l = 0; l < rows; ++l) s += b2f(vp[(size_t)l * QS]);
    part[(size_t)blkc * DM + t] = s;
  }
}

// ---------------- rank-based top-U, 4-way scan split (JAX tie-break) -------
__global__ __launch_bounds__(1024) void topk_k(
    const float* __restrict__ Mbuf, int* __restrict__ Mtop, int Lx, int U) {
  int nch = Lx >> 8;
  int bh = blockIdx.x / nch, ch = blockIdx.x % nch;
  const float* m = Mbuf + (size_t)bh * Lx;
  __shared__ float sm[2048];
  __shared__ int part[1024];
  int t = threadIdx.x;
  int c = t & 255, q = t >> 8;
  for (int i = t; i < Lx; i += 1024) sm[i] = m[i];
  __syncthreads();
  int i0 = (ch << 8) + c;
  float v0 = sm[i0];
  int r0 = 0;
  int qlen = Lx >> 2;
  int j0 = q * qlen, j1 = j0 + qlen;
  for (int j = j0; j < j1; j += 4) {
    float4 mj = *(const float4*)&sm[j];
    r0 += (mj.x > v0) || (mj.x == v0 && (j + 0) < i0);
    r0 += (mj.y > v0) || (mj.y == v0 && (j + 1) < i0);
    r0 += (mj.z > v0) || (mj.z == v0 && (j + 2) < i0);
    r0 += (mj.w > v0) || (mj.w == v0 && (j + 3) < i0);
  }
  part[t] = r0;
  __syncthreads();
  if (q == 0) {
    int r = part[c] + part[c + 256] + part[c + 512] + part[c + 768];
    if (r < U) Mtop[bh * U + r] = i0;
  }
}

// ---------------- meanV stage 2 --------------------------------------------
__global__ __launch_bounds__(512) void meanv2_k(const float* __restrict__ part,
                                                float* __restrict__ mv,
                                                int Lx) {
  int b = blockIdx.x, t = threadIdx.x;
  float s = 0.f;
  #pragma unroll
  for (int c = 0; c < 16; ++c) s += part[(size_t)(b * 16 + c) * DM + t];
  mv[b * DM + t] = s / (float)Lx;
}

__global__ void fillctx_k(ushort_t* __restrict__ ctx,
                          const float* __restrict__ mv, int Lx) {
  size_t i4 = (size_t)blockIdx.x * 256 + threadIdx.x;
  int col4 = (int)(i4 & 127);
  size_t row = i4 >> 7;
  int b = (int)(row / (size_t)Lx);
  const float* m = mv + b * DM + col4 * 4;
  ushort4 o;
  o.x = f2b(m[0]); o.y = f2b(m[1]); o.z = f2b(m[2]); o.w = f2b(m[3]);
  ((ushort4*)ctx)[i4] = o;
}

// ---------------- one-shot MFMA attention (wave = one 64-key chunk) --------
// 2 waves/block (128 thr): waves fully independent.
template <int UP>  // padded query count (48 >= U)
__global__ __launch_bounds__(128) void attn_mfma_k(
    const ushort_t* __restrict__ QKVb, const int* __restrict__ Mtop,
    float* __restrict__ part, int Lx, int U, int nblk) {
  __shared__ ushort_t Ps[2][UP * 72];   // P transpose buf (stride 72 elems)
  __shared__ ushort_t Vs[2][64 * 64];   // V tile, xor-swizzled
  int bh = blockIdx.x / nblk, blkc = blockIdx.x % nblk;
  int h = bh & 7, b = bh >> 3;
  int t = threadIdx.x;
  int wv = t >> 6, lane = t & 63;
  int quad = lane >> 4, lr = lane & 15;
  int chunk = blkc * 2 + wv;
  int k0 = chunk * 64;
  const ushort_t* Qb = QKVb + (size_t)b * Lx * QS + h * HD;
  const ushort_t* Kb = Qb + 512;
  const ushort_t* Vb = Qb + 1024;

  // Q fragments: rows gathered via Mtop (clamped for padded rows)
  bf16x8 qf[3][2];
  #pragma unroll
  for (int mt = 0; mt < 3; ++mt) {
    int u = mt * 16 + lr;
    int qi = Mtop[bh * U + (u < U ? u : U - 1)];
    const ushort_t* qp = Qb + (size_t)qi * QS + quad * 8;
    qf[mt][0] = *(const bf16x8*)qp;
    qf[mt][1] = *(const bf16x8*)(qp + 32);
  }

  // stage V tile (64 rows x 64 d), xor-swizzle so column reads are
  // conflict-free: elem addr = k*64 + (d ^ (((k>>3)&3)<<4))
  ushort_t* vs = Vs[wv];
  #pragma unroll
  for (int i = 0; i < 8; ++i) {
    int cid = i * 64 + lane;
    int k = cid >> 3, c = cid & 7;
    ushort8_t v = *(const ushort8_t*)(Vb + (size_t)(k0 + k) * QS + c * 8);
    *(ushort8_t*)&vs[k * 64 + ((c * 8) ^ (((k >> 3) & 3) << 4))] = v;
  }

  // S = Q K^T (K frags direct from global)
  floatx4 Sa[3][4] = {};
  #pragma unroll
  for (int kt = 0; kt < 4; ++kt) {
    const ushort_t* kp = Kb + (size_t)(k0 + kt * 16 + lr) * QS + quad * 8;
    bf16x8 kf0 = *(const bf16x8*)kp;
    bf16x8 kf1 = *(const bf16x8*)(kp + 32);
    #pragma unroll
    for (int mt = 0; mt < 3; ++mt) {
      Sa[mt][kt] = __builtin_amdgcn_mfma_f32_16x16x32_bf16(
          qf[mt][0], kf0, Sa[mt][kt], 0, 0, 0);
      Sa[mt][kt] = __builtin_amdgcn_mfma_f32_16x16x32_bf16(
          qf[mt][1], kf1, Sa[mt][kt], 0, 0, 0);
    }
  }

  // softmax over the 64 local keys (rows u = mt*16 + quad*4 + r, col = lr)
  float m_[3][4], l_[3][4];
  #pragma unroll
  for (int mt = 0; mt < 3; ++mt) {
    #pragma unroll
    for (int kt = 0; kt < 4; ++kt) Sa[mt][kt] *= 0.125f;
    #pragma unroll
    for (int r = 0; r < 4; ++r) {
      float mx = fmaxf(fmaxf(Sa[mt][0][r], Sa[mt][1][r]),
                       fmaxf(Sa[mt][2][r], Sa[mt][3][r]));
      #pragma unroll
      for (int o = 1; o <= 8; o <<= 1) mx = fmaxf(mx, __shfl_xor(mx, o, 64));
      float rs = 0.f;
      #pragma unroll
      for (int kt = 0; kt < 4; ++kt) {
        float e = __expf(Sa[mt][kt][r] - mx);
        Sa[mt][kt][r] = e;
        rs += e;
      }
      #pragma unroll
      for (int o = 1; o <= 8; o <<= 1) rs += __shfl_xor(rs, o, 64);
      m_[mt][r] = mx;
      l_[mt][r] = rs;
    }
  }

  // PV in bf16 hi+lo (near-fp32 accuracy). P transposed via per-wave LDS.
  ushort_t* ps = Ps[wv];
  floatx4 Oa[3][4] = {};
  #pragma unroll
  for (int pass = 0; pass < 2; ++pass) {
    #pragma unroll
    for (int mt = 0; mt < 3; ++mt)
      #pragma unroll
      for (int kt = 0; kt < 4; ++kt)
        #pragma unroll
        for (int r = 0; r < 4; ++r) {
          float e = Sa[mt][kt][r];
          ushort_t hb = f2b(e);
          ps[(mt * 16 + quad * 4 + r) * 72 + kt * 16 + lr] = hb;
          Sa[mt][kt][r] = e - b2f(hb);  // residual for lo pass
        }
    #pragma unroll
    for (int kk = 0; kk < 2; ++kk) {
      bf16x8 pf[3];
      #pragma unroll
      for (int mt = 0; mt < 3; ++mt)
        pf[mt] = *(const bf16x8*)&ps[(mt * 16 + lr) * 72 + kk * 32 + quad * 8];
      #pragma unroll
      for (int nt = 0; nt < 4; ++nt) {
        ushort8_t vt;
        #pragma unroll
        for (int j = 0; j < 8; ++j)
          vt[j] = vs[(kk * 32 + quad * 8 + j) * 64 +
                     ((nt * 16 + lr) ^ (quad << 4))];
        bf16x8 vf = *(bf16x8*)&vt;
        #pragma unroll
        for (int mt = 0; mt < 3; ++mt)
          Oa[mt][nt] = __builtin_amdgcn_mfma_f32_16x16x32_bf16(
              pf[mt], vf, Oa[mt][nt], 0, 0, 0);
      }
    }
  }

  // store partial (u < U only; format matches attn_merge_k)
  float* pb = part + (size_t)(bh * (nblk * 2) + chunk) * U * 66;
  #pragma unroll
  for (int mt = 0; mt < 3; ++mt) {
    #pragma unroll
    for (int r = 0; r < 4; ++r) {
      int u = mt * 16 + quad * 4 + r;
      if (u < U) {
        #pragma unroll
        for (int nt = 0; nt < 4; ++nt)
          pb[(size_t)u * 66 + nt * 16 + lr] = Oa[mt][nt][r];
        if (lr == 0) {
          pb[(size_t)u * 66 + 64] = m_[mt][r];
          pb[(size_t)u * 66 + 65] = l_[mt][r];
        }
      }
    }
  }
}

__global__ __launch_bounds__(64) void attn_merge_k(
    const float* __restrict__ part, const int* __restrict__ Mtop,
    ushort_t* __restrict__ ctx, int Lx, int U, int nchunk) {
  int bu = blockIdx.x;
  int u = bu % U, bh = bu / U;
  int h = bh & 7, b = bh >> 3;
  int d = threadIdx.x;  // 64
  float M = -INFINITY;
  for (int c = 0; c < nchunk; ++c)
    M = fmaxf(M, part[((size_t)(bh * nchunk + c) * U + u) * 66 + 64]);
  float L = 0.f, O = 0.f;
  for (int c = 0; c < nchunk; ++c) {
    const float* pp = part + ((size_t)(bh * nchunk + c) * U + u) * 66;
    float w = __expf(pp[64] - M);
    L += pp[65] * w;
    O += pp[d] * w;
  }
  int qi = Mtop[bh * U + u];
  ctx[((size_t)b * Lx + qi) * DM + h * HD + d] = f2b(O / L);
}

// ---------------- batch-norm stats over two partials + bias ----------------
__global__ __launch_bounds__(256) void bn1_k(const float* __restrict__ Y0,
                                             const float* __restrict__ Y1,
                                             const float* __restrict__ cb,
                                             float* __restrict__ ps,
                                             float* __restrict__ pq) {
  int blk = blockIdx.x;
  int t = threadIdx.x;
  float cb0 = cb[t], cb1 = cb[t + 256];
  float s0 = 0, q0 = 0, s1 = 0, q1 = 0;
  const float* b0 = Y0 + (size_t)blk * 256 * DM;
  const float* b1 = Y1 + (size_t)blk * 256 * DM;
  for (int r = 0; r < 256; ++r) {
    float a = b0[(size_t)r * DM + t] + b1[(size_t)r * DM + t] + cb0;
    float b = b0[(size_t)r * DM + t + 256] + b1[(size_t)r * DM + t + 256] + cb1;
    s0 += a; q0 += a * a; s1 += b; q1 += b * b;
  }
  ps[blk * DM + t] = s0; ps[blk * DM + t + 256] = s1;
  pq[blk * DM + t] = q0; pq[blk * DM + t + 256] = q1;
}
__global__ __launch_bounds__(512) void bn2_k(const float* __restrict__ ps,
                                             const float* __restrict__ pq,
                                             float* __restrict__ mu,
                                             float* __restrict__ var) {
  int t = threadIdx.x;
  float s = 0, q = 0;
  #pragma unroll
  for (int c = 0; c < 32; ++c) { s += ps[c * DM + t]; q += pq[c * DM + t]; }
  float m = s * (1.0f / 8192.f);
  mu[t] = m;
  var[t] = q * (1.0f / 8192.f) - m * m;
}

// fused bn+elu+maxpool(k=3,s=2,pad=1) over two partials + bias
__global__ void bnpool_k(const float* __restrict__ Y0,
                         const float* __restrict__ Y1,
                         const float* __restrict__ cb,
                         const float* __restrict__ mu,
                         const float* __restrict__ var,
                         const float* __restrict__ g,
                         const float* __restrict__ be, float* __restrict__ O,
                         ushort_t* __restrict__ Ob) {
  size_t i = (size_t)blockIdx.x * 256 + threadIdx.x;  // 4*1024*512
  int c = (int)(i & 511);
  size_t row = i >> 9;
  int lo = (int)(row & 1023);
  int b = (int)(row >> 10);
  float sc = g[c] / sqrtf(var[c] + 1e-5f);
  float sh = be[c] - mu[c] * sc;
  float cbv = cb[c];
  int l0 = 2 * lo - 1;
  float m = -INFINITY;
  #pragma unroll
  for (int tt = 0; tt < 3; ++tt) {
    int l = l0 + tt;
    if (l >= 0 && l < 2048) {
      size_t off = ((size_t)b * 2048 + l) * DM + c;
      float v = (Y0[off] + Y1[off] + cbv) * sc + sh;
      v = v > 0.f ? v : expm1f(v);
      m = fmaxf(m, v);
    }
  }
  O[i] = m;
  Ob[i] = f2b(m);
}

// ---------------------------------------------------------------------------
extern "C" void kernel_launch(void* const* d_in, const int* in_sizes, int n_in,
                              void* d_out, int out_size, void* d_ws,
                              size_t ws_size, hipStream_t stream) {
  (void)in_sizes; (void)n_in; (void)out_size; (void)ws_size;
  const float* x_enc  = (const float*)d_in[0];
  const float* tok_w  = (const float*)d_in[1];
  const float* Wq     = (const float*)d_in[2];
  const float* bq     = (const float*)d_in[3];
  const float* Wk     = (const float*)d_in[4];
  const float* bk     = (const float*)d_in[5];
  const float* Wv     = (const float*)d_in[6];
  const float* bv     = (const float*)d_in[7];
  const float* Wo     = (const float*)d_in[8];
  const float* bo     = (const float*)d_in[9];
  const float* W1     = (const float*)d_in[10];
  const float* b1     = (const float*)d_in[11];
  const float* W2     = (const float*)d_in[12];
  const float* b2     = (const float*)d_in[13];
  const float* ln1_g  = (const float*)d_in[14];
  const float* ln1_b  = (const float*)d_in[15];
  const float* ln2_g  = (const float*)d_in[16];
  const float* ln2_b  = (const float*)d_in[17];
  const float* conv_w = (const float*)d_in[18];
  const float* conv_b = (const float*)d_in[19];
  const float* bn_g   = (const float*)d_in[20];
  const float* bn_b   = (const float*)d_in[21];
  const float* normf_g = (const float*)d_in[22];
  const float* normf_b = (const float*)d_in[23];
  const float* proj_w = (const float*)d_in[24];
  const float* proj_b = (const float*)d_in[25];
  float* out = (float*)d_out;
  float* ws = (float*)d_ws;

  // ---- fp32 workspace layout (float offsets) ----
  float* X    = ws;                    // 4,194,304
  float* Y2B  = ws + 4194304;          // 4,194,304 (split-K partial #2)
  ushort_t* CTXb = (ushort_t*)(ws + 16777216);  // bf16 ctx
  float* Y2   = ws + 20971520;         // 4,194,304 (attn partials / partial #1)
  float* Mb   = ws + 25165824;         // 65,536
  float* MV   = ws + 25231360;         // 2,048
  float* MVP  = ws + 25233408;         // 32,768
  float* BNps = ws + 25266176;         // 16,384
  float* BNpq = ws + 25282560;         // 16,384
  float* BNmu = ws + 25298944;         // 512
  float* BNvr = ws + 25299456;         // 512
  float* ZB   = ws + 25299968;         // 512 (zero bias)
  float* BQKV = ws + 25300480;         // 3,072 (concat qkv bias, 2 layers)
  int*   IDX  = (int*)(ws + 25303552); // 81,920 (layer 0)
  int*   MT   = (int*)(ws + 25385472); // 1,280
  // ---- bf16 workspace ----
  ushort_t* U0   = (ushort_t*)(ws + 25386752);
  ushort_t* Xb   = U0;                 // 4,194,304
  ushort_t* Hb   = U0 + 4194304;       // 16,777,216 (FFN hidden)
  ushort_t* QKVb = Hb;                 // alias: bf16 QKV — live QKV-GEMM ->
                                       // attn, before FFN uses Hb
  ushort_t* Wqkvb= U0 + 20971520;      // 1,572,864
  ushort_t* Wob  = U0 + 22544384;      // 524,288
  ushort_t* W1b  = U0 + 23068672;      // 2,097,152
  ushort_t* W2b  = U0 + 25165824;      // 2,097,152
  ushort_t* Cwb  = U0 + 27262976;      // 786,432 ([d][t][i] layout)
  ushort_t* Twb  = U0 + 28049408;      // 49,152
  ushort_t* Atok = U0 + 28098560;      // 786,432
  float* PEf = ws + 39829248;          // 1,048,576 (PE table)
  float* PWt = ws + 40877824;          // 16,384 (transposed proj weight)
  int*   IDX2 = (int*)(ws + 40894208); // 35,840 (layer 1)

  // ---- single fused preamble launch (casts + tables + both idx sets) ----
  uint32_t s00, s01, s10, s11;
  {
    uint32_t kl0, kl1;
    threefry2x32(0u, 42u, 0u, 0u, &kl0, &kl1);
    threefry2x32(kl0, kl1, 0u, 1u, &s00, &s01);
    threefry2x32(0u, 42u, 0u, 1u, &kl0, &kl1);
    threefry2x32(kl0, kl1, 0u, 1u, &s10, &s11);
  }
  preamble_k<<<14922, 256, 0, stream>>>(
      Wq, Wk, Wv, Wo, W1, W2, tok_w, conv_w, proj_w, bq, bk, bv, x_enc,
      Wqkvb, Wob, W1b, W2b, Twb, Cwb, PWt, ZB, BQKV, PEf, Atok,
      IDX, IDX2, s00, s01, s10, s11);

  // token embedding GEMM (+PE): K=96
  mgemm_k<128, 0, 0, 2, 1, 1><<<256, 512, 0, stream>>>(
      Atok, Twb, ZB, X, nullptr, Xb, PEf, 4, DM, 96);

  for (int layer = 0; layer < 2; ++layer) {
    const int Lx = (layer == 0) ? 2048 : 1024;
    const int U  = (layer == 0) ? 40 : 35;
    const int M  = NB * Lx;
    const int Yt = M / 128;
    const int NCHT = Lx / 64;          // one 64-key chunk per wave
    const int NBLK = NCHT / 2;         // 2 waves per block
    const int* idxp = (layer == 0) ? IDX : IDX2;

    // fused QKV GEMM: bf16-only output
    mgemm_k<128, 0, 0, 1, 0, 1><<<12 * Yt, 512, 0, stream>>>(
        Xb, Wqkvb + (size_t)layer * 786432, BQKV + layer * 1536, nullptr,
        nullptr, QKVb, nullptr, 12, QS, DM);

    // ProbSparse attention (all bf16 QKV); qk_m + meanv1 fused
    if (layer == 0)
      qkmean_k<40><<<Lx / 2 + 64, 512, 0, stream>>>(QKVb, idxp, Mb, MVP, Lx);
    else
      qkmean_k<35><<<Lx / 2 + 64, 512, 0, stream>>>(QKVb, idxp, Mb, MVP, Lx);
    topk_k<<<NB * NH * (Lx >> 8), 1024, 0, stream>>>(Mb, MT, Lx, U);
    meanv2_k<<<NB, 512, 0, stream>>>(MVP, MV, Lx);
    fillctx_k<<<(M * DM / 4) / 256, 256, 0, stream>>>(CTXb, MV, Lx);
    attn_mfma_k<48><<<NB * NH * NBLK, 128, 0, stream>>>(QKVb, MT, Y2, Lx, U,
                                                        NBLK);
    attn_merge_k<<<NB * NH * U, 64, 0, stream>>>(Y2, MT, CTXb, Lx, U, NCHT);

    // output projection split-K x2 (raw partials) + residual+bias in LN1
    mgemm_k<128, 0, 0, 0, 0, 2><<<2 * 4 * Yt, 512, 0, stream>>>(
        CTXb, Wob + (size_t)layer * 262144, nullptr, Y2, Y2B, nullptr,
        nullptr, 4, DM, DM);
    ln_k<<<M, 128, 0, stream>>>(X, Y2, Y2B, bo + layer * DM,
                                ln1_g + layer * DM, ln1_b + layer * DM, X, Xb);

    // FFN1 (GELU fused; hidden kept in bf16)
    mgemm_k<128, 0, 1, 1, 0, 1><<<16 * Yt, 512, 0, stream>>>(
        Xb, W1b + (size_t)layer * 1048576, b1 + layer * 2048, nullptr, nullptr,
        Hb, nullptr, 16, 2048, DM);
    // FFN2 split-K x2 (raw partials) + residual+bias in LN2
    mgemm_k<128, 0, 0, 0, 0, 2><<<2 * 4 * Yt, 512, 0, stream>>>(
        Hb, W2b + (size_t)layer * 1048576, nullptr, Y2, Y2B, nullptr,
        nullptr, 4, DM, 2048);
    ln_k<<<M, 128, 0, stream>>>(X, Y2, Y2B, b2 + layer * DM,
                                ln2_g + layer * DM, ln2_b + layer * DM, X, Xb);

    if (layer == 0) {
      // distil conv as implicit GEMM, split-K x2; bias folded into bn stats
      mgemm_k<128, 1, 0, 0, 0, 2><<<2 * 4 * 64, 512, 0, stream>>>(
          Xb, Cwb, nullptr, Y2, Y2B, nullptr, nullptr, 4, DM, 1536);
      bn1_k<<<32, 256, 0, stream>>>(Y2, Y2B, conv_b, BNps, BNpq);
      bn2_k<<<1, 512, 0, stream>>>(BNps, BNpq, BNmu, BNvr);
      bnpool_k<<<(NB * 1024 * 512) / 256, 256, 0, stream>>>(
          Y2, Y2B, conv_b, BNmu, BNvr, bn_g, bn_b, X, Xb);
    }
  }

  // fused final LN + projection (row-local; no SCR round-trip)
  lnprojf_k<<<NB * 1024, 128, 0, stream>>>(X, normf_g, normf_b, PWt, proj_b,
                                           out);
}

// Round 16
// 548.373 us; speedup vs baseline: 1.1713x; 1.0332x over previous
//
#include <hip/hip_runtime.h>
#include <cstdint>
#include <cmath>

// ---------------------------------------------------------------------------
// Informer encoder forward (B=4, L=2048, ENC_IN=32, D_MODEL=512, D_FF=2048,
// E_LAYERS=2, H=8, FACTOR=5).
// Round 32: qkmean K-gather L2 fix. Counter: FETCH_SIZE 98.7MB @1.7TB/s for
// a 335MB-logical gather over an 8MB K-set -> per-XCD L2 (4MB, not shared)
// thrashes because each block's waves spanned all 4 batches (b = w&3).
// New map batch-partitions by XCD: b = (blk&7)>>1 (XCDs {2b,2b+1} serve
// only batch b under round-robin block->XCD), waves = 8 consecutive l of
// that batch (l = 8*((blk>>3)*2+(blk&1)) + w). Working set/XCD: 8MB -> 2MB.
// Same math, bijective coverage, XCD map is speed-only. Rest = R31 (566.6).
// ---------------------------------------------------------------------------

#define NB 4
#define DM 512
#define NH 8
#define HD 64
#define QS 1536  // QKV row stride

typedef unsigned short ushort_t;
typedef __bf16 bf16x8 __attribute__((ext_vector_type(8)));
typedef float floatx4 __attribute__((ext_vector_type(4)));
typedef unsigned short ushort8_t __attribute__((ext_vector_type(8)));

__device__ inline ushort_t f2b(float f) {
  uint32_t u = __float_as_uint(f);
  uint32_t r = (u + 0x7fffu + ((u >> 16) & 1u)) >> 16;
  return (ushort_t)r;
}
__device__ inline float b2f(ushort_t u) {
  return __uint_as_float((uint32_t)u << 16);
}

__host__ __device__ inline void threefry2x32(uint32_t k0, uint32_t k1,
                                             uint32_t c0, uint32_t c1,
                                             uint32_t* o0, uint32_t* o1) {
  uint32_t ks0 = k0, ks1 = k1, ks2 = k0 ^ k1 ^ 0x1BD11BDAu;
  uint32_t x0 = c0 + ks0;
  uint32_t x1 = c1 + ks1;
  const uint32_t rotA[4] = {13u, 15u, 26u, 6u};
  const uint32_t rotB[4] = {17u, 29u, 16u, 24u};
  uint32_t ks[3] = {ks0, ks1, ks2};
  #pragma unroll
  for (int i = 0; i < 5; ++i) {
    const uint32_t* r = (i & 1) ? rotB : rotA;
    #pragma unroll
    for (int j = 0; j < 4; ++j) {
      x0 += x1;
      x1 = (x1 << r[j]) | (x1 >> (32u - r[j]));
      x1 ^= x0;
    }
    x0 += ks[(i + 1) % 3];
    x1 += ks[(i + 2) % 3] + (uint32_t)(i + 1);
  }
  *o0 = x0; *o1 = x1;
}

// ---------------- fused preamble: all weight casts + tables + indices ------
__global__ void preamble_k(
    const float* __restrict__ Wq, const float* __restrict__ Wk,
    const float* __restrict__ Wv, const float* __restrict__ Wo,
    const float* __restrict__ W1, const float* __restrict__ W2,
    const float* __restrict__ tw, const float* __restrict__ conv_w,
    const float* __restrict__ proj_w, const float* __restrict__ bq,
    const float* __restrict__ bk, const float* __restrict__ bv,
    const float* __restrict__ xe, ushort_t* __restrict__ Wqkvb,
    ushort_t* __restrict__ oWo, ushort_t* __restrict__ oW1,
    ushort_t* __restrict__ oW2, ushort_t* __restrict__ otw,
    ushort_t* __restrict__ Cwb, float* __restrict__ PWt,
    float* __restrict__ ZB, float* __restrict__ BQKV,
    float* __restrict__ pe, ushort_t* __restrict__ Atok,
    int* __restrict__ idx0, int* __restrict__ idx1,
    uint32_t s00, uint32_t s01, uint32_t s10, uint32_t s11) {
  int gid = blockIdx.x * 256 + threadIdx.x;
  if (gid < 393216) {
    int ly = gid / 196608, r4 = gid - ly * 196608;
    int r = r4 >> 7, c4 = r4 & 127;
    int sel = r >> 9, srow = r & 511;
    const float* src = (sel == 0 ? Wq : sel == 1 ? Wk : Wv) + ly * 262144 +
                       srow * 512 + c4 * 4;
    float4 v = *(const float4*)src;
    ushort4 o;
    o.x = f2b(v.x); o.y = f2b(v.y); o.z = f2b(v.z); o.w = f2b(v.w);
    ((ushort4*)Wqkvb)[ly * 196608 + r * 128 + c4] = o;
  } else if (gid < 1585152) {
    int g = gid - 393216;
    const float* src;
    ushort4* dst;
    int i;
    if (g < 131072) { src = Wo; dst = (ushort4*)oWo; i = g; }
    else if (g < 655360) { src = W1; dst = (ushort4*)oW1; i = g - 131072; }
    else if (g < 1179648) { src = W2; dst = (ushort4*)oW2; i = g - 655360; }
    else { src = tw; dst = (ushort4*)otw; i = g - 1179648; }
    float4 v = ((const float4*)src)[i];
    ushort4 o;
    o.x = f2b(v.x); o.y = f2b(v.y); o.z = f2b(v.z); o.w = f2b(v.w);
    dst[i] = o;
  } else if (gid < 2371584) {
    int g = gid - 1585152;  // conv weight (D,I,3) -> bf16 (D,3,I)
    int d = g / 1536, r = g - d * 1536;
    int t = r >> 9, i = r & 511;
    Cwb[g] = f2b(conv_w[d * 1536 + i * 3 + t]);
  } else if (gid < 2387968) {
    int g = gid - 2371584;  // proj weight (32,512) -> (512,32) fp32
    int k = g >> 5, n = g & 31;
    PWt[g] = proj_w[n * 512 + k];
  } else if (gid < 2391552) {
    int g = gid - 2387968;  // ZB + concat qkv bias
    if (g < 512) { ZB[g] = 0.f; }
    else {
      int gg = g - 512;
      int layer = gg / 1536, r = gg - layer * 1536;
      float v;
      if (r < 512) v = bq[layer * 512 + r];
      else if (r < 1024) v = bk[layer * 512 + r - 512];
      else v = bv[layer * 512 + r - 1024];
      BQKV[gg] = v;
    }
  } else if (gid < 2915840) {
    int i = gid - 2391552;  // PE (sin,cos) pairs
    int d2 = i & 255, l = i >> 8;
    float div = __expf((float)(2 * d2) * -1.7988946039e-2f);
    float ang = (float)l * div;
    float s, c;
    __sincosf(ang, &s, &c);
    ((float2*)pe)[i] = make_float2(s, c);
  } else if (gid < 3702272) {
    int g = gid - 2915840;  // im2col for token conv
    int col = g % 96;
    int row = g / 96;
    int c = col / 3, t = col - c * 3;
    int b = row >> 11, l = row & 2047;
    int ls = (l + t - 1) & 2047;
    Atok[g] = f2b(xe[((size_t)b * 2048 + ls) * 32 + c]);
  } else if (gid < 3784192) {
    int i = gid - 3702272;  // gen_idx layer 0
    uint32_t o0, o1;
    threefry2x32(s00, s01, 0u, (uint32_t)i, &o0, &o1);
    idx0[i] = (int)((o0 ^ o1) & 2047u);
  } else if (gid < 3820032) {
    int i = gid - 3784192;  // gen_idx layer 1
    uint32_t o0, o1;
    threefry2x32(s10, s11, 0u, (uint32_t)i, &o0, &o1);
    idx1[i] = (int)((o0 ^ o1) & 1023u);
  }
}

__device__ inline float wave_sum64(float v) {
  #pragma unroll
  for (int o = 32; o > 0; o >>= 1) v += __shfl_xor(v, o, 64);
  return v;
}

// ---------------- bf16 MFMA GEMM: TM=128, in-row swizzle, counted vmcnt ----
__device__ inline void gload16(const ushort_t* g, ushort_t* l) {
  __builtin_amdgcn_global_load_lds(
      (const __attribute__((address_space(1))) unsigned int*)(const void*)g,
      (__attribute__((address_space(3))) unsigned int*)(void*)l, 16, 0, 0);
}

// CONV: A is Xb (B*L x 512 bf16); logical A[row][k] = Xb[(row_b, (l+t-1)%2048)][c]
// with t = k/512, c = k%512. Otherwise plain row-major A (M x K).
// SPLITK==2: both halves write RAW fp32 partials; consumers reduce.
template <int TM, int CONV, int GELU, int OMODE, int ADDPE, int SPLITK>
__global__ __launch_bounds__(512, 4) void mgemm_k(
    const ushort_t* __restrict__ A, const ushort_t* __restrict__ W,
    const float* __restrict__ bias, float* __restrict__ Cf,
    float* __restrict__ Cf2, ushort_t* __restrict__ Cb,
    const float* __restrict__ pe, int X, int ldc, int K) {
  constexpr int MT = TM / 64;        // acc row-tiles per wave (2 or 4)
  constexpr int AG = TM / 128;       // A gloads per wave per K-step (1 or 2)
  constexpr int BUFSZ = (TM + 128) * 32;  // ushorts per staging buffer
  constexpr int SHSZ = (3 * BUFSZ > 18432) ? 3 * BUFSZ : 18432;
  __shared__ __align__(16) ushort_t SH[SHSZ];
  int id = blockIdx.x;
  int half = 0;
  if (SPLITK == 2) {
    int nb = gridDim.x >> 1;
    if (id >= nb) { half = 1; id -= nb; }
  }
  int kbase = half * (K >> 1);
  int KK = (SPLITK == 2) ? (K >> 1) : K;
  int cc = id & 7, j = id >> 3;
  int bx = j % X;
  int by = (j / X) * 8 + cc;
  int m0 = by * TM, n0 = bx * 128;
  int t = threadIdx.x;
  int lane = t & 63, wv = t >> 6;  // 8 waves
  int rl = lane >> 2;
  int cl = ((lane & 3) ^ ((rl >> 1) & 3)) * 8;  // in-segment chunk swizzle
  int RaA = wv * (16 * AG);  // A rows staged per wave
  int RaB = wv * 16;         // B rows staged per wave
  const ushort_t* gA[AG];
  int cbv[AG], clrv[AG], lAoff[AG];
  #pragma unroll
  for (int g = 0; g < AG; ++g) {
    int ar = m0 + RaA + g * 16 + rl;
    gA[g] = A + (size_t)ar * K + kbase + cl;  // non-CONV path
    cbv[g] = ar >> 11;                        // CONV: batch
    clrv[g] = ar & 2047;                      // CONV: seq pos
    lAoff[g] = (RaA + g * 16) * 32;
  }
  const ushort_t* gB = W + (size_t)(n0 + RaB + rl) * K + kbase + cl;
  int lBoff = TM * 32 + RaB * 32;

  int quad = lane >> 4, lr = lane & 15;
  int qs = (quad ^ ((lr >> 1) & 3)) * 8;  // swizzled read chunk offset
  int wm = wv >> 1, wn = wv & 1;  // 4 (M) x 2 (N) waves, (TM/4)x64 each

  // stage K-step kst into LDS buffer buf (AG+1 vmem instructions per wave)
  auto STAGE = [&](int kst, int buf) {
    int bb = buf * BUFSZ;
    int ko = kst << 5;
    #pragma unroll
    for (int g = 0; g < AG; ++g) {
      if (CONV) {
        int kg = kbase + ko;
        int tt = kg >> 9;
        int c = (kg & 511) + cl;
        int ls = (clrv[g] + tt - 1) & 2047;
        gload16(A + ((size_t)(cbv[g] * 2048 + ls) * 512 + c),
                SH + bb + lAoff[g]);
      } else {
        gload16(gA[g] + ko, SH + bb + lAoff[g]);
      }
    }
    gload16(gB + ko, SH + bb + lBoff);
  };

  floatx4 acc[MT][4] = {};
  int nt = KK >> 5;
  STAGE(0, 0);
  if (nt > 1) STAGE(1, 1);
  int cur = 0;
  for (int it = 0; it < nt; ++it) {
    // counted wait: own stage(it) complete; stage(it+1) stays in flight
    if (it < nt - 1) {
      if constexpr (AG == 1)
        asm volatile("s_waitcnt vmcnt(2)" ::: "memory");
      else
        asm volatile("s_waitcnt vmcnt(3)" ::: "memory");
    } else {
      asm volatile("s_waitcnt vmcnt(0)" ::: "memory");
    }
    __builtin_amdgcn_s_barrier();        // all waves: stage(it) landed,
    __builtin_amdgcn_sched_barrier(0);   // prior-iter reads retired
    int nx = it + 2;
    if (nx < nt) {
      int nb3 = cur + 2;
      if (nb3 >= 3) nb3 -= 3;
      STAGE(nx, nb3);                    // buf last read at it-1: safe
    }
    const ushort_t* Ab = SH + cur * BUFSZ;
    const ushort_t* Bb = Ab + TM * 32;
    bf16x8 av[MT], bv[4];
    #pragma unroll
    for (int mt = 0; mt < MT; ++mt)
      av[mt] =
          *(const bf16x8*)&Ab[(wm * (16 * MT) + mt * 16 + lr) * 32 + qs];
    #pragma unroll
    for (int nt2 = 0; nt2 < 4; ++nt2)
      bv[nt2] = *(const bf16x8*)&Bb[(wn * 64 + nt2 * 16 + lr) * 32 + qs];
    #pragma unroll
    for (int mt = 0; mt < MT; ++mt)
      #pragma unroll
      for (int nt2 = 0; nt2 < 4; ++nt2)
        acc[mt][nt2] = __builtin_amdgcn_mfma_f32_16x16x32_bf16(
            av[mt], bv[nt2], acc[mt][nt2], 0, 0, 0);
    // all my LDS reads retired before next barrier (closes WAR window)
    asm volatile("s_waitcnt lgkmcnt(0)" ::: "memory");
    __builtin_amdgcn_sched_barrier(0);
    cur = (cur == 2) ? 0 : cur + 1;
  }
  __syncthreads();  // epilogue reuses SH

  if (SPLITK == 2) {
    // raw fp32 partial; bias applied by the consumer
    float* dst = half ? Cf2 : Cf;
    #pragma unroll
    for (int nt2 = 0; nt2 < 4; ++nt2) {
      int col = n0 + wn * 64 + nt2 * 16 + lr;
      #pragma unroll
      for (int mt = 0; mt < MT; ++mt) {
        int row0 = m0 + wm * (16 * MT) + mt * 16 + quad * 4;
        #pragma unroll
        for (int r = 0; r < 4; ++r)
          dst[(size_t)(row0 + r) * ldc + col] = acc[mt][nt2][r];
      }
    }
  } else if (OMODE == 0) {
    #pragma unroll
    for (int nt2 = 0; nt2 < 4; ++nt2) {
      int col = n0 + wn * 64 + nt2 * 16 + lr;
      float bsv = bias[col];
      #pragma unroll
      for (int mt = 0; mt < MT; ++mt) {
        int row0 = m0 + wm * (16 * MT) + mt * 16 + quad * 4;
        #pragma unroll
        for (int r = 0; r < 4; ++r) {
          int row = row0 + r;
          float v = acc[mt][nt2][r] + bsv;
          if (ADDPE) v += pe[(size_t)(row & 2047) * ldc + col];
          if (GELU) v = 0.5f * v * (1.0f + erff(v * 0.70710678118654752f));
          Cf[(size_t)row * ldc + col] = v;
        }
      }
    }
  } else {
    // bf16 through per-wave LDS transpose -> coalesced ushort8 stores.
    ushort_t* ep = SH + wv * 2304;
    #pragma unroll
    for (int p = 0; p < MT / 2; ++p) {
      #pragma unroll
      for (int nt2 = 0; nt2 < 4; ++nt2) {
        int col = n0 + wn * 64 + nt2 * 16 + lr;
        float bsv = bias[col];
        #pragma unroll
        for (int ml = 0; ml < 2; ++ml) {
          int mt = p * 2 + ml;
          #pragma unroll
          for (int r = 0; r < 4; ++r) {
            int row = m0 + wm * (16 * MT) + mt * 16 + quad * 4 + r;
            float v = acc[mt][nt2][r] + bsv;
            if (ADDPE) v += pe[(size_t)(row & 2047) * ldc + col];
            if (GELU) v = 0.5f * v * (1.0f + erff(v * 0.70710678118654752f));
            if (OMODE == 2) Cf[(size_t)row * ldc + col] = v;
            ep[(ml * 16 + quad * 4 + r) * 72 + nt2 * 16 + lr] = f2b(v);
          }
        }
      }
      int r8 = lane >> 3, c8 = (lane & 7) * 8;
      #pragma unroll
      for (int i = 0; i < 4; ++i) {
        int row = i * 8 + r8;
        ushort8_t vv = *(const ushort8_t*)&ep[row * 72 + c8];
        *(ushort8_t*)&Cb[(size_t)(m0 + wm * (16 * MT) + p * 32 + row) * ldc +
                         n0 + wn * 64 + c8] = vv;
      }
    }
  }
}

// ---------------- fused final LayerNorm + projection (row-local) -----------
// out[r][n] = (LN(A[r]) * g + be) @ Wt[:,n] + bias[n];  Wt is (512,32).
__global__ __launch_bounds__(128) void lnprojf_k(
    const float* __restrict__ A, const float* __restrict__ g,
    const float* __restrict__ be, const float* __restrict__ Wt,
    const float* __restrict__ bias, float* __restrict__ C) {
  int r = blockIdx.x, t = threadIdx.x;
  __shared__ float red[2];
  __shared__ float row[512];
  __shared__ float pacc[128];
  float4 v = ((const float4*)(A + (size_t)r * DM))[t];
  float s = wave_sum64(v.x + v.y + v.z + v.w);
  int w = t >> 6;
  if ((t & 63) == 0) red[w] = s;
  __syncthreads();
  float mu = (red[0] + red[1]) * (1.0f / 512.0f);
  __syncthreads();
  float dx = v.x - mu, dy = v.y - mu, dz = v.z - mu, dw = v.w - mu;
  float sq = wave_sum64(dx * dx + dy * dy + dz * dz + dw * dw);
  if ((t & 63) == 0) red[w] = sq;
  __syncthreads();
  float var = (red[0] + red[1]) * (1.0f / 512.0f);
  float inv = 1.0f / sqrtf(var + 1e-5f);
  float4 gv = ((const float4*)g)[t];
  float4 bv = ((const float4*)be)[t];
  float4 o;
  o.x = dx * inv * gv.x + bv.x;
  o.y = dy * inv * gv.y + bv.y;
  o.z = dz * inv * gv.z + bv.z;
  o.w = dw * inv * gv.w + bv.w;
  ((float4*)row)[t] = o;
  __syncthreads();
  int n = t & 31, ks = t >> 5;  // 4 k-slices of 128
  const float* rp = row + ks * 128;
  const float* wp = Wt + ks * 128 * 32 + n;
  float acc = 0.f;
  #pragma unroll 4
  for (int k = 0; k < 128; ++k) acc += rp[k] * wp[k * 32];
  pacc[t] = acc;
  __syncthreads();
  if (t < 32)
    C[(size_t)r * 32 + t] =
        (pacc[t] + pacc[t + 64]) + (pacc[t + 32] + pacc[t + 96]) + bias[t];
}

// ---------------- LayerNorm (+residuals, +col bias, +optional bf16 copy) ---
// O = LN(A + Bres + Bres2 + cbias) * g + be; Bres/Bres2/cbias nullable.
__global__ __launch_bounds__(128) void ln_k(
    const float* __restrict__ A, const float* __restrict__ Bres,
    const float* __restrict__ Bres2, const float* __restrict__ cbias,
    const float* __restrict__ g, const float* __restrict__ be,
    float* __restrict__ O, ushort_t* __restrict__ Ob) {
  int r = blockIdx.x, t = threadIdx.x;
  __shared__ float lds[2];
  float4 v = ((const float4*)(A + (size_t)r * DM))[t];
  if (Bres) {
    float4 u = ((const float4*)(Bres + (size_t)r * DM))[t];
    v.x += u.x; v.y += u.y; v.z += u.z; v.w += u.w;
  }
  if (Bres2) {
    float4 u = ((const float4*)(Bres2 + (size_t)r * DM))[t];
    v.x += u.x; v.y += u.y; v.z += u.z; v.w += u.w;
  }
  if (cbias) {
    float4 u = ((const float4*)cbias)[t];
    v.x += u.x; v.y += u.y; v.z += u.z; v.w += u.w;
  }
  float s = wave_sum64(v.x + v.y + v.z + v.w);
  int w = t >> 6;
  if ((t & 63) == 0) lds[w] = s;
  __syncthreads();
  float mu = (lds[0] + lds[1]) * (1.0f / 512.0f);
  __syncthreads();
  float dx = v.x - mu, dy = v.y - mu, dz = v.z - mu, dw = v.w - mu;
  float sq = wave_sum64(dx * dx + dy * dy + dz * dz + dw * dw);
  if ((t & 63) == 0) lds[w] = sq;
  __syncthreads();
  float var = (lds[0] + lds[1]) * (1.0f / 512.0f);
  float inv = 1.0f / sqrtf(var + 1e-5f);
  float4 gv = ((const float4*)g)[t];
  float4 bv = ((const float4*)be)[t];
  float4 o;
  o.x = dx * inv * gv.x + bv.x;
  o.y = dy * inv * gv.y + bv.y;
  o.z = dz * inv * gv.z + bv.z;
  o.w = dw * inv * gv.w + bv.w;
  ((float4*)(O + (size_t)r * DM))[t] = o;
  if (Ob) {
    ushort4 ob;
    ob.x = f2b(o.x); ob.y = f2b(o.y); ob.z = f2b(o.z); ob.w = f2b(o.w);
    ((ushort4*)(Ob + (size_t)r * DM))[t] = ob;
  }
}

// ---------------- fused M[b,h,l] + meanV stage 1 ---------------------------
// blocks [0, Lx/2): qk_m, XCD-batch-partitioned: b = (blk&7)>>1 (XCDs
// {2b,2b+1} serve batch b only -> K working set 2MB/XCD fits 4MB L2);
// wave w handles l = 8*((blk>>3)*2 + (blk&1)) + w.
// blocks [Lx/2, Lx/2 + 64): meanv1 body (b = c>>4, chunk = c&15).
template <int UU>
__global__ __launch_bounds__(512) void qkmean_k(
    const ushort_t* __restrict__ QKVb, const int* __restrict__ idx,
    float* __restrict__ Mout, float* __restrict__ part, int Lx) {
  int qkb = Lx >> 1;
  int t = threadIdx.x;
  if ((int)blockIdx.x < qkb) {
    int blk = blockIdx.x;
    int wv = t >> 6, lane = t & 63;
    int b = (blk & 7) >> 1;
    int j = ((blk >> 3) << 1) | (blk & 1);
    int l = j * 8 + wv;
    const ushort_t* qp = QKVb + ((size_t)b * Lx + l) * QS + lane * 8;
    float q[8];
    {
      ushort8_t qv = *(const ushort8_t*)qp;
      #pragma unroll
      for (int c = 0; c < 8; ++c) q[c] = b2f(qv[c]);
    }
    const ushort_t* Kbase = QKVb + (size_t)b * Lx * QS + 512 + lane * 8;
    const int* ip = idx + (size_t)l * UU;
    float maxv = -INFINITY, sumv = 0.f;
    #pragma unroll
    for (int u0 = 0; u0 < UU; u0 += 8) {
      ushort8_t kv[8];
      #pragma unroll
      for (int j2 = 0; j2 < 8; ++j2) {
        if (u0 + j2 < UU)
          kv[j2] = *(const ushort8_t*)(Kbase + (size_t)ip[u0 + j2] * QS);
      }
      #pragma unroll
      for (int j2 = 0; j2 < 8; ++j2) {
        if (u0 + j2 < UU) {
          float p = 0.f;
          #pragma unroll
          for (int c = 0; c < 8; ++c) p += q[c] * b2f(kv[j2][c]);
          p += __shfl_xor(p, 1, 64);
          p += __shfl_xor(p, 2, 64);
          p += __shfl_xor(p, 4, 64);
          maxv = fmaxf(maxv, p);
          sumv += p;
        }
      }
    }
    if ((lane & 7) == 0) {
      int h = lane >> 3;
      Mout[(size_t)(b * 8 + h) * Lx + l] = maxv - sumv / (float)Lx;
    }
  } else {
    int blkc = (int)blockIdx.x - qkb;  // 0..63
    int b = blkc >> 4, chunk = blkc & 15;
    int rows = Lx >> 4;
    const ushort_t* vp =
        QKVb + ((size_t)b * Lx + (size_t)chunk * rows) * QS + 1024 + t;
    float s = 0.f;
    for (int l = 0; l < rows; ++l) s += b2f(vp[(size_t)l * QS]);
    part[(size_t)blkc * DM + t] = s;
  }
}

// ---------------- rank-based top-U, 4-way scan split (JAX tie-break) -------
__global__ __launch_bounds__(1024) void topk_k(
    const float* __restrict__ Mbuf, int* __restrict__ Mtop, int Lx, int U) {
  int nch = Lx >> 8;
  int bh = blockIdx.x / nch, ch = blockIdx.x % nch;
  const float* m = Mbuf + (size_t)bh * Lx;
  __shared__ float sm[2048];
  __shared__ int part[1024];
  int t = threadIdx.x;
  int c = t & 255, q = t >> 8;
  for (int i = t; i < Lx; i += 1024) sm[i] = m[i];
  __syncthreads();
  int i0 = (ch << 8) + c;
  float v0 = sm[i0];
  int r0 = 0;
  int qlen = Lx >> 2;
  int j0 = q * qlen, j1 = j0 + qlen;
  for (int j = j0; j < j1; j += 4) {
    float4 mj = *(const float4*)&sm[j];
    r0 += (mj.x > v0) || (mj.x == v0 && (j + 0) < i0);
    r0 += (mj.y > v0) || (mj.y == v0 && (j + 1) < i0);
    r0 += (mj.z > v0) || (mj.z == v0 && (j + 2) < i0);
    r0 += (mj.w > v0) || (mj.w == v0 && (j + 3) < i0);
  }
  part[t] = r0;
  __syncthreads();
  if (q == 0) {
    int r = part[c] + part[c + 256] + part[c + 512] + part[c + 768];
    if (r < U) Mtop[bh * U + r] = i0;
  }
}

// ---------------- meanV stage 2 --------------------------------------------
__global__ __launch_bounds__(512) void meanv2_k(const float* __restrict__ part,
                                                float* __restrict__ mv,
                                                int Lx) {
  int b = blockIdx.x, t = threadIdx.x;
  float s = 0.f;
  #pragma unroll
  for (int c = 0; c < 16; ++c) s += part[(size_t)(b * 16 + c) * DM + t];
  mv[b * DM + t] = s / (float)Lx;
}

__global__ void fillctx_k(ushort_t* __restrict__ ctx,
                          const float* __restrict__ mv, int Lx) {
  size_t i4 = (size_t)blockIdx.x * 256 + threadIdx.x;
  int col4 = (int)(i4 & 127);
  size_t row = i4 >> 7;
  int b = (int)(row / (size_t)Lx);
  const float* m = mv + b * DM + col4 * 4;
  ushort4 o;
  o.x = f2b(m[0]); o.y = f2b(m[1]); o.z = f2b(m[2]); o.w = f2b(m[3]);
  ((ushort4*)ctx)[i4] = o;
}

// ---------------- one-shot MFMA attention (wave = one 64-key chunk) --------
// 2 waves/block (128 thr): waves fully independent.
template <int UP>  // padded query count (48 >= U)
__global__ __launch_bounds__(128) void attn_mfma_k(
    const ushort_t* __restrict__ QKVb, const int* __restrict__ Mtop,
    float* __restrict__ part, int Lx, int U, int nblk) {
  __shared__ ushort_t Ps[2][UP * 72];   // P transpose buf (stride 72 elems)
  __shared__ ushort_t Vs[2][64 * 64];   // V tile, xor-swizzled
  int bh = blockIdx.x / nblk, blkc = blockIdx.x % nblk;
  int h = bh & 7, b = bh >> 3;
  int t = threadIdx.x;
  int wv = t >> 6, lane = t & 63;
  int quad = lane >> 4, lr = lane & 15;
  int chunk = blkc * 2 + wv;
  int k0 = chunk * 64;
  const ushort_t* Qb = QKVb + (size_t)b * Lx * QS + h * HD;
  const ushort_t* Kb = Qb + 512;
  const ushort_t* Vb = Qb + 1024;

  // Q fragments: rows gathered via Mtop (clamped for padded rows)
  bf16x8 qf[3][2];
  #pragma unroll
  for (int mt = 0; mt < 3; ++mt) {
    int u = mt * 16 + lr;
    int qi = Mtop[bh * U + (u < U ? u : U - 1)];
    const ushort_t* qp = Qb + (size_t)qi * QS + quad * 8;
    qf[mt][0] = *(const bf16x8*)qp;
    qf[mt][1] = *(const bf16x8*)(qp + 32);
  }

  // stage V tile (64 rows x 64 d), xor-swizzle so column reads are
  // conflict-free: elem addr = k*64 + (d ^ (((k>>3)&3)<<4))
  ushort_t* vs = Vs[wv];
  #pragma unroll
  for (int i = 0; i < 8; ++i) {
    int cid = i * 64 + lane;
    int k = cid >> 3, c = cid & 7;
    ushort8_t v = *(const ushort8_t*)(Vb + (size_t)(k0 + k) * QS + c * 8);
    *(ushort8_t*)&vs[k * 64 + ((c * 8) ^ (((k >> 3) & 3) << 4))] = v;
  }

  // S = Q K^T (K frags direct from global)
  floatx4 Sa[3][4] = {};
  #pragma unroll
  for (int kt = 0; kt < 4; ++kt) {
    const ushort_t* kp = Kb + (size_t)(k0 + kt * 16 + lr) * QS + quad * 8;
    bf16x8 kf0 = *(const bf16x8*)kp;
    bf16x8 kf1 = *(const bf16x8*)(kp + 32);
    #pragma unroll
    for (int mt = 0; mt < 3; ++mt) {
      Sa[mt][kt] = __builtin_amdgcn_mfma_f32_16x16x32_bf16(
          qf[mt][0], kf0, Sa[mt][kt], 0, 0, 0);
      Sa[mt][kt] = __builtin_amdgcn_mfma_f32_16x16x32_bf16(
          qf[mt][1], kf1, Sa[mt][kt], 0, 0, 0);
    }
  }

  // softmax over the 64 local keys (rows u = mt*16 + quad*4 + r, col = lr)
  float m_[3][4], l_[3][4];
  #pragma unroll
  for (int mt = 0; mt < 3; ++mt) {
    #pragma unroll
    for (int kt = 0; kt < 4; ++kt) Sa[mt][kt] *= 0.125f;
    #pragma unroll
    for (int r = 0; r < 4; ++r) {
      float mx = fmaxf(fmaxf(Sa[mt][0][r], Sa[mt][1][r]),
                       fmaxf(Sa[mt][2][r], Sa[mt][3][r]));
      #pragma unroll
      for (int o = 1; o <= 8; o <<= 1) mx = fmaxf(mx, __shfl_xor(mx, o, 64));
      float rs = 0.f;
      #pragma unroll
      for (int kt = 0; kt < 4; ++kt) {
        float e = __expf(Sa[mt][kt][r] - mx);
        Sa[mt][kt][r] = e;
        rs += e;
      }
      #pragma unroll
      for (int o = 1; o <= 8; o <<= 1) rs += __shfl_xor(rs, o, 64);
      m_[mt][r] = mx;
      l_[mt][r] = rs;
    }
  }

  // PV in bf16 hi+lo (near-fp32 accuracy). P transposed via per-wave LDS.
  ushort_t* ps = Ps[wv];
  floatx4 Oa[3][4] = {};
  #pragma unroll
  for (int pass = 0; pass < 2; ++pass) {
    #pragma unroll
    for (int mt = 0; mt < 3; ++mt)
      #pragma unroll
      for (int kt = 0; kt < 4; ++kt)
        #pragma unroll
        for (int r = 0; r < 4; ++r) {
          float e = Sa[mt][kt][r];
          ushort_t hb = f2b(e);
          ps[(mt * 16 + quad * 4 + r) * 72 + kt * 16 + lr] = hb;
          Sa[mt][kt][r] = e - b2f(hb);  // residual for lo pass
        }
    #pragma unroll
    for (int kk = 0; kk < 2; ++kk) {
      bf16x8 pf[3];
      #pragma unroll
      for (int mt = 0; mt < 3; ++mt)
        pf[mt] = *(const bf16x8*)&ps[(mt * 16 + lr) * 72 + kk * 32 + quad * 8];
      #pragma unroll
      for (int nt = 0; nt < 4; ++nt) {
        ushort8_t vt;
        #pragma unroll
        for (int j = 0; j < 8; ++j)
          vt[j] = vs[(kk * 32 + quad * 8 + j) * 64 +
                     ((nt * 16 + lr) ^ (quad << 4))];
        bf16x8 vf = *(bf16x8*)&vt;
        #pragma unroll
        for (int mt = 0; mt < 3; ++mt)
          Oa[mt][nt] = __builtin_amdgcn_mfma_f32_16x16x32_bf16(
              pf[mt], vf, Oa[mt][nt], 0, 0, 0);
      }
    }
  }

  // store partial (u < U only; format matches attn_merge_k)
  float* pb = part + (size_t)(bh * (nblk * 2) + chunk) * U * 66;
  #pragma unroll
  for (int mt = 0; mt < 3; ++mt) {
    #pragma unroll
    for (int r = 0; r < 4; ++r) {
      int u = mt * 16 + quad * 4 + r;
      if (u < U) {
        #pragma unroll
        for (int nt = 0; nt < 4; ++nt)
          pb[(size_t)u * 66 + nt * 16 + lr] = Oa[mt][nt][r];
        if (lr == 0) {
          pb[(size_t)u * 66 + 64] = m_[mt][r];
          pb[(size_t)u * 66 + 65] = l_[mt][r];
        }
      }
    }
  }
}

__global__ __launch_bounds__(64) void attn_merge_k(
    const float* __restrict__ part, const int* __restrict__ Mtop,
    ushort_t* __restrict__ ctx, int Lx, int U, int nchunk) {
  int bu = blockIdx.x;
  int u = bu % U, bh = bu / U;
  int h = bh & 7, b = bh >> 3;
  int d = threadIdx.x;  // 64
  float M = -INFINITY;
  for (int c = 0; c < nchunk; ++c)
    M = fmaxf(M, part[((size_t)(bh * nchunk + c) * U + u) * 66 + 64]);
  float L = 0.f, O = 0.f;
  for (int c = 0; c < nchunk; ++c) {
    const float* pp = part + ((size_t)(bh * nchunk + c) * U + u) * 66;
    float w = __expf(pp[64] - M);
    L += pp[65] * w;
    O += pp[d] * w;
  }
  int qi = Mtop[bh * U + u];
  ctx[((size_t)b * Lx + qi) * DM + h * HD + d] = f2b(O / L);
}

// ---------------- batch-norm stats over two partials + bias ----------------
__global__ __launch_bounds__(256) void bn1_k(const float* __restrict__ Y0,
                                             const float* __restrict__ Y1,
                                             const float* __restrict__ cb,
                                             float* __restrict__ ps,
                                             float* __restrict__ pq) {
  int blk = blockIdx.x;
  int t = threadIdx.x;
  float cb0 = cb[t], cb1 = cb[t + 256];
  float s0 = 0, q0 = 0, s1 = 0, q1 = 0;
  const float* b0 = Y0 + (size_t)blk * 256 * DM;
  const float* b1 = Y1 + (size_t)blk * 256 * DM;
  for (int r = 0; r < 256; ++r) {
    float a = b0[(size_t)r * DM + t] + b1[(size_t)r * DM + t] + cb0;
    float b = b0[(size_t)r * DM + t + 256] + b1[(size_t)r * DM + t + 256] + cb1;
    s0 += a; q0 += a * a; s1 += b; q1 += b * b;
  }
  ps[blk * DM + t] = s0; ps[blk * DM + t + 256] = s1;
  pq[blk * DM + t] = q0; pq[blk * DM + t + 256] = q1;
}
__global__ __launch_bounds__(512) void bn2_k(const float* __restrict__ ps,
                                             const float* __restrict__ pq,
                                             float* __restrict__ mu,
                                             float* __restrict__ var) {
  int t = threadIdx.x;
  float s = 0, q = 0;
  #pragma unroll
  for (int c = 0; c < 32; ++c) { s += ps[c * DM + t]; q += pq[c * DM + t]; }
  float m = s * (1.0f / 8192.f);
  mu[t] = m;
  var[t] = q * (1.0f / 8192.f) - m * m;
}

// fused bn+elu+maxpool(k=3,s=2,pad=1) over two partials + bias
__global__ void bnpool_k(const float* __restrict__ Y0,
                         const float* __restrict__ Y1,
                         const float* __restrict__ cb,
                         const float* __restrict__ mu,
                         const float* __restrict__ var,
                         const float* __restrict__ g,
                         const float* __restrict__ be, float* __restrict__ O,
                         ushort_t* __restrict__ Ob) {
  size_t i = (size_t)blockIdx.x * 256 + threadIdx.x;  // 4*1024*512
  int c = (int)(i & 511);
  size_t row = i >> 9;
  int lo = (int)(row & 1023);
  int b = (int)(row >> 10);
  float sc = g[c] / sqrtf(var[c] + 1e-5f);
  float sh = be[c] - mu[c] * sc;
  float cbv = cb[c];
  int l0 = 2 * lo - 1;
  float m = -INFINITY;
  #pragma unroll
  for (int tt = 0; tt < 3; ++tt) {
    int l = l0 + tt;
    if (l >= 0 && l < 2048) {
      size_t off = ((size_t)b * 2048 + l) * DM + c;
      float v = (Y0[off] + Y1[off] + cbv) * sc + sh;
      v = v > 0.f ? v : expm1f(v);
      m = fmaxf(m, v);
    }
  }
  O[i] = m;
  Ob[i] = f2b(m);
}

// ---------------------------------------------------------------------------
extern "C" void kernel_launch(void* const* d_in, const int* in_sizes, int n_in,
                              void* d_out, int out_size, void* d_ws,
                              size_t ws_size, hipStream_t stream) {
  (void)in_sizes; (void)n_in; (void)out_size; (void)ws_size;
  const float* x_enc  = (const float*)d_in[0];
  const float* tok_w  = (const float*)d_in[1];
  const float* Wq     = (const float*)d_in[2];
  const float* bq     = (const float*)d_in[3];
  const float* Wk     = (const float*)d_in[4];
  const float* bk     = (const float*)d_in[5];
  const float* Wv     = (const float*)d_in[6];
  const float* bv     = (const float*)d_in[7];
  const float* Wo     = (const float*)d_in[8];
  const float* bo     = (const float*)d_in[9];
  const float* W1     = (const float*)d_in[10];
  const float* b1     = (const float*)d_in[11];
  const float* W2     = (const float*)d_in[12];
  const float* b2     = (const float*)d_in[13];
  const float* ln1_g  = (const float*)d_in[14];
  const float* ln1_b  = (const float*)d_in[15];
  const float* ln2_g  = (const float*)d_in[16];
  const float* ln2_b  = (const float*)d_in[17];
  const float* conv_w = (const float*)d_in[18];
  const float* conv_b = (const float*)d_in[19];
  const float* bn_g   = (const float*)d_in[20];
  const float* bn_b   = (const float*)d_in[21];
  const float* normf_g = (const float*)d_in[22];
  const float* normf_b = (const float*)d_in[23];
  const float* proj_w = (const float*)d_in[24];
  const float* proj_b = (const float*)d_in[25];
  float* out = (float*)d_out;
  float* ws = (float*)d_ws;

  // ---- fp32 workspace layout (float offsets) ----
  float* X    = ws;                    // 4,194,304
  float* Y2B  = ws + 4194304;          // 4,194,304 (split-K partial #2)
  ushort_t* CTXb = (ushort_t*)(ws + 16777216);  // bf16 ctx
  float* Y2   = ws + 20971520;         // 4,194,304 (attn partials / partial #1)
  float* Mb   = ws + 25165824;         // 65,536
  float* MV   = ws + 25231360;         // 2,048
  float* MVP  = ws + 25233408;         // 32,768
  float* BNps = ws + 25266176;         // 16,384
  float* BNpq = ws + 25282560;         // 16,384
  float* BNmu = ws + 25298944;         // 512
  float* BNvr = ws + 25299456;         // 512
  float* ZB   = ws + 25299968;         // 512 (zero bias)
  float* BQKV = ws + 25300480;         // 3,072 (concat qkv bias, 2 layers)
  int*   IDX  = (int*)(ws + 25303552); // 81,920 (layer 0)
  int*   MT   = (int*)(ws + 25385472); // 1,280
  // ---- bf16 workspace ----
  ushort_t* U0   = (ushort_t*)(ws + 25386752);
  ushort_t* Xb   = U0;                 // 4,194,304
  ushort_t* Hb   = U0 + 4194304;       // 16,777,216 (FFN hidden)
  ushort_t* QKVb = Hb;                 // alias: bf16 QKV — live QKV-GEMM ->
                                       // attn, before FFN uses Hb
  ushort_t* Wqkvb= U0 + 20971520;      // 1,572,864
  ushort_t* Wob  = U0 + 22544384;      // 524,288
  ushort_t* W1b  = U0 + 23068672;      // 2,097,152
  ushort_t* W2b  = U0 + 25165824;      // 2,097,152
  ushort_t* Cwb  = U0 + 27262976;      // 786,432 ([d][t][i] layout)
  ushort_t* Twb  = U0 + 28049408;      // 49,152
  ushort_t* Atok = U0 + 28098560;      // 786,432
  float* PEf = ws + 39829248;          // 1,048,576 (PE table)
  float* PWt = ws + 40877824;          // 16,384 (transposed proj weight)
  int*   IDX2 = (int*)(ws + 40894208); // 35,840 (layer 1)

  // ---- single fused preamble launch (casts + tables + both idx sets) ----
  uint32_t s00, s01, s10, s11;
  {
    uint32_t kl0, kl1;
    threefry2x32(0u, 42u, 0u, 0u, &kl0, &kl1);
    threefry2x32(kl0, kl1, 0u, 1u, &s00, &s01);
    threefry2x32(0u, 42u, 0u, 1u, &kl0, &kl1);
    threefry2x32(kl0, kl1, 0u, 1u, &s10, &s11);
  }
  preamble_k<<<14922, 256, 0, stream>>>(
      Wq, Wk, Wv, Wo, W1, W2, tok_w, conv_w, proj_w, bq, bk, bv, x_enc,
      Wqkvb, Wob, W1b, W2b, Twb, Cwb, PWt, ZB, BQKV, PEf, Atok,
      IDX, IDX2, s00, s01, s10, s11);

  // token embedding GEMM (+PE): K=96
  mgemm_k<128, 0, 0, 2, 1, 1><<<256, 512, 0, stream>>>(
      Atok, Twb, ZB, X, nullptr, Xb, PEf, 4, DM, 96);

  for (int layer = 0; layer < 2; ++layer) {
    const int Lx = (layer == 0) ? 2048 : 1024;
    const int U  = (layer == 0) ? 40 : 35;
    const int M  = NB * Lx;
    const int Yt = M / 128;
    const int NCHT = Lx / 64;          // one 64-key chunk per wave
    const int NBLK = NCHT / 2;         // 2 waves per block
    const int* idxp = (layer == 0) ? IDX : IDX2;

    // fused QKV GEMM: bf16-only output
    mgemm_k<128, 0, 0, 1, 0, 1><<<12 * Yt, 512, 0, stream>>>(
        Xb, Wqkvb + (size_t)layer * 786432, BQKV + layer * 1536, nullptr,
        nullptr, QKVb, nullptr, 12, QS, DM);

    // ProbSparse attention (all bf16 QKV); qk_m + meanv1 fused
    if (layer == 0)
      qkmean_k<40><<<Lx / 2 + 64, 512, 0, stream>>>(QKVb, idxp, Mb, MVP, Lx);
    else
      qkmean_k<35><<<Lx / 2 + 64, 512, 0, stream>>>(QKVb, idxp, Mb, MVP, Lx);
    topk_k<<<NB * NH * (Lx >> 8), 1024, 0, stream>>>(Mb, MT, Lx, U);
    meanv2_k<<<NB, 512, 0, stream>>>(MVP, MV, Lx);
    fillctx_k<<<(M * DM / 4) / 256, 256, 0, stream>>>(CTXb, MV, Lx);
    attn_mfma_k<48><<<NB * NH * NBLK, 128, 0, stream>>>(QKVb, MT, Y2, Lx, U,
                                                        NBLK);
    attn_merge_k<<<NB * NH * U, 64, 0, stream>>>(Y2, MT, CTXb, Lx, U, NCHT);

    // output projection split-K x2 (raw partials) + residual+bias in LN1
    mgemm_k<128, 0, 0, 0, 0, 2><<<2 * 4 * Yt, 512, 0, stream>>>(
        CTXb, Wob + (size_t)layer * 262144, nullptr, Y2, Y2B, nullptr,
        nullptr, 4, DM, DM);
    ln_k<<<M, 128, 0, stream>>>(X, Y2, Y2B, bo + layer * DM,
                                ln1_g + layer * DM, ln1_b + layer * DM, X, Xb);

    // FFN1 (GELU fused; hidden kept in bf16)
    mgemm_k<128, 0, 1, 1, 0, 1><<<16 * Yt, 512, 0, stream>>>(
        Xb, W1b + (size_t)layer * 1048576, b1 + layer * 2048, nullptr, nullptr,
        Hb, nullptr, 16, 2048, DM);
    // FFN2 split-K x2 (raw partials) + residual+bias in LN2
    mgemm_k<128, 0, 0, 0, 0, 2><<<2 * 4 * Yt, 512, 0, stream>>>(
        Hb, W2b + (size_t)layer * 1048576, nullptr, Y2, Y2B, nullptr,
        nullptr, 4, DM, 2048);
    ln_k<<<M, 128, 0, stream>>>(X, Y2, Y2B, b2 + layer * DM,
                                ln2_g + layer * DM, ln2_b + layer * DM, X, Xb);

    if (layer == 0) {
      // distil conv as implicit GEMM, split-K x2; bias folded into bn stats
      mgemm_k<128, 1, 0, 0, 0, 2><<<2 * 4 * 64, 512, 0, stream>>>(
          Xb, Cwb, nullptr, Y2, Y2B, nullptr, nullptr, 4, DM, 1536);
      bn1_k<<<32, 256, 0, stream>>>(Y2, Y2B, conv_b, BNps, BNpq);
      bn2_k<<<1, 512, 0, stream>>>(BNps, BNpq, BNmu, BNvr);
      bnpool_k<<<(NB * 1024 * 512) / 256, 256, 0, stream>>>(
          Y2, Y2B, conv_b, BNmu, BNvr, bn_g, bn_b, X, Xb);
    }
  }

  // fused final LN + projection (row-local; no SCR round-trip)
  lnprojf_k<<<NB * 1024, 128, 0, stream>>>(X, normf_g, normf_b, PWt, proj_b,
                                           out);
}